// Round 2
// baseline (285171.387 us; speedup 1.0000x reference)
//
#include <hip/hip_runtime.h>
#include <math.h>

#define DZ 128
#define DX 64
#define KMIX 16
#define JITTER_C 1e-4f

// =====================================================================
// mm_core: acc[a][b] += sum_k At[k][i0+a] * B[k][j0+b]
// i.e. C = A*B where At holds A transposed (row k = column k of A).
// Works for LDS or global pointers. TM,TN in {2,4,8}.
// =====================================================================
template<int TM, int TN, int K>
__device__ __forceinline__ void mm_core(const float* __restrict__ At, int lda,
                                        const float* __restrict__ B, int ldb,
                                        int i0, int j0, float* __restrict__ acc)
{
#pragma unroll 2
    for (int k = 0; k < K; ++k) {
        const float* ar = At + k * lda + i0;
        const float* br = B + k * ldb + j0;
        float av[TM], bv[TN];
        if constexpr (TM == 2) {
            float2 t = *reinterpret_cast<const float2*>(ar);
            av[0] = t.x; av[1] = t.y;
        } else {
#pragma unroll
            for (int a = 0; a < TM; a += 4) {
                float4 t = *reinterpret_cast<const float4*>(ar + a);
                av[a] = t.x; av[a + 1] = t.y; av[a + 2] = t.z; av[a + 3] = t.w;
            }
        }
        if constexpr (TN == 2) {
            float2 t = *reinterpret_cast<const float2*>(br);
            bv[0] = t.x; bv[1] = t.y;
        } else {
#pragma unroll
            for (int b = 0; b < TN; b += 4) {
                float4 t = *reinterpret_cast<const float4*>(br + b);
                bv[b] = t.x; bv[b + 1] = t.y; bv[b + 2] = t.z; bv[b + 3] = t.w;
            }
        }
#pragma unroll
        for (int a = 0; a < TM; ++a)
#pragma unroll
            for (int b = 0; b < TN; ++b)
                acc[a * TN + b] = fmaf(av[a], bv[b], acc[a * TN + b]);
    }
}

// =====================================================================
// prep: Ct[z][m] = C[m][z]   (C^T, 128x64)
// =====================================================================
__global__ void kf_prep(const float* __restrict__ Cm, float* __restrict__ Ct)
{
    for (int i = threadIdx.x; i < DZ * DX; i += 256) {
        int z = i >> 6, m = i & 63;
        Ct[i] = Cm[m * DZ + z];
    }
}

// =====================================================================
// phase 1: per step k (one block per step) compute
//   G  = F^T            (F = R(h*eA), RK stability polynomial, deg 6)
//   Qe = h * sum_{m=0..5} gamma[m+1] * (hL)^m [eQ]   (exact RK noise term)
//   c  = h * sum_{m=0..5} gamma[m+1] * (h*eA)^m eb   (exact RK bias term)
// =====================================================================
__global__ __launch_bounds__(256) void kf_phase1(
    const float* __restrict__ A_s, const float* __restrict__ b_s,
    const float* __restrict__ Qch, const float* __restrict__ es,
    const float* __restrict__ ts,
    float* __restrict__ Gb, float* __restrict__ Qb, float* __restrict__ cb,
    int pred_start,
    float g1, float g2, float g3, float g4, float g5, float g6)
{
    __shared__ float hAt[DZ * DZ];   // (h*eA)^T
    __shared__ float Xs[DZ * DZ];    // working matrix (row-major)
    __shared__ float wsh[KMIX];
    __shared__ float ebv[DZ];
    __shared__ float eqv[DZ];
    __shared__ float vv[DZ];

    const int tid = threadIdx.x;
    const int tx = tid & 15, ty = tid >> 4;
    const int i0 = ty * 8, j0 = tx * 8;
    const int k = pred_start + blockIdx.x;
    float* Gk = Gb + (size_t)blockIdx.x * (DZ * DZ);
    float* Qk = Qb + (size_t)blockIdx.x * (DZ * DZ);
    float* ck = cb + (size_t)blockIdx.x * DZ;
    const float h = ts[k] - ts[k - 1];
    float g[7];
    g[0] = 1.f; g[1] = g1; g[2] = g2; g[3] = g3; g[4] = g4; g[5] = g5; g[6] = g6;

    if (h <= 0.f) {   // reference: no integration -> identity map
        for (int i = tid; i < DZ * DZ; i += 256) {
            int r = i >> 7, c = i & 127;
            Gk[i] = (r == c) ? 1.f : 0.f;
            Qk[i] = 0.f;
        }
        if (tid < DZ) ck[tid] = 0.f;
        return;
    }

    // weights
    if (tid < KMIX) wsh[tid] = es[(size_t)k * KMIX + tid];
    __syncthreads();
    if (tid == 0) {
        float s = 0.f;
        for (int m = 0; m < KMIX; ++m) s += wsh[m];
        float inv = 1.f / s;
        for (int m = 0; m < KMIX; ++m) wsh[m] *= inv;
    }
    __syncthreads();

    if (tid < DZ) {
        float eb = 0.f, eq = 0.f;
        for (int m = 0; m < KMIX; ++m) {
            float wm = wsh[m];
            eb += wm * b_s[m * DZ + tid];
            float qc = Qch[m * DZ + tid];
            eq += wm * qc * qc;
        }
        ebv[tid] = eb; eqv[tid] = eq;
    }

    // hA tile (h * sum_m w_m A_s[m]) into regs; write hAt (transposed) + Xs (= hA)
    float t64[64];
#pragma unroll
    for (int e = 0; e < 64; ++e) t64[e] = 0.f;
    for (int m = 0; m < KMIX; ++m) {
        float wm = wsh[m];
        const float* Am = A_s + (size_t)m * (DZ * DZ);
#pragma unroll
        for (int a = 0; a < 8; ++a) {
            float4 p0 = *reinterpret_cast<const float4*>(&Am[(i0 + a) * DZ + j0]);
            float4 p1 = *reinterpret_cast<const float4*>(&Am[(i0 + a) * DZ + j0 + 4]);
            t64[a * 8 + 0] = fmaf(wm, p0.x, t64[a * 8 + 0]);
            t64[a * 8 + 1] = fmaf(wm, p0.y, t64[a * 8 + 1]);
            t64[a * 8 + 2] = fmaf(wm, p0.z, t64[a * 8 + 2]);
            t64[a * 8 + 3] = fmaf(wm, p0.w, t64[a * 8 + 3]);
            t64[a * 8 + 4] = fmaf(wm, p1.x, t64[a * 8 + 4]);
            t64[a * 8 + 5] = fmaf(wm, p1.y, t64[a * 8 + 5]);
            t64[a * 8 + 6] = fmaf(wm, p1.z, t64[a * 8 + 6]);
            t64[a * 8 + 7] = fmaf(wm, p1.w, t64[a * 8 + 7]);
        }
    }
#pragma unroll
    for (int a = 0; a < 8; ++a)
#pragma unroll
        for (int b = 0; b < 8; ++b) {
            float v = h * t64[a * 8 + b];
            t64[a * 8 + b] = v;
            Xs[(i0 + a) * DZ + (j0 + b)] = v;
            hAt[(j0 + b) * DZ + (i0 + a)] = v;
        }
    __syncthreads();

    // ---- F = sum_m g[m] (hA)^m ----
    float Fa[64];
#pragma unroll
    for (int a = 0; a < 8; ++a)
#pragma unroll
        for (int b = 0; b < 8; ++b)
            Fa[a * 8 + b] = (((i0 + a) == (j0 + b)) ? 1.f : 0.f) + g[1] * t64[a * 8 + b];

    for (int m = 2; m <= 6; ++m) {
        float xn[64];
#pragma unroll
        for (int e = 0; e < 64; ++e) xn[e] = 0.f;
        mm_core<8, 8, DZ>(hAt, DZ, Xs, DZ, i0, j0, xn);   // xn = hA * X
#pragma unroll
        for (int e = 0; e < 64; ++e) Fa[e] = fmaf(g[m], xn[e], Fa[e]);
        __syncthreads();
#pragma unroll
        for (int a = 0; a < 8; ++a)
#pragma unroll
            for (int b = 0; b < 8; ++b)
                Xs[(i0 + a) * DZ + (j0 + b)] = xn[a * 8 + b];
        __syncthreads();
    }
    // F -> Xs, then store G = F^T coalesced
#pragma unroll
    for (int a = 0; a < 8; ++a)
#pragma unroll
        for (int b = 0; b < 8; ++b)
            Xs[(i0 + a) * DZ + (j0 + b)] = Fa[a * 8 + b];
    __syncthreads();
    if (tid < DZ) {
        for (int i = 0; i < DZ; i += 4) {
            float4 v;
            v.x = Xs[(i + 0) * DZ + tid];
            v.y = Xs[(i + 1) * DZ + tid];
            v.z = Xs[(i + 2) * DZ + tid];
            v.w = Xs[(i + 3) * DZ + tid];
            *reinterpret_cast<float4*>(&Gk[tid * DZ + i]) = v;
        }
    }
    __syncthreads();

    // ---- Q_eff = h * sum_{m=0..5} g[m+1] * Y_m,  Y_0 = eQ, Y_m = hA Y + Y hA^T ----
    float Qa[64];
#pragma unroll
    for (int a = 0; a < 8; ++a)
#pragma unroll
        for (int b = 0; b < 8; ++b) {
            float y0 = ((i0 + a) == (j0 + b)) ? eqv[i0 + a] : 0.f;
            Xs[(i0 + a) * DZ + (j0 + b)] = y0;
            Qa[a * 8 + b] = g[1] * y0;
        }
    __syncthreads();
    for (int m = 1; m <= 5; ++m) {
        float M[64];
#pragma unroll
        for (int e = 0; e < 64; ++e) M[e] = 0.f;
        mm_core<8, 8, DZ>(hAt, DZ, Xs, DZ, i0, j0, M);    // M = hA * Y
        __syncthreads();
#pragma unroll
        for (int a = 0; a < 8; ++a)
#pragma unroll
            for (int b = 0; b < 8; ++b)
                Xs[(i0 + a) * DZ + (j0 + b)] = M[a * 8 + b];
        __syncthreads();
        // Y_next = M + M^T
#pragma unroll
        for (int a = 0; a < 8; ++a)
#pragma unroll
            for (int b = 0; b < 8; ++b)
                M[a * 8 + b] += Xs[(j0 + b) * DZ + (i0 + a)];
#pragma unroll
        for (int e = 0; e < 64; ++e) Qa[e] = fmaf(g[m + 1], M[e], Qa[e]);
        __syncthreads();
#pragma unroll
        for (int a = 0; a < 8; ++a)
#pragma unroll
            for (int b = 0; b < 8; ++b)
                Xs[(i0 + a) * DZ + (j0 + b)] = M[a * 8 + b];
        __syncthreads();
    }
#pragma unroll
    for (int a = 0; a < 8; ++a) {
        float4 v0 = make_float4(h * Qa[a * 8 + 0], h * Qa[a * 8 + 1], h * Qa[a * 8 + 2], h * Qa[a * 8 + 3]);
        float4 v1 = make_float4(h * Qa[a * 8 + 4], h * Qa[a * 8 + 5], h * Qa[a * 8 + 6], h * Qa[a * 8 + 7]);
        *reinterpret_cast<float4*>(&Qk[(i0 + a) * DZ + j0]) = v0;
        *reinterpret_cast<float4*>(&Qk[(i0 + a) * DZ + j0 + 4]) = v1;
    }

    // ---- c = h * sum_{m=0..5} g[m+1] (hA)^m eb ----
    if (tid < DZ) vv[tid] = ebv[tid];
    float creg = (tid < DZ) ? g[1] * ebv[tid] : 0.f;
    __syncthreads();
    for (int m = 1; m <= 5; ++m) {
        float vn = 0.f;
        if (tid < DZ) {
            for (int kk = 0; kk < DZ; ++kk)
                vn = fmaf(hAt[kk * DZ + tid], vv[kk], vn);
        }
        __syncthreads();
        if (tid < DZ) vv[tid] = vn;
        creg = fmaf(g[m + 1], vn, creg);
        __syncthreads();
    }
    if (tid < DZ) ck[tid] = h * creg;
}

// =====================================================================
// phase 2: sequential filter, ONE block of 1024 threads (16 waves,
// 4 waves/SIMD for latency hiding).
// state layout (floats): P[16384], mu[128], Sinv[4096]
// =====================================================================
__global__ __launch_bounds__(1024) void kf_phase2(
    const float* __restrict__ xs, const float* __restrict__ Gb,
    const float* __restrict__ Qb, const float* __restrict__ cb,
    const float* __restrict__ Ct, const float* __restrict__ Cm,
    const float* __restrict__ Rm, const float* __restrict__ mu0,
    const float* __restrict__ P0,
    float* __restrict__ mu_out, float* __restrict__ P_out,
    float* __restrict__ state,
    int k0, int k1, int pred_start)
{
    __shared__ float Pl[DZ * DZ];      // P (then P_pr, then P_u)
    __shared__ float Ub[DZ * DZ];      // U / {CPt,CP} / {S,T} / Kgt
    __shared__ float Xinv[DX * DX];    // running S^{-1} (Newton-Schulz)
    __shared__ float muv[DZ];
    __shared__ float mupr[DZ];
    __shared__ float yv[DX];
    __shared__ float rowsum[DX];
    __shared__ float red[1];

    const int tid = threadIdx.x;
    const int tx = tid & 31, ty = tid >> 5;
    const int iL = ty * 4, jL = tx * 4;    // 128x128 tiles (4x4)
    const int jH = tx * 2;                 // 128x64 tiles (4x2)
    const int iS = ty * 2, jS = tx * 2;    // 64x64 tiles (2x2)

    if (k0 == 0) {
        for (int i = tid; i < DZ * DZ; i += 1024) Pl[i] = P0[i];
        if (tid < DZ) muv[tid] = mu0[tid];
        for (int i = tid; i < DX * DX; i += 1024) Xinv[i] = 0.f;
    } else {
        for (int i = tid; i < DZ * DZ; i += 1024) Pl[i] = state[i];
        if (tid < DZ) muv[tid] = state[16384 + tid];
        for (int i = tid; i < DX * DX; i += 1024) Xinv[i] = state[16512 + i];
    }
    __syncthreads();

    for (int k = k0; k < k1; ++k) {
        if (k > 0) {
            const size_t slot = (size_t)(k - pred_start);
            const float* Gk = Gb + slot * (DZ * DZ);
            const float* Qk = Qb + slot * (DZ * DZ);
            const float* ck = cb + slot * DZ;
            // U = P * F^T   (At = P symmetric, B = G global)
            float acc[16];
#pragma unroll
            for (int e = 0; e < 16; ++e) acc[e] = 0.f;
            mm_core<4, 4, DZ>(Pl, DZ, Gk, DZ, iL, jL, acc);
#pragma unroll
            for (int a = 0; a < 4; ++a)
                *reinterpret_cast<float4*>(&Ub[(iL + a) * DZ + jL]) =
                    make_float4(acc[a * 4 + 0], acc[a * 4 + 1], acc[a * 4 + 2], acc[a * 4 + 3]);
            // mu_pr = F mu + c   (8 threads per row, shfl reduce)
            {
                const int r = tid >> 3, sg = tid & 7;
                float s = 0.f;
                const int kb = sg * 16;
#pragma unroll
                for (int kk = 0; kk < 16; ++kk)
                    s = fmaf(Gk[(kb + kk) * DZ + r], muv[kb + kk], s);
                s += __shfl_xor(s, 1); s += __shfl_xor(s, 2); s += __shfl_xor(s, 4);
                if (sg == 0) mupr[r] = s + ck[r];
            }
            __syncthreads();
            // P_pr = F * U + Q   (At = G global, B = U)
#pragma unroll
            for (int e = 0; e < 16; ++e) acc[e] = 0.f;
            mm_core<4, 4, DZ>(Gk, DZ, Ub, DZ, iL, jL, acc);
#pragma unroll
            for (int a = 0; a < 4; ++a) {
                float4 q = *reinterpret_cast<const float4*>(&Qk[(iL + a) * DZ + jL]);
                *reinterpret_cast<float4*>(&Pl[(iL + a) * DZ + jL]) =
                    make_float4(acc[a * 4 + 0] + q.x, acc[a * 4 + 1] + q.y,
                                acc[a * 4 + 2] + q.z, acc[a * 4 + 3] + q.w);
            }
            __syncthreads();
        } else {
            if (tid < DZ) mupr[tid] = muv[tid];
            __syncthreads();
        }

        // ---------- measurement update ----------
        // CPt = P_pr * Ct (128x64); also CP = CPt^T (64x128)
        {
            float a8[8];
#pragma unroll
            for (int e = 0; e < 8; ++e) a8[e] = 0.f;
            mm_core<4, 2, DZ>(Pl, DZ, Ct, DX, iL, jH, a8);
#pragma unroll
            for (int a = 0; a < 4; ++a)
#pragma unroll
                for (int b = 0; b < 2; ++b) {
                    float v = a8[a * 2 + b];
                    Ub[(iL + a) * DX + (jH + b)] = v;            // CPt at Ub[0:8192)
                    Ub[8192 + (jH + b) * DZ + (iL + a)] = v;     // CP  at Ub[8192:16384)
                }
        }
        __syncthreads();

        // S = C * CPt + R + jitter*I  (64x64) into regs
        float s4[4];
#pragma unroll
        for (int e = 0; e < 4; ++e) s4[e] = 0.f;
        mm_core<2, 2, DZ>(Ct, DX, Ub, DX, iS, jS, s4);
#pragma unroll
        for (int a = 0; a < 2; ++a)
#pragma unroll
            for (int b = 0; b < 2; ++b) {
                s4[a * 2 + b] += Rm[(iS + a) * DX + (jS + b)];
                if ((iS + a) == (jS + b)) s4[a * 2 + b] += JITTER_C;
            }
        if (tid == 0) red[0] = 0.f;
        __syncthreads();   // all CPt reads done; red zeroed
#pragma unroll
        for (int a = 0; a < 2; ++a)
#pragma unroll
            for (int b = 0; b < 2; ++b)
                Ub[(iS + a) * DX + (jS + b)] = s4[a * 2 + b];   // S -> Ub[0:4096)

        // y = x - C mu_pr   (16 threads per row, shfl reduce)
        {
            const int r = tid >> 4, sg = tid & 15;
            const int z0 = sg * 8;
            float4 c0 = *reinterpret_cast<const float4*>(&Cm[r * DZ + z0]);
            float4 c1 = *reinterpret_cast<const float4*>(&Cm[r * DZ + z0 + 4]);
            float s = c0.x * mupr[z0] + c0.y * mupr[z0 + 1] + c0.z * mupr[z0 + 2] + c0.w * mupr[z0 + 3]
                    + c1.x * mupr[z0 + 4] + c1.y * mupr[z0 + 5] + c1.z * mupr[z0 + 6] + c1.w * mupr[z0 + 7];
            s += __shfl_xor(s, 1); s += __shfl_xor(s, 2); s += __shfl_xor(s, 4); s += __shfl_xor(s, 8);
            if (sg == 0) yv[r] = xs[(size_t)k * DX + r] - s;
        }
        __syncthreads();   // S + yv visible

        // ---------- Newton-Schulz S^{-1} (warm-started) ----------
        {
            float* Sp = Ub;
            float* Tp = Ub + 4096;
            float t4[4];
#pragma unroll
            for (int e = 0; e < 4; ++e) t4[e] = 0.f;
            mm_core<2, 2, DX>(Sp, DX, Xinv, DX, iS, jS, t4);   // T = S*X
            float pr = 0.f;
#pragma unroll
            for (int a = 0; a < 2; ++a)
#pragma unroll
                for (int b = 0; b < 2; ++b) {
                    float d = (((iS + a) == (jS + b)) ? 1.f : 0.f) - t4[a * 2 + b];
                    pr += d * d;
                }
            for (int o = 1; o < 64; o <<= 1) pr += __shfl_xor(pr, o);
            if ((tid & 63) == 0) atomicAdd(&red[0], pr);
#pragma unroll
            for (int a = 0; a < 2; ++a)
#pragma unroll
                for (int b = 0; b < 2; ++b)
                    Tp[(iS + a) * DX + (jS + b)] = t4[a * 2 + b];
            __syncthreads();
            const bool cold = !(red[0] <= 0.25f);   // ||I-SX||_F^2 check (NaN -> cold)
            const int iters = cold ? 12 : 3;
            if (cold) {
                if (tid < DX) {
                    float s = 0.f;
                    for (int j = 0; j < DX; ++j) s += fabsf(Sp[tid * DX + j]);
                    rowsum[tid] = s;
                }
                __syncthreads();
                if (tid == 0) {
                    float mx = 0.f;
                    for (int m = 0; m < DX; ++m) mx = fmaxf(mx, rowsum[m]);
                    red[0] = 1.f / mx;
                }
                __syncthreads();
                float inv = red[0];
#pragma unroll
                for (int a = 0; a < 2; ++a)
#pragma unroll
                    for (int b = 0; b < 2; ++b)
                        Xinv[(iS + a) * DX + (jS + b)] = ((iS + a) == (jS + b)) ? inv : 0.f;
                __syncthreads();
#pragma unroll
                for (int e = 0; e < 4; ++e) t4[e] = 0.f;
                mm_core<2, 2, DX>(Sp, DX, Xinv, DX, iS, jS, t4);
#pragma unroll
                for (int a = 0; a < 2; ++a)
#pragma unroll
                    for (int b = 0; b < 2; ++b)
                        Tp[(iS + a) * DX + (jS + b)] = t4[a * 2 + b];
                __syncthreads();
            }
            for (int it = 0; it < iters; ++it) {
                float xa[4];
#pragma unroll
                for (int e = 0; e < 4; ++e) xa[e] = 0.f;
                mm_core<2, 2, DX>(Xinv, DX, Tp, DX, iS, jS, xa);  // X*T
                float xn[4];
#pragma unroll
                for (int a = 0; a < 2; ++a)
#pragma unroll
                    for (int b = 0; b < 2; ++b)
                        xn[a * 2 + b] = 2.f * Xinv[(iS + a) * DX + (jS + b)] - xa[a * 2 + b];
                __syncthreads();
#pragma unroll
                for (int a = 0; a < 2; ++a)
#pragma unroll
                    for (int b = 0; b < 2; ++b)
                        Xinv[(iS + a) * DX + (jS + b)] = xn[a * 2 + b];
                __syncthreads();
                if (it + 1 < iters) {
                    float ta[4];
#pragma unroll
                    for (int e = 0; e < 4; ++e) ta[e] = 0.f;
                    mm_core<2, 2, DX>(Sp, DX, Xinv, DX, iS, jS, ta);
#pragma unroll
                    for (int a = 0; a < 2; ++a)
#pragma unroll
                        for (int b = 0; b < 2; ++b)
                            Tp[(iS + a) * DX + (jS + b)] = ta[a * 2 + b];
                    __syncthreads();
                }
            }
            // symmetrize X
            float xsym[4];
#pragma unroll
            for (int a = 0; a < 2; ++a)
#pragma unroll
                for (int b = 0; b < 2; ++b)
                    xsym[a * 2 + b] = 0.5f * (Xinv[(iS + a) * DX + (jS + b)] +
                                              Xinv[(jS + b) * DX + (iS + a)]);
            __syncthreads();
#pragma unroll
            for (int a = 0; a < 2; ++a)
#pragma unroll
                for (int b = 0; b < 2; ++b)
                    Xinv[(iS + a) * DX + (jS + b)] = xsym[a * 2 + b];
            __syncthreads();
        }

        // Kgt = Sinv * CP  (64x128) -> Ub[0:8192)
        {
            float kg[8];
#pragma unroll
            for (int e = 0; e < 8; ++e) kg[e] = 0.f;
            mm_core<2, 4, DX>(Xinv, DX, Ub + 8192, DZ, iS, jL, kg);
#pragma unroll
            for (int a = 0; a < 2; ++a)
                *reinterpret_cast<float4*>(&Ub[(iS + a) * DZ + jL]) =
                    make_float4(kg[a * 4 + 0], kg[a * 4 + 1], kg[a * 4 + 2], kg[a * 4 + 3]);
        }
        __syncthreads();

        // mu_u = mu_pr + Kg y   (8 threads per row, shfl reduce)
        {
            const int r = tid >> 3, sg = tid & 7;
            const int m0 = sg * 8;
            float s = 0.f;
#pragma unroll
            for (int m = 0; m < 8; ++m)
                s = fmaf(Ub[(m0 + m) * DZ + r], yv[m0 + m], s);
            s += __shfl_xor(s, 1); s += __shfl_xor(s, 2); s += __shfl_xor(s, 4);
            if (sg == 0) {
                float v = mupr[r] + s;
                muv[r] = v;
                mu_out[(size_t)k * DZ + r] = v;
            }
        }

        // P_u = P_pr - Kg * CP ; symmetrize ; store
        float pa[16];
#pragma unroll
        for (int e = 0; e < 16; ++e) pa[e] = 0.f;
        mm_core<4, 4, DX>(Ub, DZ, Ub + 8192, DZ, iL, jL, pa);
#pragma unroll
        for (int a = 0; a < 4; ++a)
#pragma unroll
            for (int b = 0; b < 4; ++b)
                pa[a * 4 + b] = Pl[(iL + a) * DZ + (jL + b)] - pa[a * 4 + b];
#pragma unroll
        for (int a = 0; a < 4; ++a)
            *reinterpret_cast<float4*>(&Pl[(iL + a) * DZ + jL]) =
                make_float4(pa[0 + a * 4], pa[1 + a * 4], pa[2 + a * 4], pa[3 + a * 4]);
        __syncthreads();
#pragma unroll
        for (int a = 0; a < 4; ++a)
#pragma unroll
            for (int b = 0; b < 4; ++b)
                pa[a * 4 + b] = 0.5f * (pa[a * 4 + b] + Pl[(jL + b) * DZ + (iL + a)]);
        __syncthreads();
        {
            float* po = P_out + (size_t)k * (DZ * DZ);
#pragma unroll
            for (int a = 0; a < 4; ++a) {
                float4 v = make_float4(pa[a * 4 + 0], pa[a * 4 + 1], pa[a * 4 + 2], pa[a * 4 + 3]);
                *reinterpret_cast<float4*>(&Pl[(iL + a) * DZ + jL]) = v;
                *reinterpret_cast<float4*>(&po[(iL + a) * DZ + jL]) = v;
            }
        }
        __syncthreads();
    }

    // persist state for next chunk
    for (int i = tid; i < DZ * DZ; i += 1024) state[i] = Pl[i];
    if (tid < DZ) state[16384 + tid] = muv[tid];
    for (int i = tid; i < DX * DX; i += 1024) state[16512 + i] = Xinv[i];
}

// =====================================================================
// host: gamma coefficients of the RK stability polynomial R(z)=sum g_m z^m
// =====================================================================
static void compute_gamma(double g[7])
{
    const double A[6][5] = {
        {0, 0, 0, 0, 0},
        {0.161, 0, 0, 0, 0},
        {-0.008480655492356989, 0.335480655492357, 0, 0, 0},
        {2.8971530571054935, -6.359448489975075, 4.3622954328695815, 0, 0},
        {5.325864828439257, -11.748883564062828, 7.4955393428898365, -0.09249506636175525, 0},
        {5.86145544294642, -12.92096931784711, 8.159367898576159, -0.071584973281401, -0.028269050394068383}};
    const double B[6] = {0.09646076681806523, 0.01, 0.4798896504144996,
                         1.379008574103742, -3.290069515436081, 2.324710524099774};
    double e[6][6];
    for (int i = 0; i < 6; ++i)
        for (int d = 0; d < 6; ++d) e[i][d] = 0.0;
    for (int i = 0; i < 6; ++i) {
        e[i][0] = 1.0;
        for (int j = 0; j < i; ++j)
            for (int d = 0; d < 5; ++d)
                e[i][d + 1] += A[i][j] * e[j][d];
    }
    g[0] = 1.0;
    for (int m = 1; m <= 6; ++m) {
        double s = 0.0;
        for (int i = 0; i < 6; ++i) s += B[i] * e[i][m - 1];
        g[m] = s;
    }
}

extern "C" void kernel_launch(void* const* d_in, const int* in_sizes, int n_in,
                              void* d_out, int out_size, void* d_ws, size_t ws_size,
                              hipStream_t stream)
{
    const float* xs  = (const float*)d_in[0];
    const float* ts  = (const float*)d_in[1];
    const float* es  = (const float*)d_in[2];
    const float* mu0 = (const float*)d_in[3];
    const float* P0  = (const float*)d_in[4];
    const float* A_s = (const float*)d_in[5];
    const float* b_s = (const float*)d_in[6];
    const float* Qch = (const float*)d_in[7];
    const float* Cm  = (const float*)d_in[8];
    const float* Rm  = (const float*)d_in[9];
    const int T = in_sizes[1];

    float* mu_out = (float*)d_out;
    float* P_out  = mu_out + (size_t)T * DZ;

    float* ws = (float*)d_ws;
    float* Ct    = ws;                 // 8192 floats
    float* state = ws + 8192;          // 20608 floats (P,mu,Sinv)
    float* chunkbase = ws + 28800;
    const long ws_floats = (long)(ws_size / 4);
    long avail = ws_floats - 28800;
    if (avail < 0) avail = 0;
    int mspc = (int)(avail / (2 * DZ * DZ + DZ));
    if (mspc < 1) mspc = 1;
    if (mspc > T - 1 && T > 1) mspc = T - 1;

    double g[7];
    compute_gamma(g);
    const float g1 = (float)g[1], g2 = (float)g[2], g3 = (float)g[3];
    const float g4 = (float)g[4], g5 = (float)g[5], g6 = (float)g[6];

    hipLaunchKernelGGL(kf_prep, dim3(1), dim3(256), 0, stream, Cm, Ct);

    if (T <= 1) {
        hipLaunchKernelGGL(kf_phase2, dim3(1), dim3(1024), 0, stream,
                           xs, chunkbase, chunkbase, chunkbase, Ct, Cm, Rm, mu0, P0,
                           mu_out, P_out, state, 0, T, 1);
        return;
    }

    float* Gb = chunkbase;
    float* Qb = Gb + (size_t)mspc * (DZ * DZ);
    float* cb = Qb + (size_t)mspc * (DZ * DZ);

    int done = 0;
    bool first = true;
    while (done < T - 1) {
        int cs = T - 1 - done;
        if (cs > mspc) cs = mspc;
        const int pred_start = done + 1;
        hipLaunchKernelGGL(kf_phase1, dim3(cs), dim3(256), 0, stream,
                           A_s, b_s, Qch, es, ts, Gb, Qb, cb, pred_start,
                           g1, g2, g3, g4, g5, g6);
        const int k0 = first ? 0 : pred_start;
        const int k1 = pred_start + cs;
        hipLaunchKernelGGL(kf_phase2, dim3(1), dim3(1024), 0, stream,
                           xs, Gb, Qb, cb, Ct, Cm, Rm, mu0, P0,
                           mu_out, P_out, state, k0, k1, pred_start);
        done += cs;
        first = false;
    }
}

// Round 4
// 60426.099 us; speedup vs baseline: 4.7193x; 4.7193x over previous
//
#include <hip/hip_runtime.h>
#include <math.h>

#define DZ 128
#define DX 64
#define KMIX 16
#define JITTER_C 1e-4f
#define MS (DZ*DZ)            // 16384
#define ESZ (4*MS + 2*DZ)     // element: A, At, C, J, b, eta = 65792 floats
#define NCH 128               // chunks
#define LCH 16                // steps per chunk
#define SCN (14*MS + 1024)    // per-chunk scratch floats

// scratch slot offsets (per chunk)
#define S_F   0
#define S_G   (1*MS)
#define S_Q   (2*MS)
#define S_PP  (3*MS)
#define S_E1  (4*MS)
#define S_E3  (5*MS)
#define S_E4  (6*MS)
#define S_T1  (7*MS)
#define S_T2  (8*MS)
#define S_T3  (9*MS)
#define S_EA  (10*MS)
#define S_EAT (11*MS)
#define S_EC  (12*MS)
#define S_EJ  (13*MS)
#define S_VEC (14*MS)

// =====================================================================
// mm: out[MxN] = op( sum_k At[k*M+i] * B[k*N+j] )  i.e. C = (At)^T * B
// MODE 0: store; 1: out += acc; 2: out = aux - acc; 3: out = aux + acc
// 256 threads, 16x16 grid, per-thread tile (M/16)x(N/16).
// =====================================================================
template<int M, int N, int K, int MODE>
__device__ void mm(const float* __restrict__ At, const float* __restrict__ B,
                   float* __restrict__ out, const float* __restrict__ aux)
{
    __syncthreads();
    const int tid = threadIdx.x;
    const int tx = tid & 15, ty = tid >> 4;
    constexpr int TM = M / 16, TN = N / 16;
    const int i0 = ty * TM, j0 = tx * TN;
    float acc[TM * TN];
#pragma unroll
    for (int e = 0; e < TM * TN; ++e) acc[e] = 0.f;
#pragma unroll 2
    for (int k = 0; k < K; ++k) {
        const float* ar = At + k * M + i0;
        const float* br = B + k * N + j0;
        float av[TM], bv[TN];
#pragma unroll
        for (int a = 0; a < TM; a += 4) {
            float4 t = *reinterpret_cast<const float4*>(ar + a);
            av[a] = t.x; av[a+1] = t.y; av[a+2] = t.z; av[a+3] = t.w;
        }
#pragma unroll
        for (int b = 0; b < TN; b += 4) {
            float4 t = *reinterpret_cast<const float4*>(br + b);
            bv[b] = t.x; bv[b+1] = t.y; bv[b+2] = t.z; bv[b+3] = t.w;
        }
#pragma unroll
        for (int a = 0; a < TM; ++a)
#pragma unroll
            for (int b = 0; b < TN; ++b)
                acc[a*TN+b] = fmaf(av[a], bv[b], acc[a*TN+b]);
    }
#pragma unroll
    for (int a = 0; a < TM; ++a) {
#pragma unroll
        for (int b = 0; b < TN; b += 4) {
            const int idx = (i0+a)*N + j0 + b;
            float4 v = make_float4(acc[a*TN+b], acc[a*TN+b+1], acc[a*TN+b+2], acc[a*TN+b+3]);
            if constexpr (MODE == 1) {
                float4 o = *reinterpret_cast<const float4*>(out + idx);
                v.x += o.x; v.y += o.y; v.z += o.z; v.w += o.w;
            } else if constexpr (MODE == 2) {
                float4 o = *reinterpret_cast<const float4*>(aux + idx);
                v.x = o.x - v.x; v.y = o.y - v.y; v.z = o.z - v.z; v.w = o.w - v.w;
            } else if constexpr (MODE == 3) {
                float4 o = *reinterpret_cast<const float4*>(aux + idx);
                v.x += o.x; v.y += o.y; v.z += o.z; v.w += o.w;
            }
            *reinterpret_cast<float4*>(out + idx) = v;
        }
    }
    __syncthreads();
}

// =====================================================================
// mv: out[i] = op(aux[i], sum_k At[k*M+i]*v[k]) for i = tid < M
// MODE 0: sum; 1: aux + sum; 2: aux - sum
// =====================================================================
template<int M, int K, int MODE>
__device__ void mv(const float* __restrict__ At, const float* __restrict__ v,
                   float* __restrict__ out, const float* __restrict__ aux)
{
    __syncthreads();
    const int tid = threadIdx.x;
    if (tid < M) {
        float s = 0.f;
        for (int k = 0; k < K; ++k)
            s = fmaf(At[k*M + tid], v[k], s);
        float r;
        if constexpr (MODE == 0) r = s;
        else if constexpr (MODE == 1) r = aux[tid] + s;
        else r = aux[tid] - s;
        out[tid] = r;
    }
    __syncthreads();
}

// =====================================================================
// trans: dst[NxM] = src[MxN]^T via LDS bounce (Lb >= M*N floats)
// =====================================================================
template<int M, int N>
__device__ void trans(const float* __restrict__ src, float* __restrict__ dst,
                      float* __restrict__ Lb)
{
    __syncthreads();
    for (int e = threadIdx.x; e < M*N; e += 256) Lb[e] = src[e];
    __syncthreads();
    for (int e = threadIdx.x; e < M*N; e += 256) {
        int j = e / M, i = e - j*M;
        dst[e] = Lb[i*N + j];
    }
    __syncthreads();
}

// =====================================================================
// gj_inv: in-place Gauss-Jordan inversion of NxN in LDS with PARTIAL
// PIVOTING (NR gaussj style: row swap during elimination, reverse
// column unscramble at the end). Needed because M = I + C*J (C,J PSD)
// can have near-singular leading minors even though eig(M) >= 1.
// =====================================================================
template<int N>
__device__ void gj_inv(float* __restrict__ A, float* __restrict__ pc, float* __restrict__ pr,
                       int* __restrict__ ipv, int* __restrict__ rec)
{
    __syncthreads();
    const int tid = threadIdx.x;
    for (int p = 0; p < N; ++p) {
        // partial pivot: r = argmax_{i>=p} |A[i][p]|
        if (tid < N) {
            pc[tid] = (tid >= p) ? fabsf(A[tid*N + p]) : -1.f;
            ipv[tid] = tid;
        }
        __syncthreads();
        for (int s = N >> 1; s > 0; s >>= 1) {
            if (tid < s) {
                if (pc[tid + s] > pc[tid]) { pc[tid] = pc[tid + s]; ipv[tid] = ipv[tid + s]; }
            }
            __syncthreads();
        }
        const int r = ipv[0];
        if (tid == 0) rec[p] = r;
        if (r != p) {
            for (int j = tid; j < N; j += 256) {
                float t = A[p*N + j]; A[p*N + j] = A[r*N + j]; A[r*N + j] = t;
            }
        }
        __syncthreads();
        if (tid < N) { pc[tid] = A[tid*N + p]; pr[tid] = A[p*N + tid]; }
        __syncthreads();
        const float rp = 1.f / pr[p];
        for (int e = tid; e < N*N; e += 256) {
            const int i = e / N, j = e - i*N;
            const float pv = pr[j] * rp;
            float o;
            if (i == p) o = (j == p) ? rp : pv;
            else {
                const float fc = pc[i];
                o = (j == p) ? (-fc * rp) : (A[e] - fc * pv);
            }
            A[e] = o;
        }
        __syncthreads();
    }
    // unscramble columns in reverse order
    for (int p = N - 1; p >= 0; --p) {
        const int r = rec[p];
        if (r != p) {
            for (int i = tid; i < N; i += 256) {
                float t = A[i*N + p]; A[i*N + p] = A[i*N + r]; A[i*N + r] = t;
            }
        }
        __syncthreads();
    }
}

// =====================================================================
// phase1_dev: per-step exact RK map: F (f), optionally G=F^T (g),
// Q_eff (q), c (cvec in LDS). Uses L0 (hA^T), L1, pp as ping-pong.
// =====================================================================
__device__ void phase1_dev(int k, const float* __restrict__ A_s, const float* __restrict__ b_s,
                           const float* __restrict__ Qch, const float* __restrict__ es,
                           const float* __restrict__ ts,
                           float* f, float* g, float* q, float* pp,
                           float* L0, float* L1,
                           float* W16, float* ebv, float* eqv, float* vvv, float* cvec,
                           float g1, float g2, float g3, float g4, float g5, float g6,
                           bool wantG)
{
    const int tid = threadIdx.x;
    const int tx = tid & 15, ty = tid >> 4;
    const int i0 = ty * 8, j0 = tx * 8;
    const float h = ts[k] - ts[k-1];
    float gg[7];
    gg[0]=1.f; gg[1]=g1; gg[2]=g2; gg[3]=g3; gg[4]=g4; gg[5]=g5; gg[6]=g6;

    if (h <= 0.f) {
        __syncthreads();
        for (int e = tid; e < MS; e += 256) {
            int i = e >> 7, j = e & 127;
            float v = (i==j) ? 1.f : 0.f;
            f[e] = v; if (wantG) g[e] = v; q[e] = 0.f;
        }
        if (tid < DZ) cvec[tid] = 0.f;
        __syncthreads();
        return;
    }
    __syncthreads();
    if (tid < KMIX) W16[tid] = es[(size_t)k*KMIX + tid];
    __syncthreads();
    if (tid == 0) {
        float s = 0.f;
        for (int m = 0; m < KMIX; ++m) s += W16[m];
        float inv = 1.f / s;
        for (int m = 0; m < KMIX; ++m) W16[m] *= inv;
    }
    __syncthreads();
    if (tid < DZ) {
        float eb = 0.f, eq = 0.f;
        for (int m = 0; m < KMIX; ++m) {
            float wm = W16[m];
            eb = fmaf(wm, b_s[m*DZ + tid], eb);
            float qc = Qch[m*DZ + tid];
            eq = fmaf(wm, qc*qc, eq);
        }
        ebv[tid] = eb; eqv[tid] = eq;
    }
    // hA tiles in regs
    float t64[64];
#pragma unroll
    for (int e = 0; e < 64; ++e) t64[e] = 0.f;
    for (int m = 0; m < KMIX; ++m) {
        float wm = W16[m];
        const float* Am = A_s + (size_t)m * MS;
#pragma unroll
        for (int a = 0; a < 8; ++a) {
            float4 p0 = *reinterpret_cast<const float4*>(&Am[(i0+a)*DZ + j0]);
            float4 p1 = *reinterpret_cast<const float4*>(&Am[(i0+a)*DZ + j0 + 4]);
            t64[a*8+0]=fmaf(wm,p0.x,t64[a*8+0]); t64[a*8+1]=fmaf(wm,p0.y,t64[a*8+1]);
            t64[a*8+2]=fmaf(wm,p0.z,t64[a*8+2]); t64[a*8+3]=fmaf(wm,p0.w,t64[a*8+3]);
            t64[a*8+4]=fmaf(wm,p1.x,t64[a*8+4]); t64[a*8+5]=fmaf(wm,p1.y,t64[a*8+5]);
            t64[a*8+6]=fmaf(wm,p1.z,t64[a*8+6]); t64[a*8+7]=fmaf(wm,p1.w,t64[a*8+7]);
        }
    }
#pragma unroll
    for (int a = 0; a < 8; ++a)
#pragma unroll
        for (int b = 0; b < 8; ++b) {
            float v = h * t64[a*8+b];
            L1[(i0+a)*DZ + (j0+b)] = v;          // hA
            L0[(j0+b)*DZ + (i0+a)] = v;          // hA^T
            f[(i0+a)*DZ + (j0+b)] = (((i0+a)==(j0+b)) ? 1.f : 0.f) + g1 * v;
        }
    __syncthreads();
    // F = sum g[m] (hA)^m
    {
        float* src = L1; float* dst = pp;
        for (int m = 2; m <= 6; ++m) {
            mm<128,128,128,0>(L0, src, dst, nullptr);
            float gm = gg[m];
            for (int e = tid; e < MS; e += 256) f[e] = fmaf(gm, dst[e], f[e]);
            float* t = src; src = dst; dst = t;
        }
    }
    __syncthreads();
    // Q = h * sum_{m=0..5} g[m+1] Y_m,  Y_{m+1} = hA*Y + (hA*Y)^T
    for (int e = tid; e < MS; e += 256) {
        int i = e >> 7, j = e & 127;
        float y0 = (i==j) ? eqv[i] : 0.f;
        L1[e] = y0; q[e] = g1 * y0;
    }
    __syncthreads();
    for (int m = 1; m <= 5; ++m) {
        mm<128,128,128,0>(L0, L1, pp, nullptr);
        float gm = gg[m+1];
        for (int e = tid; e < MS; e += 256) {
            int i = e >> 7, j = e & 127;
            float tmp = pp[e] + pp[j*DZ + i];
            L1[e] = tmp;
            q[e] = fmaf(gm, tmp, q[e]);
        }
        __syncthreads();
    }
    for (int e = tid; e < MS; e += 256) q[e] *= h;
    // cvec = h * sum g[m+1] (hA)^m eb
    if (tid < DZ) vvv[tid] = ebv[tid];
    float creg = (tid < DZ) ? g1 * ebv[tid] : 0.f;
    __syncthreads();
    for (int m = 1; m <= 5; ++m) {
        float vn = 0.f;
        if (tid < DZ)
            for (int kk = 0; kk < DZ; ++kk)
                vn = fmaf(L0[kk*DZ + tid], vvv[kk], vn);
        __syncthreads();
        if (tid < DZ) vvv[tid] = vn;
        creg = fmaf(gg[m+1], vn, creg);
        __syncthreads();
    }
    if (tid < DZ) cvec[tid] = h * creg;
    __syncthreads();
    if (wantG) trans<128,128>(f, g, L1);
    __syncthreads();
}

// =====================================================================
// elem_build: step element E=(A,At,C,J,b,eta) from (F,Q,c,x_k)
//   S = C Q C^T + R~ ; Kq = Q C^T S^-1
//   EA = (I-Kq C)F ; EC = (I-Kq C)Q ; Eb = c + Kq r ; Eh = F^T C^T Si r
//   EJ = F^T C^T Si C F ;  r = x - C c
// =====================================================================
__device__ void elem_build(int k, const float* __restrict__ xs, const float* __restrict__ Ct,
                           const float* __restrict__ Rj,
                           const float* f, const float* q,
                           float* e1, float* e3, float* e4, float* zt,
                           float* EA, float* EAt, float* EC, float* EJ,
                           float* Ebg, float* Ehg,
                           float* L1, float* SL, float* cvec, float* r64, float* u64,
                           float* GJc, float* GJr, int* IPV, int* REC)
{
    mm<64,128,128,0>(Ct, q, e1, nullptr);               // e1 = C*Q (64x128)
    trans<64,128>(e1, zt, L1);                          // zt = Q*C^T (128x64)
    mm<64,64,128,3>(zt, Ct, SL, Rj);                    // S = C Q C^T + R~
    gj_inv<64>(SL, GJc, GJr, IPV, REC);                 // SL = S^-1
    mm<64,128,64,0>(SL, e1, e4, nullptr);               // e4 = Kq^T = Si*CQ
    mm<64,128,128,0>(Ct, f, e3, nullptr);               // e3 = W = C*F
    mm<128,128,64,2>(e4, e3, EA, f);                    // EA = F - Kq*W
    mm<128,128,64,2>(e4, e1, EC, q);                    // EC = Q - Kq*CQ
    trans<128,128>(EA, EAt, L1);
    mv<64,128,2>(Ct, cvec, r64, xs + (size_t)k*DX);     // r = x - C*c
    mv<64,64,0>(SL, r64, u64, nullptr);                 // u = Si*r
    mv<128,64,1>(e4, r64, Ebg, cvec);                   // Eb = c + Kq*r   (FIXED: r, not u)
    mv<128,64,0>(e3, u64, Ehg, nullptr);                // Eh = W^T u = F^T C^T Si r
    mm<64,128,64,0>(SL, e3, e1, nullptr);               // e1 = Si*W
    mm<128,128,64,0>(e3, e1, EJ, nullptr);              // EJ = W^T Si W
}

// =====================================================================
// combine: R <- R (earlier) (x) E (later)     [Sarkka filtering operator]
// M = I + RC*EJ ; built transposed: Mt = I + EJ*RC, GJ -> M^-T in L0.
// =====================================================================
__device__ void combine(float* R,
                        const float* EA, const float* EAt, const float* EC,
                        const float* EJ, const float* Ebg, const float* Ehg,
                        float* t1, float* t2, float* t3,
                        float* L0, float* L1,
                        float* V0, float* V1, float* V2, float* V3, float* V4, float* V5,
                        float* GJc, float* GJr, int* IPV, int* REC)
{
    float* RA = R;  float* RAt = R + MS;  float* RC = R + 2*MS;  float* RJ = R + 3*MS;
    float* Rb = R + 4*MS;  float* Rh = R + 4*MS + DZ;
    const int tid = threadIdx.x;
    __syncthreads();
    if (tid < DZ) { V0[tid] = Ebg[tid]; V1[tid] = Ehg[tid]; V2[tid] = Rb[tid]; }
    mm<128,128,128,0>(EJ, RC, L0, nullptr);             // L0 = EJ*RC
    if (tid < DZ) L0[tid*DZ + tid] += 1.f;              // L0 = M^T
    gj_inv<128>(L0, GJc, GJr, IPV, REC);                // L0 = M^-T
    mm<128,128,128,0>(L0, RA, t1, nullptr);             // t1 = Minv*RA
    mm<128,128,128,0>(EJ, RA, t2, nullptr);             // t2 = EJ*RA
    mm<128,128,128,1>(t1, t2, RJ, nullptr);             // RJ += t1^T t2
    mv<128,128,1>(RC, V1, V3, V2);                      // v1 = Rb + RC*Eh
    mv<128,128,2>(EJ, V2, V4, V1);                      // w1 = Eh - EJ*Rb
    mv<128,128,1>(t1, V4, Rh, Rh);                      // Rh += t1^T w1
    mv<128,128,0>(L0, V3, V5, nullptr);                 // z1 = Minv*v1
    mv<128,128,1>(EAt, V5, Rb, V0);                     // Rb = Eb + EA*z1
    mm<128,128,128,0>(L0, RC, t3, nullptr);             // t3 = Minv*RC
    mm<128,128,128,0>(t3, EAt, t2, nullptr);            // t2 = t3^T*EA^T
    mm<128,128,128,3>(EAt, t2, RC, EC);                 // RC = EA*t2 + EC
    mm<128,128,128,0>(EAt, t1, RA, nullptr);            // RA = EA*t1
    trans<128,128>(RA, RAt, L1);
}

__device__ void elem_from_parts(float* R, const float* EA, const float* EAt,
                                const float* EC, const float* EJ,
                                const float* Ebg, const float* Ehg)
{
    __syncthreads();
    for (int e = threadIdx.x; e < MS; e += 256) {
        R[e] = EA[e]; R[MS+e] = EAt[e]; R[2*MS+e] = EC[e]; R[3*MS+e] = EJ[e];
    }
    if (threadIdx.x < DZ) {
        R[4*MS + threadIdx.x] = Ebg[threadIdx.x];
        R[4*MS + DZ + threadIdx.x] = Ehg[threadIdx.x];
    }
    __syncthreads();
}

#define SHARED_DECLS \
    __shared__ __align__(16) float L0[MS]; \
    __shared__ __align__(16) float L1[MS]; \
    __shared__ __align__(16) float SL[DX*DX]; \
    __shared__ float V0[DZ],V1[DZ],V2[DZ],V3[DZ],V4[DZ],V5[DZ]; \
    __shared__ float R64[DX], U64[DX], W16[KMIX], GJc[DZ], GJr[DZ]; \
    __shared__ int IPV[DZ], REC[DZ];

// =====================================================================
// prep: Ct, Rj, and initial updated state (mu0u, p0u)
// =====================================================================
__global__ __launch_bounds__(256) void kf_prep(
    const float* __restrict__ Cm, const float* __restrict__ Rm,
    const float* __restrict__ mu0, const float* __restrict__ P0,
    const float* __restrict__ xs,
    float* Ct, float* Rj, float* mu0u, float* p0u, float* scr)
{
    SHARED_DECLS
    const int tid = threadIdx.x;
    for (int i = tid; i < DZ*DX; i += 256) { int z = i >> 6, m = i & 63; Ct[i] = Cm[m*DZ + z]; }
    for (int i = tid; i < DX*DX; i += 256) { int a = i >> 6, b = i & 63; Rj[i] = Rm[i] + ((a==b) ? JITTER_C : 0.f); }
    if (tid < DZ) V0[tid] = mu0[tid];
    float* zt = scr + S_T1; float* cp = scr + S_T2; float* kt = scr + S_T3;
    mm<128,64,128,0>(P0, Ct, zt, nullptr);              // Zt0 = P0*C^T
    trans<128,64>(zt, cp, L1);                          // CP0
    mm<64,64,128,3>(zt, Ct, SL, Rj);                    // S0
    gj_inv<64>(SL, GJc, GJr, IPV, REC);
    mm<64,128,64,0>(SL, cp, kt, nullptr);               // K0^T = Si*CP0
    mv<64,128,2>(Ct, V0, R64, xs);                      // r = x0 - C mu0
    mv<128,64,1>(kt, R64, mu0u, V0);                    // mu0u = mu0 + K0*r   (FIXED: r)
    mm<128,128,64,2>(kt, cp, p0u, P0);                  // P0u = P0 - K0*CP0
    __syncthreads();
    for (int e = tid; e < MS; e += 256) L1[e] = p0u[e];
    __syncthreads();
    for (int e = tid; e < MS; e += 256) {
        int i = e >> 7, j = e & 127;
        p0u[e] = 0.5f * (L1[e] + L1[j*DZ + i]);
    }
}

// =====================================================================
// pass A: per chunk, fuse phase1 + element build + sequential compose
// =====================================================================
__global__ __launch_bounds__(256) void kf_passA(
    const float* __restrict__ A_s, const float* __restrict__ b_s,
    const float* __restrict__ Qch, const float* __restrict__ es,
    const float* __restrict__ ts, const float* __restrict__ xs,
    const float* __restrict__ Ct, const float* __restrict__ Rj,
    const float* __restrict__ mu0u, const float* __restrict__ p0u,
    float* elems, float* scr, int T,
    float g1, float g2, float g3, float g4, float g5, float g6)
{
    SHARED_DECLS
    const int c = blockIdx.x;
    const int tid = threadIdx.x;
    float* sc = scr + (size_t)c * SCN;
    float* R  = elems + (size_t)c * ESZ;
    float* f = sc+S_F;  float* g = sc+S_G;  float* q = sc+S_Q;  float* pp = sc+S_PP;
    float* e1 = sc+S_E1; float* e3 = sc+S_E3; float* e4 = sc+S_E4;
    float* t1 = sc+S_T1; float* t2 = sc+S_T2; float* t3 = sc+S_T3;
    float* EA = sc+S_EA; float* EAt = sc+S_EAT; float* EC = sc+S_EC; float* EJ = sc+S_EJ;
    float* Ebg = sc+S_VEC; float* Ehg = sc+S_VEC+DZ;

    int eBeg = c * LCH;
    int eEnd = min(T, eBeg + LCH);
    bool have = false;
    if (c == 0) {
        for (int e = tid; e < MS; e += 256) {
            R[e] = 0.f; R[MS+e] = 0.f; R[2*MS+e] = p0u[e]; R[3*MS+e] = 0.f;
        }
        if (tid < DZ) { R[4*MS+tid] = mu0u[tid]; R[4*MS+DZ+tid] = 0.f; }
        have = true;
        eBeg = 1;
    }
    __syncthreads();
    for (int e = eBeg; e < eEnd; ++e) {
        phase1_dev(e, A_s,b_s,Qch,es,ts, f,g,q,pp, L0,L1, W16, V4,V5,V2,V3,
                   g1,g2,g3,g4,g5,g6, false);
        elem_build(e, xs, Ct, Rj, f, q, e1,e3,e4, t1, EA,EAt,EC,EJ, Ebg,Ehg,
                   L1, SL, V3, R64, U64, GJc, GJr, IPV, REC);
        if (!have) { elem_from_parts(R, EA,EAt,EC,EJ,Ebg,Ehg); have = true; }
        else combine(R, EA,EAt,EC,EJ,Ebg,Ehg, t1,t2,t3, L0,L1,
                     V0,V1,V2,V3,V4,V5, GJc,GJr, IPV,REC);
    }
    if (!have) {    // empty chunk (only if T < NCH*LCH): identity element
        for (int e = tid; e < MS; e += 256) {
            int i = e >> 7, j = e & 127; float id = (i==j) ? 1.f : 0.f;
            R[e] = id; R[MS+e] = id; R[2*MS+e] = 0.f; R[3*MS+e] = 0.f;
        }
        if (tid < DZ) { R[4*MS+tid] = 0.f; R[4*MS+DZ+tid] = 0.f; }
    }
}

// =====================================================================
// Kogge-Stone scan round: out[c] = in[c-r] (x) in[c]   (c >= r), else copy
// =====================================================================
__global__ __launch_bounds__(256) void kf_scan(
    const float* __restrict__ in, float* __restrict__ out, float* scr, int r)
{
    SHARED_DECLS
    const int c = blockIdx.x;
    float* sc = scr + (size_t)c * SCN;
    float* dst = out + (size_t)c * ESZ;
    const float* src = in + (size_t)((c >= r) ? (c - r) : c) * ESZ;
    __syncthreads();
    for (int e = threadIdx.x; e < ESZ; e += 256) dst[e] = src[e];
    __syncthreads();
    if (c >= r) {
        const float* E = in + (size_t)c * ESZ;
        combine(dst, E, E+MS, E+2*MS, E+3*MS, E+4*MS, E+4*MS+DZ,
                sc+S_T1, sc+S_T2, sc+S_T3, L0, L1,
                V0,V1,V2,V3,V4,V5, GJc, GJr, IPV, REC);
    }
}

// =====================================================================
// pass C: per chunk, plain filter from exact boundary state; writes outputs
// =====================================================================
__global__ __launch_bounds__(256) void kf_passC(
    const float* __restrict__ A_s, const float* __restrict__ b_s,
    const float* __restrict__ Qch, const float* __restrict__ es,
    const float* __restrict__ ts, const float* __restrict__ xs,
    const float* __restrict__ Ct, const float* __restrict__ Rj,
    const float* __restrict__ mu0u, const float* __restrict__ p0u,
    const float* __restrict__ pfx,
    float* mu_out, float* P_out, float* scr, int T,
    float g1, float g2, float g3, float g4, float g5, float g6)
{
    SHARED_DECLS
    const int c = blockIdx.x;
    const int tid = threadIdx.x;
    float* sc = scr + (size_t)c * SCN;
    float* f = sc+S_F;  float* g = sc+S_G;  float* q = sc+S_Q;  float* pp = sc+S_PP;
    float* P  = sc+S_E1; float* P2 = sc+S_E3; float* U = sc+S_E4;
    float* zt = sc+S_T1; float* cp = sc+S_T2; float* kt = sc+S_T3;

    if (c == 0) {
        for (int e = tid; e < MS; e += 256) { float v = p0u[e]; P[e] = v; P_out[e] = v; }
        if (tid < DZ) { V0[tid] = mu0u[tid]; mu_out[tid] = mu0u[tid]; }
    } else {
        const float* X = pfx + (size_t)(c-1) * ESZ;
        for (int e = tid; e < MS; e += 256) P[e] = X[2*MS + e];
        if (tid < DZ) V0[tid] = X[4*MS + tid];
    }
    __syncthreads();
    const int eBeg = max(1, c * LCH);
    const int eEnd = min(T, c * LCH + LCH);
    for (int e = eBeg; e < eEnd; ++e) {
        phase1_dev(e, A_s,b_s,Qch,es,ts, f,g,q,pp, L0,L1, W16, V4,V5,V2,V3,
                   g1,g2,g3,g4,g5,g6, true);
        mm<128,128,128,0>(P, g, U, nullptr);            // U = P*F^T
        mm<128,128,128,3>(g, U, P2, q);                 // Ppr = F*U + Q
        mv<128,128,1>(g, V0, V1, V3);                   // mupr = F*mu + c
        mm<128,64,128,0>(P2, Ct, zt, nullptr);          // Zt = Ppr*C^T
        trans<128,64>(zt, cp, L1);                      // CP
        mm<64,64,128,3>(zt, Ct, SL, Rj);                // S
        gj_inv<64>(SL, GJc, GJr, IPV, REC);
        mm<64,128,64,0>(SL, cp, kt, nullptr);           // K^T = Si*CP
        mv<64,128,2>(Ct, V1, R64, xs + (size_t)e*DX);   // y = x - C*mupr
        mv<128,64,1>(kt, R64, V0, V1);                  // mu = mupr + K*y
        if (tid < DZ) mu_out[(size_t)e*DZ + tid] = V0[tid];
        mm<128,128,64,2>(kt, cp, U, P2);                // U = Ppr - K*CP
        __syncthreads();
        float* po = P_out + (size_t)e * MS;
        for (int ee = tid; ee < MS; ee += 256) {
            int i = ee >> 7, j = ee & 127;
            float v = 0.5f * (U[ee] + U[j*DZ + i]);
            P[ee] = v; po[ee] = v;
        }
        __syncthreads();
    }
}

// =====================================================================
// host: RK stability polynomial coefficients
// =====================================================================
static void compute_gamma(double g[7])
{
    const double A[6][5] = {
        {0, 0, 0, 0, 0},
        {0.161, 0, 0, 0, 0},
        {-0.008480655492356989, 0.335480655492357, 0, 0, 0},
        {2.8971530571054935, -6.359448489975075, 4.3622954328695815, 0, 0},
        {5.325864828439257, -11.748883564062828, 7.4955393428898365, -0.09249506636175525, 0},
        {5.86145544294642, -12.92096931784711, 8.159367898576159, -0.071584973281401, -0.028269050394068383}};
    const double B[6] = {0.09646076681806523, 0.01, 0.4798896504144996,
                         1.379008574103742, -3.290069515436081, 2.324710524099774};
    double e[6][6];
    for (int i = 0; i < 6; ++i)
        for (int d = 0; d < 6; ++d) e[i][d] = 0.0;
    for (int i = 0; i < 6; ++i) {
        e[i][0] = 1.0;
        for (int j = 0; j < i; ++j)
            for (int d = 0; d < 5; ++d)
                e[i][d + 1] += A[i][j] * e[j][d];
    }
    g[0] = 1.0;
    for (int m = 1; m <= 6; ++m) {
        double s = 0.0;
        for (int i = 0; i < 6; ++i) s += B[i] * e[i][m - 1];
        g[m] = s;
    }
}

extern "C" void kernel_launch(void* const* d_in, const int* in_sizes, int n_in,
                              void* d_out, int out_size, void* d_ws, size_t ws_size,
                              hipStream_t stream)
{
    const float* xs  = (const float*)d_in[0];
    const float* ts  = (const float*)d_in[1];
    const float* es  = (const float*)d_in[2];
    const float* mu0 = (const float*)d_in[3];
    const float* P0  = (const float*)d_in[4];
    const float* A_s = (const float*)d_in[5];
    const float* b_s = (const float*)d_in[6];
    const float* Qch = (const float*)d_in[7];
    const float* Cm  = (const float*)d_in[8];
    const float* Rm  = (const float*)d_in[9];
    const int T = in_sizes[1];

    float* mu_out = (float*)d_out;
    float* P_out  = mu_out + (size_t)T * DZ;

    float* ws = (float*)d_ws;
    float* Ct    = ws;                       // 8192
    float* Rj    = ws + 8192;                // 4096
    float* mu0u  = ws + 12288;               // 128
    float* p0u   = ws + 12416;               // 16384
    float* elemsA = ws + 28800;
    float* elemsB = elemsA + (size_t)NCH * ESZ;
    float* scr    = elemsB + (size_t)NCH * ESZ;

    double g[7];
    compute_gamma(g);
    const float g1 = (float)g[1], g2 = (float)g[2], g3 = (float)g[3];
    const float g4 = (float)g[4], g5 = (float)g[5], g6 = (float)g[6];

    hipLaunchKernelGGL(kf_prep, dim3(1), dim3(256), 0, stream,
                       Cm, Rm, mu0, P0, xs, Ct, Rj, mu0u, p0u, scr);
    hipLaunchKernelGGL(kf_passA, dim3(NCH), dim3(256), 0, stream,
                       A_s, b_s, Qch, es, ts, xs, Ct, Rj, mu0u, p0u,
                       elemsA, scr, T, g1, g2, g3, g4, g5, g6);
    float* bufs[2] = {elemsA, elemsB};
    int cur = 0;
    for (int r = 1; r < NCH; r <<= 1) {
        hipLaunchKernelGGL(kf_scan, dim3(NCH), dim3(256), 0, stream,
                           bufs[cur], bufs[cur ^ 1], scr, r);
        cur ^= 1;
    }
    hipLaunchKernelGGL(kf_passC, dim3(NCH), dim3(256), 0, stream,
                       A_s, b_s, Qch, es, ts, xs, Ct, Rj, mu0u, p0u,
                       bufs[cur], mu_out, P_out, scr, T, g1, g2, g3, g4, g5, g6);
}

// Round 5
// 20113.741 us; speedup vs baseline: 14.1779x; 3.0042x over previous
//
#include <hip/hip_runtime.h>
#include <math.h>

#define DZ 128
#define DX 64
#define KMIX 16
#define JITTER_C 1e-4f
#define MS (DZ*DZ)            // 16384
#define ESZ (4*MS + 2*DZ)     // element: A, At, C, J, b, eta
#define NCH 256               // chunks
#define SCN (7*MS + 256)      // per-chunk scratch floats

// scr slot offsets (per chunk)
#define SP   0
#define SX   (1*MS)
#define SX2  (2*MS)
#define SX2T (3*MS)
#define SX3  (4*MS)
#define SX3T (5*MS)
#define SQ   (6*MS)

// =====================================================================
// mm_: out[MxN] = op( sum_k At[k*M+i] * B[k*N+j] )  i.e. out = (At)^T*B
// MODE 0: store; 1: out += acc; 2: out = aux - acc; 3: out = aux + acc
// DUAL: additionally store transposed result to outT (N x M).
// 256 threads, 16x16 grid, per-thread tile (M/16)x(N/16).
// =====================================================================
template<int M, int N, int K, int MODE, bool DUAL>
__device__ void mm_(const float* __restrict__ At, const float* __restrict__ B,
                    float* __restrict__ out, const float* __restrict__ aux,
                    float* __restrict__ outT)
{
    __syncthreads();
    const int tid = threadIdx.x;
    constexpr int TM = M/16, TN = N/16;
    const int tx = tid & 15, ty = tid >> 4;
    const int i0 = ty*TM, j0 = tx*TN;
    float acc[TM*TN];
#pragma unroll
    for (int e = 0; e < TM*TN; ++e) acc[e] = 0.f;
#pragma unroll 4
    for (int k = 0; k < K; ++k) {
        const float* ar = At + k*M + i0;
        const float* br = B + k*N + j0;
        float av[TM], bv[TN];
#pragma unroll
        for (int a = 0; a < TM; a += 4) {
            float4 t = *reinterpret_cast<const float4*>(ar + a);
            av[a]=t.x; av[a+1]=t.y; av[a+2]=t.z; av[a+3]=t.w;
        }
#pragma unroll
        for (int b = 0; b < TN; b += 4) {
            float4 t = *reinterpret_cast<const float4*>(br + b);
            bv[b]=t.x; bv[b+1]=t.y; bv[b+2]=t.z; bv[b+3]=t.w;
        }
#pragma unroll
        for (int a = 0; a < TM; ++a)
#pragma unroll
            for (int b = 0; b < TN; ++b)
                acc[a*TN+b] = fmaf(av[a], bv[b], acc[a*TN+b]);
    }
#pragma unroll
    for (int a = 0; a < TM; ++a) {
#pragma unroll
        for (int b = 0; b < TN; b += 4) {
            const int idx = (i0+a)*N + j0 + b;
            float4 v = make_float4(acc[a*TN+b], acc[a*TN+b+1], acc[a*TN+b+2], acc[a*TN+b+3]);
            if constexpr (MODE == 1) { float4 o = *reinterpret_cast<const float4*>(out+idx); v.x+=o.x; v.y+=o.y; v.z+=o.z; v.w+=o.w; }
            else if constexpr (MODE == 2) { float4 o = *reinterpret_cast<const float4*>(aux+idx); v.x=o.x-v.x; v.y=o.y-v.y; v.z=o.z-v.z; v.w=o.w-v.w; }
            else if constexpr (MODE == 3) { float4 o = *reinterpret_cast<const float4*>(aux+idx); v.x+=o.x; v.y+=o.y; v.z+=o.z; v.w+=o.w; }
            *reinterpret_cast<float4*>(out+idx) = v;
            acc[a*TN+b]=v.x; acc[a*TN+b+1]=v.y; acc[a*TN+b+2]=v.z; acc[a*TN+b+3]=v.w;
        }
    }
    if constexpr (DUAL) {
#pragma unroll
        for (int b = 0; b < TN; ++b) {
#pragma unroll
            for (int a = 0; a < TM; a += 4) {
                float4 v = make_float4(acc[(a)*TN+b], acc[(a+1)*TN+b], acc[(a+2)*TN+b], acc[(a+3)*TN+b]);
                *reinterpret_cast<float4*>(outT + (j0+b)*M + i0 + a) = v;
            }
        }
    }
    __syncthreads();
}

// =====================================================================
// mv_: out[i] = op(aux[i], sum_k At[k*M+i]*v[k]) for i = tid < M
// MODE 0: sum; 1: aux + sum; 2: aux - sum
// =====================================================================
template<int M, int K, int MODE>
__device__ void mv_(const float* __restrict__ At, const float* __restrict__ v,
                    float* __restrict__ out, const float* __restrict__ aux)
{
    __syncthreads();
    const int tid = threadIdx.x;
    if (tid < M) {
        float s = 0.f;
        for (int k = 0; k < K; ++k)
            s = fmaf(At[k*M + tid], v[k], s);
        float r;
        if constexpr (MODE == 0) r = s;
        else if constexpr (MODE == 1) r = aux[tid] + s;
        else r = aux[tid] - s;
        out[tid] = r;
    }
    __syncthreads();
}

// dst[NxM] = src[MxN]^T via LDS bounce (128x128 only)
__device__ void trans_g(const float* __restrict__ src, float* __restrict__ dst,
                        float* __restrict__ Lb)
{
    __syncthreads();
    for (int e = threadIdx.x; e < MS; e += 256) Lb[e] = src[e];
    __syncthreads();
    for (int e = threadIdx.x; e < MS; e += 256) {
        int j = e >> 7, i = e & 127;
        dst[e] = Lb[i*DZ + j];
    }
    __syncthreads();
}

// =====================================================================
// gj64_spd: unpivoted in-place Gauss-Jordan of SPD 64x64 in LDS.
// Safe: used only on S-matrices with lambda_min >= 0.1.
// =====================================================================
__device__ void gj64_spd(float* __restrict__ A, float* __restrict__ pc, float* __restrict__ pr)
{
    __syncthreads();
    const int tid = threadIdx.x;
    for (int p = 0; p < DX; ++p) {
        if (tid < DX) { pc[tid] = A[tid*DX + p]; pr[tid] = A[p*DX + tid]; }
        __syncthreads();
        const float rp = 1.f / pr[p];
        for (int e = tid; e < DX*DX; e += 256) {
            const int i = e >> 6, j = e & 63;
            const float pv = pr[j] * rp;
            float o;
            if (i == p) o = (j == p) ? rp : pv;
            else { const float fc = pc[i]; o = (j == p) ? (-fc*rp) : (A[e] - fc*pv); }
            A[e] = o;
        }
        __syncthreads();
    }
}

// =====================================================================
// gj128_piv: partial-pivoted GJ of 128x128 in LDS; wave-0 shfl argmax.
// =====================================================================
__device__ void gj128_piv(float* __restrict__ A, float* __restrict__ pc, float* __restrict__ pr,
                          int* __restrict__ rec, int* __restrict__ ipv1)
{
    __syncthreads();
    const int tid = threadIdx.x;
    for (int p = 0; p < DZ; ++p) {
        if (tid < 64) {
            float best = -1.f; int bi = p;
            for (int i = tid; i < DZ; i += 64) {
                float v = (i >= p) ? fabsf(A[i*DZ + p]) : -2.f;
                if (v > best) { best = v; bi = i; }
            }
            for (int off = 32; off > 0; off >>= 1) {
                float ob = __shfl_xor(best, off);
                int obi = __shfl_xor(bi, off);
                if (ob > best) { best = ob; bi = obi; }
            }
            if (tid == 0) { rec[p] = bi; ipv1[0] = bi; }
        }
        __syncthreads();
        const int r = ipv1[0];
        if (r != p) {
            for (int j = tid; j < DZ; j += 256) { float t = A[p*DZ+j]; A[p*DZ+j] = A[r*DZ+j]; A[r*DZ+j] = t; }
            __syncthreads();
        }
        if (tid < DZ) { pc[tid] = A[tid*DZ + p]; pr[tid] = A[p*DZ + tid]; }
        __syncthreads();
        const float rp = 1.f / pr[p];
        for (int e = tid; e < MS; e += 256) {
            const int i = e >> 7, j = e & 127;
            const float pv = pr[j] * rp;
            float o;
            if (i == p) o = (j == p) ? rp : pv;
            else { const float fc = pc[i]; o = (j == p) ? (-fc*rp) : (A[e] - fc*pv); }
            A[e] = o;
        }
        __syncthreads();
    }
    for (int p = DZ - 1; p >= 0; --p) {
        const int r = rec[p];
        if (r != p) {
            for (int i = tid; i < DZ; i += 256) { float t = A[i*DZ+p]; A[i*DZ+p] = A[i*DZ+r]; A[i*DZ+r] = t; }
            __syncthreads();
        }
    }
    __syncthreads();
}

// =====================================================================
// phase1_dev: exact RK step map via Paterson-Stockmeyer + truncated
// Lyapunov series. Produces L1 = F^T (LDS), sq = Q_eff, cvec = c.
// =====================================================================
__device__ void phase1_dev(int k,
    const float* __restrict__ A_s, const float* __restrict__ b_s,
    const float* __restrict__ Qch, const float* __restrict__ es, const float* __restrict__ ts,
    float* sx, float* sx2, float* sx2t, float* sx3, float* sx3t, float* sq,
    float* L0, float* L1,
    float* W16, float* ebv, float* eqv, float* vvv, float* cvec,
    float g1, float g2, float g3, float g4, float g5, float g6)
{
    const int tid = threadIdx.x;
    const float h = ts[k] - ts[k-1];
    if (h <= 0.f) {
        __syncthreads();
        for (int e = tid; e < MS; e += 256) {
            int i = e >> 7, j = e & 127;
            L1[e] = (i==j) ? 1.f : 0.f;
            sq[e] = 0.f;
        }
        if (tid < DZ) cvec[tid] = 0.f;
        __syncthreads();
        return;
    }
    __syncthreads();
    if (tid < KMIX) W16[tid] = es[(size_t)k*KMIX + tid];
    __syncthreads();
    if (tid == 0) {
        float s = 0.f;
        for (int m = 0; m < KMIX; ++m) s += W16[m];
        float inv = 1.f/s;
        for (int m = 0; m < KMIX; ++m) W16[m] *= inv;
    }
    __syncthreads();
    if (tid < DZ) {
        float eb = 0.f, eq = 0.f;
        for (int m = 0; m < KMIX; ++m) {
            float wm = W16[m];
            eb = fmaf(wm, b_s[m*DZ+tid], eb);
            float qc = Qch[m*DZ+tid];
            eq = fmaf(wm, qc*qc, eq);
        }
        ebv[tid] = eb; eqv[tid] = eq;
    }
    // X = h * sum_m w_m A_s[m]; write X (L1 + sx) and Xt (L0)
    const int tx = tid & 15, ty = tid >> 4;
    const int i0 = ty*8, j0 = tx*8;
    float t64[64];
#pragma unroll
    for (int e = 0; e < 64; ++e) t64[e] = 0.f;
    for (int m = 0; m < KMIX; ++m) {
        float wm = W16[m];
        const float* Am = A_s + (size_t)m * MS;
#pragma unroll
        for (int a = 0; a < 8; ++a) {
            float4 p0 = *reinterpret_cast<const float4*>(&Am[(i0+a)*DZ + j0]);
            float4 p1 = *reinterpret_cast<const float4*>(&Am[(i0+a)*DZ + j0 + 4]);
            t64[a*8+0]=fmaf(wm,p0.x,t64[a*8+0]); t64[a*8+1]=fmaf(wm,p0.y,t64[a*8+1]);
            t64[a*8+2]=fmaf(wm,p0.z,t64[a*8+2]); t64[a*8+3]=fmaf(wm,p0.w,t64[a*8+3]);
            t64[a*8+4]=fmaf(wm,p1.x,t64[a*8+4]); t64[a*8+5]=fmaf(wm,p1.y,t64[a*8+5]);
            t64[a*8+6]=fmaf(wm,p1.z,t64[a*8+6]); t64[a*8+7]=fmaf(wm,p1.w,t64[a*8+7]);
        }
    }
#pragma unroll
    for (int a = 0; a < 8; ++a)
#pragma unroll
        for (int b = 0; b < 8; ++b) {
            float v = h * t64[a*8+b];
            L1[(i0+a)*DZ + (j0+b)] = v;
            sx[(i0+a)*DZ + (j0+b)] = v;
            L0[(j0+b)*DZ + (i0+a)] = v;
        }
    __syncthreads();
    // cvec = h * sum_{m=0..5} g[m+1] X^m eb   (uses L0 = Xt)
    {
        float gg[7]; gg[1]=g1; gg[2]=g2; gg[3]=g3; gg[4]=g4; gg[5]=g5; gg[6]=g6;
        if (tid < DZ) vvv[tid] = ebv[tid];
        float creg = (tid < DZ) ? g1 * ebv[tid] : 0.f;
        __syncthreads();
        for (int m = 1; m <= 5; ++m) {
            float vn = 0.f;
            if (tid < DZ)
                for (int kk = 0; kk < DZ; ++kk)
                    vn = fmaf(L0[kk*DZ + tid], vvv[kk], vn);
            __syncthreads();
            if (tid < DZ) vvv[tid] = vn;
            creg = fmaf(gg[m+1], vn, creg);
            __syncthreads();
        }
        if (tid < DZ) cvec[tid] = h * creg;
    }
    // X2, X3 (dual-stored)
    mm_<128,128,128,0,true>(L0, L1, sx2, nullptr, sx2t);
    mm_<128,128,128,0,true>(L0, sx2, sx3, nullptr, sx3t);
    // L1 := Gt * sqrt(D),  G = X + alpha*X2, alpha = 3 g4 / (2 g3)
    const float alpha = 1.5f * g4 / g3;
    for (int e = tid; e < MS; e += 256) {
        int kk = e >> 7;
        L1[e] = (L0[e] + alpha * sx2t[e]) * sqrtf(eqv[kk]);
    }
    // qm = G D G^T
    mm_<128,128,128,0,false>(L1, L1, sq, nullptr, nullptr);
    // Q = h*( g1 D + W1 D + D W1^T + 2 g3 * qm ),  W1 = g2 X + g3 X2 + g4 X3
    const float c10 = g2, c20 = g3, c30 = g4, c11 = 2.f*g3;
    for (int e = tid; e < MS; e += 256) {
        int j = e >> 7, i = e & 127;
        float w1  = c10*sx[e]  + c20*sx2[e]  + c30*sx3[e];
        float w1t = c10*L0[e]  + c20*sx2t[e] + c30*sx3t[e];
        float vq = w1*eqv[i] + eqv[j]*w1t + c11*sq[e];
        if (i == j) vq += g1*eqv[j];
        sq[e] = h * vq;
    }
    __syncthreads();
    // L1 := A0^T, L0 := A1^T  (A0 = I+g1X+g2X2+g3X3, A1 = g4X+g5X2+g6X3)
    for (int e = tid; e < MS; e += 256) {
        int j = e >> 7, i = e & 127;
        float xt = L0[e], x2t_ = sx2t[e], x3t_ = sx3t[e];
        L1[e] = ((i==j)?1.f:0.f) + g1*xt + g2*x2t_ + g3*x3t_;
        L0[e] = g4*xt + g5*x2t_ + g6*x3t_;
    }
    // Ft = A0t + (A1*X3)^T
    mm_<128,128,128,1,false>(sx3, L0, L1, nullptr, nullptr);
}

#define SHARED_DECLS \
    __shared__ __align__(16) float L0[MS]; \
    __shared__ __align__(16) float L1[MS]; \
    __shared__ __align__(16) float SL[DX*DX]; \
    __shared__ float V0[DZ],V1[DZ],V2[DZ],V3[DZ],V4[DZ],V5[DZ]; \
    __shared__ float r64s[DX], u64s[DX]; \
    __shared__ float W16[KMIX], ebv[DZ], eqv[DZ], vvv[DZ], cvec[DZ]; \
    __shared__ float GJc[DZ], GJr[DZ]; \
    __shared__ int REC[DZ]; __shared__ int IPV1[1];

// =====================================================================
// prep: Ct, Rj, Rji, initial updated state (mu0u, p0u)
// =====================================================================
__global__ __launch_bounds__(256) void kf_prep(
    const float* __restrict__ Cm, const float* __restrict__ Rm,
    const float* __restrict__ mu0, const float* __restrict__ P0,
    const float* __restrict__ xs,
    float* Ct, float* Rj, float* Rji, float* mu0u, float* p0u, float* scr)
{
    SHARED_DECLS
    const int tid = threadIdx.x;
    for (int i = tid; i < DZ*DX; i += 256) { int z = i>>6, m = i&63; Ct[i] = Cm[m*DZ + z]; }
    for (int i = tid; i < DX*DX; i += 256) {
        int a = i>>6, b = i&63;
        float v = Rm[i] + ((a==b) ? JITTER_C : 0.f);
        Rj[i] = v; SL[i] = v;
    }
    gj64_spd(SL, GJc, GJr);
    for (int i = tid; i < DX*DX; i += 256) Rji[i] = SL[i];
    float* z  = scr + SX;
    float* cp = scr + SX + DZ*DX;
    float* kt = scr + SX2;
    mm_<128,64,128,0,true>(P0, Ct, z, nullptr, cp);     // z = P0 C^T, cp = C P0
    mm_<64,64,128,3,false>(Ct, z, SL, Rj, nullptr);     // S0
    gj64_spd(SL, GJc, GJr);
    mm_<64,128,64,0,false>(SL, cp, kt, nullptr, nullptr); // K0^T
    mv_<64,128,2>(Ct, mu0, r64s, xs);                   // r = x0 - C mu0
    mv_<128,64,1>(kt, r64s, mu0u, mu0);                 // mu0u = mu0 + K0 r
    mm_<128,128,64,2,false>(kt, cp, p0u, P0, nullptr);  // P0u = P0 - K0 C P0
    __syncthreads();
    for (int e = tid; e < MS; e += 256) L0[e] = p0u[e];
    __syncthreads();
    for (int e = tid; e < MS; e += 256) {
        int i = e>>7, j = e&127;
        p0u[e] = 0.5f * (L0[e] + L0[j*DZ + i]);
    }
}

// =====================================================================
// pass A: per chunk, direct element recursion (predict + Woodbury update)
// =====================================================================
__global__ __launch_bounds__(256) void kf_passA(
    const float* __restrict__ A_s, const float* __restrict__ b_s,
    const float* __restrict__ Qch, const float* __restrict__ es,
    const float* __restrict__ ts, const float* __restrict__ xs,
    const float* __restrict__ Ct, const float* __restrict__ Rj,
    const float* __restrict__ Rji,
    const float* __restrict__ mu0u, const float* __restrict__ p0u,
    float* elems, float* scr, int T, int LCH,
    float g1, float g2, float g3, float g4, float g5, float g6)
{
    SHARED_DECLS
    const int c = blockIdx.x, tid = threadIdx.x;
    float* sc = scr + (size_t)c * SCN;
    float* R = elems + (size_t)c * ESZ;
    float* RAs = R; float* RAts = R+MS; float* RCs = R+2*MS; float* RJs = R+3*MS;
    float* Rbs = R+4*MS; float* Rhs = R+4*MS+DZ;
    int eBeg = c*LCH, eEnd = (c*LCH + LCH < T) ? (c*LCH + LCH) : T;
    if (eBeg >= eEnd && c != 0) {
        for (int e = tid; e < MS; e += 256) {
            int i = e>>7, j = e&127; float id = (i==j)?1.f:0.f;
            RAs[e]=id; RAts[e]=id; RCs[e]=0.f; RJs[e]=0.f;
        }
        if (tid < DZ) { Rbs[tid]=0.f; Rhs[tid]=0.f; }
        return;
    }
    if (c == 0) {
        for (int e = tid; e < MS; e += 256) { RAs[e]=0.f; RCs[e]=p0u[e]; RJs[e]=0.f; }
        if (tid < DZ) { V0[tid]=mu0u[tid]; V5[tid]=0.f; }
        eBeg = 1;
    } else {
        for (int e = tid; e < MS; e += 256) {
            int i = e>>7, j = e&127;
            RAs[e] = (i==j)?1.f:0.f; RCs[e]=0.f; RJs[e]=0.f;
        }
        if (tid < DZ) { V0[tid]=0.f; V5[tid]=0.f; }
    }
    __syncthreads();
    float* tA = sc+SX;  float* tU = sc+SX2;
    float* z  = sc+SX3; float* zt = sc+SX3+DZ*DX;
    float* y  = sc+SX2T; float* hh = sc+SX2T+DZ*DX;
    float* h2 = sc+SX3T;
    for (int e = eBeg; e < eEnd; ++e) {
        phase1_dev(e, A_s,b_s,Qch,es,ts, sc+SX,sc+SX2,sc+SX2T,sc+SX3,sc+SX3T,sc+SQ,
                   L0,L1, W16,ebv,eqv,vvv,cvec, g1,g2,g3,g4,g5,g6);
        // ---- predict-compose (EJ=0) ----
        mm_<128,128,128,0,false>(L1, RAs, tA, nullptr, nullptr);   // RA' = F RA
        mm_<128,128,128,0,false>(RCs, L1, tU, nullptr, nullptr);   // U = RC F^T
        mm_<128,128,128,3,false>(L1, tU, L0, sc+SQ, nullptr);      // L0 = RC' = F U + Q
        mv_<128,128,1>(L1, V0, V1, cvec);                          // V1 = Rb' = F Rb + c
        // ---- update-compose (Woodbury on rank-64 J_u) ----
        mm_<128,64,128,0,true>(L0, Ct, z, nullptr, zt);            // Z = RC' C^T (dual)
        mm_<64,64,128,3,false>(Ct, z, SL, Rj, nullptr);            // S~ = R~ + C Z
        gj64_spd(SL, GJc, GJr);                                    // SL = S~^-1
        mm_<64,128,128,0,false>(Ct, tA, y, nullptr, nullptr);      // Y = C RA'
        mm_<64,128,64,0,false>(SL, y, hh, nullptr, nullptr);       // H = Si Y
        mm_<128,128,64,2,false>(zt, hh, RAs, tA, nullptr);         // RA'' = RA' - Z H
        mm_<128,128,64,1,false>(y, hh, RJs, nullptr, nullptr);     // RJ += Y^T H
        mm_<64,128,64,0,false>(SL, zt, h2, nullptr, nullptr);      // h2 = Si Z^T
        mm_<128,128,64,2,false>(zt, h2, RCs, L0, nullptr);         // RC'' = RC' - Z h2
        // vectors
        mv_<64,128,2>(Ct, V1, r64s, xs + (size_t)e*DX);            // r = x - C Rb'
        mv_<64,64,0>(Rji, xs + (size_t)e*DX, u64s, nullptr);       // u = R~i x
        mv_<128,64,1>(zt, u64s, V2, V1);                           // v1 = Rb' + Z u
        mv_<64,128,0>(Ct, V2, GJc, nullptr);                       // w = C v1
        mv_<64,64,0>(SL, GJc, GJr, nullptr);                       // w2 = Si w
        mv_<128,64,2>(zt, GJr, V0, V2);                            // Rb'' = v1 - Z w2
        mv_<64,64,0>(SL, r64s, u64s, nullptr);                     // s = Si r
        mv_<128,64,1>(y, u64s, V5, V5);                            // Reta += Y^T s
    }
    __syncthreads();
    if (tid < DZ) { Rbs[tid] = V0[tid]; Rhs[tid] = V5[tid]; }
    trans_g(RAs, RAts, L0);
}

// =====================================================================
// combine (generic, validated in R4): Rd <- Rd (earlier) (x) E (later)
// =====================================================================
__device__ void combine(float* Rd,
    const float* EA, const float* EAt, const float* EC, const float* EJ,
    const float* Ebg, const float* Ehg,
    float* t1, float* t2, float* t3,
    float* L0, float* L1,
    float* V0, float* V1, float* V2, float* V3, float* V4, float* V5,
    float* GJc, float* GJr, int* REC, int* IPV1)
{
    float* RA = Rd; float* RAt = Rd+MS; float* RC = Rd+2*MS; float* RJ = Rd+3*MS;
    float* Rb = Rd+4*MS; float* Rh = Rd+4*MS+DZ;
    const int tid = threadIdx.x;
    __syncthreads();
    if (tid < DZ) { V0[tid]=Ebg[tid]; V1[tid]=Ehg[tid]; V2[tid]=Rb[tid]; }
    mm_<128,128,128,0,false>(EJ, RC, L0, nullptr, nullptr);    // L0 = EJ RC
    if (tid < DZ) L0[tid*DZ + tid] += 1.f;                     // M^T
    gj128_piv(L0, GJc, GJr, REC, IPV1);                        // L0 = M^-T
    mm_<128,128,128,0,false>(L0, RA, t1, nullptr, nullptr);    // t1 = Minv RA
    mm_<128,128,128,0,false>(EJ, RA, t2, nullptr, nullptr);    // t2 = EJ RA
    mm_<128,128,128,1,false>(t1, t2, RJ, nullptr, nullptr);    // RJ += t1^T t2
    mv_<128,128,1>(RC, V1, V3, V2);                            // v1 = Rb + RC Eh
    mv_<128,128,2>(EJ, V2, V4, V1);                            // w1 = Eh - EJ Rb
    mv_<128,128,1>(t1, V4, Rh, Rh);                            // Rh += t1^T w1
    mv_<128,128,0>(L0, V3, V5, nullptr);                       // z1 = Minv v1
    mv_<128,128,1>(EAt, V5, Rb, V0);                           // Rb = Eb + EA z1
    mm_<128,128,128,0,false>(L0, RC, t3, nullptr, nullptr);    // t3 = Minv RC
    mm_<128,128,128,0,false>(t3, EAt, t2, nullptr, nullptr);   // t2 = Minv RC EA^T
    mm_<128,128,128,3,false>(EAt, t2, RC, EC, nullptr);        // RC = EA t2 + EC
    mm_<128,128,128,0,false>(EAt, t1, RA, nullptr, nullptr);   // RA = EA t1
    trans_g(RA, RAt, L1);
}

// =====================================================================
// Kogge-Stone scan round
// =====================================================================
__global__ __launch_bounds__(256) void kf_scan(
    const float* __restrict__ in, float* __restrict__ out, float* scr, int r)
{
    SHARED_DECLS
    const int c = blockIdx.x;
    float* sc = scr + (size_t)c * SCN;
    float* dst = out + (size_t)c * ESZ;
    const float* src = in + (size_t)((c >= r) ? (c - r) : c) * ESZ;
    for (int e = threadIdx.x; e < ESZ; e += 256) dst[e] = src[e];
    if (c >= r) {
        const float* E = in + (size_t)c * ESZ;
        combine(dst, E, E+MS, E+2*MS, E+3*MS, E+4*MS, E+4*MS+DZ,
                sc+SX, sc+SX2, sc+SX3, L0, L1,
                V0,V1,V2,V3,V4,V5, GJc, GJr, REC, IPV1);
    }
}

// =====================================================================
// pass C: per chunk, plain filter from exact boundary state; writes outputs
// =====================================================================
__global__ __launch_bounds__(256) void kf_passC(
    const float* __restrict__ A_s, const float* __restrict__ b_s,
    const float* __restrict__ Qch, const float* __restrict__ es,
    const float* __restrict__ ts, const float* __restrict__ xs,
    const float* __restrict__ Ct, const float* __restrict__ Rj,
    const float* __restrict__ mu0u, const float* __restrict__ p0u,
    const float* __restrict__ pfx,
    float* mu_out, float* P_out, float* scr, int T, int LCH,
    float g1, float g2, float g3, float g4, float g5, float g6)
{
    SHARED_DECLS
    const int c = blockIdx.x, tid = threadIdx.x;
    float* sc = scr + (size_t)c * SCN;
    float* P = sc + SP;
    int eBeg = c*LCH, eEnd = (c*LCH + LCH < T) ? (c*LCH + LCH) : T;
    if (eBeg >= eEnd && c != 0) return;
    if (c == 0) {
        for (int e = tid; e < MS; e += 256) { float v = p0u[e]; P[e] = v; P_out[e] = v; }
        if (tid < DZ) { V0[tid] = mu0u[tid]; mu_out[tid] = mu0u[tid]; }
        eBeg = 1;
    } else {
        const float* X = pfx + (size_t)(c-1) * ESZ;
        for (int e = tid; e < MS; e += 256) P[e] = X[2*MS + e];
        if (tid < DZ) V0[tid] = X[4*MS + tid];
    }
    __syncthreads();
    float* U   = sc+SX;  float* Ppr = sc+SX2;
    float* z   = sc+SX3; float* zt  = sc+SX3+DZ*DX;
    float* kt  = sc+SX2T;
    for (int e = eBeg; e < eEnd; ++e) {
        phase1_dev(e, A_s,b_s,Qch,es,ts, sc+SX,sc+SX2,sc+SX2T,sc+SX3,sc+SX3T,sc+SQ,
                   L0,L1, W16,ebv,eqv,vvv,cvec, g1,g2,g3,g4,g5,g6);
        mm_<128,128,128,0,false>(P, L1, U, nullptr, nullptr);      // U = P F^T
        mm_<128,128,128,3,false>(L1, U, Ppr, sc+SQ, nullptr);      // Ppr = F U + Q
        mv_<128,128,1>(L1, V0, V1, cvec);                          // mupr = F mu + c
        mm_<128,64,128,0,true>(Ppr, Ct, z, nullptr, zt);           // Z = Ppr C^T (dual)
        mm_<64,64,128,3,false>(Ct, z, SL, Rj, nullptr);            // S
        gj64_spd(SL, GJc, GJr);
        mm_<64,128,64,0,false>(SL, zt, kt, nullptr, nullptr);      // K^T = Si Z^T
        mv_<64,128,2>(Ct, V1, r64s, xs + (size_t)e*DX);            // y = x - C mupr
        mv_<128,64,1>(kt, r64s, V0, V1);                           // mu = mupr + K y
        if (tid < DZ) mu_out[(size_t)e*DZ + tid] = V0[tid];
        mm_<128,128,64,2,false>(zt, kt, L1, Ppr, nullptr);         // L1 = Ppr - Z K^T
        float* po = P_out + (size_t)e * MS;
        for (int ee = tid; ee < MS; ee += 256) {
            int i = ee>>7, j = ee&127;
            float v = 0.5f * (L1[ee] + L1[j*DZ + i]);
            P[ee] = v; po[ee] = v;
        }
        __syncthreads();
    }
}

// =====================================================================
// host: RK stability polynomial coefficients
// =====================================================================
static void compute_gamma(double g[7])
{
    const double A[6][5] = {
        {0, 0, 0, 0, 0},
        {0.161, 0, 0, 0, 0},
        {-0.008480655492356989, 0.335480655492357, 0, 0, 0},
        {2.8971530571054935, -6.359448489975075, 4.3622954328695815, 0, 0},
        {5.325864828439257, -11.748883564062828, 7.4955393428898365, -0.09249506636175525, 0},
        {5.86145544294642, -12.92096931784711, 8.159367898576159, -0.071584973281401, -0.028269050394068383}};
    const double B[6] = {0.09646076681806523, 0.01, 0.4798896504144996,
                         1.379008574103742, -3.290069515436081, 2.324710524099774};
    double e[6][6];
    for (int i = 0; i < 6; ++i)
        for (int d = 0; d < 6; ++d) e[i][d] = 0.0;
    for (int i = 0; i < 6; ++i) {
        e[i][0] = 1.0;
        for (int j = 0; j < i; ++j)
            for (int d = 0; d < 5; ++d)
                e[i][d + 1] += A[i][j] * e[j][d];
    }
    g[0] = 1.0;
    for (int m = 1; m <= 6; ++m) {
        double s = 0.0;
        for (int i = 0; i < 6; ++i) s += B[i] * e[i][m - 1];
        g[m] = s;
    }
}

extern "C" void kernel_launch(void* const* d_in, const int* in_sizes, int n_in,
                              void* d_out, int out_size, void* d_ws, size_t ws_size,
                              hipStream_t stream)
{
    const float* xs  = (const float*)d_in[0];
    const float* ts  = (const float*)d_in[1];
    const float* es  = (const float*)d_in[2];
    const float* mu0 = (const float*)d_in[3];
    const float* P0  = (const float*)d_in[4];
    const float* A_s = (const float*)d_in[5];
    const float* b_s = (const float*)d_in[6];
    const float* Qch = (const float*)d_in[7];
    const float* Cm  = (const float*)d_in[8];
    const float* Rm  = (const float*)d_in[9];
    const int T = in_sizes[1];

    float* mu_out = (float*)d_out;
    float* P_out  = mu_out + (size_t)T * DZ;

    float* ws = (float*)d_ws;
    float* Ct    = ws;                        // 8192
    float* Rj    = ws + 8192;                 // 4096
    float* Rji   = ws + 12288;                // 4096
    float* mu0u  = ws + 16384;                // 128
    float* p0u   = ws + 16512;                // 16384
    float* elemsA = ws + 32896;
    float* elemsB = elemsA + (size_t)NCH * ESZ;
    float* scr    = elemsB + (size_t)NCH * ESZ;

    const int LCH = (T + NCH - 1) / NCH;

    double g[7];
    compute_gamma(g);
    const float g1 = (float)g[1], g2 = (float)g[2], g3 = (float)g[3];
    const float g4 = (float)g[4], g5 = (float)g[5], g6 = (float)g[6];

    hipLaunchKernelGGL(kf_prep, dim3(1), dim3(256), 0, stream,
                       Cm, Rm, mu0, P0, xs, Ct, Rj, Rji, mu0u, p0u, scr);
    hipLaunchKernelGGL(kf_passA, dim3(NCH), dim3(256), 0, stream,
                       A_s, b_s, Qch, es, ts, xs, Ct, Rj, Rji, mu0u, p0u,
                       elemsA, scr, T, LCH, g1, g2, g3, g4, g5, g6);
    float* bufs[2] = {elemsA, elemsB};
    int cur = 0;
    for (int r = 1; r < NCH; r <<= 1) {
        hipLaunchKernelGGL(kf_scan, dim3(NCH), dim3(256), 0, stream,
                           bufs[cur], bufs[cur ^ 1], scr, r);
        cur ^= 1;
    }
    hipLaunchKernelGGL(kf_passC, dim3(NCH), dim3(256), 0, stream,
                       A_s, b_s, Qch, es, ts, xs, Ct, Rj, mu0u, p0u,
                       bufs[cur], mu_out, P_out, scr, T, LCH, g1, g2, g3, g4, g5, g6);
}

// Round 6
// 14699.240 us; speedup vs baseline: 19.4004x; 1.3684x over previous
//
#include <hip/hip_runtime.h>
#include <math.h>

#define DZ 128
#define DX 64
#define KMIX 16
#define JITTER_C 1e-4f
#define MS (DZ*DZ)            // 16384
#define ESZ (4*MS + 2*DZ)     // element: A, At, C, J, b, eta
#define NCH 256               // chunks
#define NT 512                // threads per block (8 waves, 2/SIMD)
#define SCN (7*MS + 256)      // per-chunk scratch floats

// scr slot offsets (per chunk)
#define SP   0
#define SX   (1*MS)
#define SX2  (2*MS)
#define SX2T (3*MS)
#define SX3  (4*MS)
#define SX3T (5*MS)
#define SQ   (6*MS)

// =====================================================================
// mm_: out[MxN] = op( sum_k At[k*M+i] * B[k*N+j] )  i.e. out = (At)^T*B
// MODE 0: store; 1: out += acc; 2: out = aux - acc; 3: out = aux + acc
// DUAL: additionally store transposed result to outT (N x M).
// NT=512 threads, 16x32 grid, per-thread tile (M/16)x(N/32).
// =====================================================================
template<int M, int N, int K, int MODE, bool DUAL>
__device__ void mm_(const float* __restrict__ At, const float* __restrict__ B,
                    float* __restrict__ out, const float* __restrict__ aux,
                    float* __restrict__ outT)
{
    __syncthreads();
    const int tid = threadIdx.x;
    constexpr int TM = M/16, TN = N/32;
    const int tx = tid & 31, ty = tid >> 5;
    const int i0 = ty*TM, j0 = tx*TN;
    float acc[TM*TN];
#pragma unroll
    for (int e = 0; e < TM*TN; ++e) acc[e] = 0.f;
#pragma unroll 4
    for (int k = 0; k < K; ++k) {
        const float* ar = At + k*M + i0;
        const float* br = B + k*N + j0;
        float av[TM], bv[TN];
#pragma unroll
        for (int a = 0; a < TM; a += 4) {
            float4 t = *reinterpret_cast<const float4*>(ar + a);
            av[a]=t.x; av[a+1]=t.y; av[a+2]=t.z; av[a+3]=t.w;
        }
        if constexpr (TN == 2) {
            float2 t = *reinterpret_cast<const float2*>(br);
            bv[0]=t.x; bv[1]=t.y;
        } else {
#pragma unroll
            for (int b = 0; b < TN; b += 4) {
                float4 t = *reinterpret_cast<const float4*>(br + b);
                bv[b]=t.x; bv[b+1]=t.y; bv[b+2]=t.z; bv[b+3]=t.w;
            }
        }
#pragma unroll
        for (int a = 0; a < TM; ++a)
#pragma unroll
            for (int b = 0; b < TN; ++b)
                acc[a*TN+b] = fmaf(av[a], bv[b], acc[a*TN+b]);
    }
#pragma unroll
    for (int a = 0; a < TM; ++a) {
        if constexpr (TN == 2) {
            const int idx = (i0+a)*N + j0;
            float2 v = make_float2(acc[a*TN], acc[a*TN+1]);
            if constexpr (MODE == 1) { float2 o = *reinterpret_cast<const float2*>(out+idx); v.x+=o.x; v.y+=o.y; }
            else if constexpr (MODE == 2) { float2 o = *reinterpret_cast<const float2*>(aux+idx); v.x=o.x-v.x; v.y=o.y-v.y; }
            else if constexpr (MODE == 3) { float2 o = *reinterpret_cast<const float2*>(aux+idx); v.x+=o.x; v.y+=o.y; }
            *reinterpret_cast<float2*>(out+idx) = v;
            acc[a*TN]=v.x; acc[a*TN+1]=v.y;
        } else {
#pragma unroll
            for (int b = 0; b < TN; b += 4) {
                const int idx = (i0+a)*N + j0 + b;
                float4 v = make_float4(acc[a*TN+b], acc[a*TN+b+1], acc[a*TN+b+2], acc[a*TN+b+3]);
                if constexpr (MODE == 1) { float4 o = *reinterpret_cast<const float4*>(out+idx); v.x+=o.x; v.y+=o.y; v.z+=o.z; v.w+=o.w; }
                else if constexpr (MODE == 2) { float4 o = *reinterpret_cast<const float4*>(aux+idx); v.x=o.x-v.x; v.y=o.y-v.y; v.z=o.z-v.z; v.w=o.w-v.w; }
                else if constexpr (MODE == 3) { float4 o = *reinterpret_cast<const float4*>(aux+idx); v.x+=o.x; v.y+=o.y; v.z+=o.z; v.w+=o.w; }
                *reinterpret_cast<float4*>(out+idx) = v;
                acc[a*TN+b]=v.x; acc[a*TN+b+1]=v.y; acc[a*TN+b+2]=v.z; acc[a*TN+b+3]=v.w;
            }
        }
    }
    if constexpr (DUAL) {
#pragma unroll
        for (int b = 0; b < TN; ++b) {
#pragma unroll
            for (int a = 0; a < TM; a += 4) {
                float4 v = make_float4(acc[(a)*TN+b], acc[(a+1)*TN+b], acc[(a+2)*TN+b], acc[(a+3)*TN+b]);
                *reinterpret_cast<float4*>(outT + (j0+b)*M + i0 + a) = v;
            }
        }
    }
    __syncthreads();
}

// =====================================================================
// mv_: out[i] = op(aux[i], sum_k At[k*M+i]*v[k]) for i = tid < M
// MODE 0: sum; 1: aux + sum; 2: aux - sum
// =====================================================================
template<int M, int K, int MODE>
__device__ void mv_(const float* __restrict__ At, const float* __restrict__ v,
                    float* __restrict__ out, const float* __restrict__ aux)
{
    __syncthreads();
    const int tid = threadIdx.x;
    if (tid < M) {
        float s = 0.f;
        for (int k = 0; k < K; ++k)
            s = fmaf(At[k*M + tid], v[k], s);
        float r;
        if constexpr (MODE == 0) r = s;
        else if constexpr (MODE == 1) r = aux[tid] + s;
        else r = aux[tid] - s;
        out[tid] = r;
    }
    __syncthreads();
}

// dst[NxM] = src[MxN]^T via LDS bounce (128x128 only)
__device__ void trans_g(const float* __restrict__ src, float* __restrict__ dst,
                        float* __restrict__ Lb)
{
    __syncthreads();
    for (int e = threadIdx.x; e < MS; e += NT) Lb[e] = src[e];
    __syncthreads();
    for (int e = threadIdx.x; e < MS; e += NT) {
        int j = e >> 7, i = e & 127;
        dst[e] = Lb[i*DZ + j];
    }
    __syncthreads();
}

// =====================================================================
// gj64_spd: unpivoted in-place Gauss-Jordan of SPD 64x64 in LDS.
// Safe: used only on S-matrices with lambda_min >= 0.1.
// =====================================================================
__device__ void gj64_spd(float* __restrict__ A, float* __restrict__ pc, float* __restrict__ pr)
{
    __syncthreads();
    const int tid = threadIdx.x;
    for (int p = 0; p < DX; ++p) {
        if (tid < DX) { pc[tid] = A[tid*DX + p]; pr[tid] = A[p*DX + tid]; }
        __syncthreads();
        const float rp = 1.f / pr[p];
        for (int e = tid; e < DX*DX; e += NT) {
            const int i = e >> 6, j = e & 63;
            const float pv = pr[j] * rp;
            float o;
            if (i == p) o = (j == p) ? rp : pv;
            else { const float fc = pc[i]; o = (j == p) ? (-fc*rp) : (A[e] - fc*pv); }
            A[e] = o;
        }
        __syncthreads();
    }
}

// =====================================================================
// gj128_piv: partial-pivoted GJ of 128x128 in LDS; wave-0 shfl argmax.
// =====================================================================
__device__ void gj128_piv(float* __restrict__ A, float* __restrict__ pc, float* __restrict__ pr,
                          int* __restrict__ rec, int* __restrict__ ipv1)
{
    __syncthreads();
    const int tid = threadIdx.x;
    for (int p = 0; p < DZ; ++p) {
        if (tid < 64) {
            float best = -1.f; int bi = p;
            for (int i = tid; i < DZ; i += 64) {
                float v = (i >= p) ? fabsf(A[i*DZ + p]) : -2.f;
                if (v > best) { best = v; bi = i; }
            }
            for (int off = 32; off > 0; off >>= 1) {
                float ob = __shfl_xor(best, off);
                int obi = __shfl_xor(bi, off);
                if (ob > best) { best = ob; bi = obi; }
            }
            if (tid == 0) { rec[p] = bi; ipv1[0] = bi; }
        }
        __syncthreads();
        const int r = ipv1[0];
        if (r != p) {
            for (int j = tid; j < DZ; j += NT) { float t = A[p*DZ+j]; A[p*DZ+j] = A[r*DZ+j]; A[r*DZ+j] = t; }
            __syncthreads();
        }
        if (tid < DZ) { pc[tid] = A[tid*DZ + p]; pr[tid] = A[p*DZ + tid]; }
        __syncthreads();
        const float rp = 1.f / pr[p];
        for (int e = tid; e < MS; e += NT) {
            const int i = e >> 7, j = e & 127;
            const float pv = pr[j] * rp;
            float o;
            if (i == p) o = (j == p) ? rp : pv;
            else { const float fc = pc[i]; o = (j == p) ? (-fc*rp) : (A[e] - fc*pv); }
            A[e] = o;
        }
        __syncthreads();
    }
    for (int p = DZ - 1; p >= 0; --p) {
        const int r = rec[p];
        if (r != p) {
            for (int i = tid; i < DZ; i += NT) { float t = A[i*DZ+p]; A[i*DZ+p] = A[i*DZ+r]; A[i*DZ+r] = t; }
            __syncthreads();
        }
    }
    __syncthreads();
}

// =====================================================================
// phase1_dev: exact RK step map via Paterson-Stockmeyer + truncated
// Lyapunov series. Produces L1 = F^T (LDS), sq = Q_eff, cvec = c.
// =====================================================================
__device__ void phase1_dev(int k,
    const float* __restrict__ A_s, const float* __restrict__ b_s,
    const float* __restrict__ Qch, const float* __restrict__ es, const float* __restrict__ ts,
    float* sx, float* sx2, float* sx2t, float* sx3, float* sx3t, float* sq,
    float* L0, float* L1,
    float* W16, float* ebv, float* eqv, float* vvv, float* cvec,
    float g1, float g2, float g3, float g4, float g5, float g6)
{
    const int tid = threadIdx.x;
    const float h = ts[k] - ts[k-1];
    if (h <= 0.f) {
        __syncthreads();
        for (int e = tid; e < MS; e += NT) {
            int i = e >> 7, j = e & 127;
            L1[e] = (i==j) ? 1.f : 0.f;
            sq[e] = 0.f;
        }
        if (tid < DZ) cvec[tid] = 0.f;
        __syncthreads();
        return;
    }
    __syncthreads();
    if (tid < KMIX) W16[tid] = es[(size_t)k*KMIX + tid];
    __syncthreads();
    if (tid == 0) {
        float s = 0.f;
        for (int m = 0; m < KMIX; ++m) s += W16[m];
        float inv = 1.f/s;
        for (int m = 0; m < KMIX; ++m) W16[m] *= inv;
    }
    __syncthreads();
    if (tid < DZ) {
        float eb = 0.f, eq = 0.f;
        for (int m = 0; m < KMIX; ++m) {
            float wm = W16[m];
            eb = fmaf(wm, b_s[m*DZ+tid], eb);
            float qc = Qch[m*DZ+tid];
            eq = fmaf(wm, qc*qc, eq);
        }
        ebv[tid] = eb; eqv[tid] = eq;
    }
    // X = h * sum_m w_m A_s[m]; write X (L1 + sx) and Xt (L0)
    const int tx = tid & 31, ty = tid >> 5;
    const int i0 = ty*8, j0 = tx*4;
    float t32[32];
#pragma unroll
    for (int e = 0; e < 32; ++e) t32[e] = 0.f;
    for (int m = 0; m < KMIX; ++m) {
        float wm = W16[m];
        const float* Am = A_s + (size_t)m * MS;
#pragma unroll
        for (int a = 0; a < 8; ++a) {
            float4 p0 = *reinterpret_cast<const float4*>(&Am[(i0+a)*DZ + j0]);
            t32[a*4+0]=fmaf(wm,p0.x,t32[a*4+0]); t32[a*4+1]=fmaf(wm,p0.y,t32[a*4+1]);
            t32[a*4+2]=fmaf(wm,p0.z,t32[a*4+2]); t32[a*4+3]=fmaf(wm,p0.w,t32[a*4+3]);
        }
    }
#pragma unroll
    for (int a = 0; a < 8; ++a)
#pragma unroll
        for (int b = 0; b < 4; ++b) {
            float v = h * t32[a*4+b];
            L1[(i0+a)*DZ + (j0+b)] = v;
            sx[(i0+a)*DZ + (j0+b)] = v;
            L0[(j0+b)*DZ + (i0+a)] = v;
        }
    __syncthreads();
    // cvec = h * sum_{m=0..5} g[m+1] X^m eb   (uses L0 = Xt)
    {
        float gg[7]; gg[1]=g1; gg[2]=g2; gg[3]=g3; gg[4]=g4; gg[5]=g5; gg[6]=g6;
        if (tid < DZ) vvv[tid] = ebv[tid];
        float creg = (tid < DZ) ? g1 * ebv[tid] : 0.f;
        __syncthreads();
        for (int m = 1; m <= 5; ++m) {
            float vn = 0.f;
            if (tid < DZ)
                for (int kk = 0; kk < DZ; ++kk)
                    vn = fmaf(L0[kk*DZ + tid], vvv[kk], vn);
            __syncthreads();
            if (tid < DZ) vvv[tid] = vn;
            creg = fmaf(gg[m+1], vn, creg);
            __syncthreads();
        }
        if (tid < DZ) cvec[tid] = h * creg;
    }
    // X2, X3 (dual-stored)
    mm_<128,128,128,0,true>(L0, L1, sx2, nullptr, sx2t);
    mm_<128,128,128,0,true>(L0, sx2, sx3, nullptr, sx3t);
    // L1 := Gt * sqrt(D),  G = X + alpha*X2, alpha = 3 g4 / (2 g3)
    const float alpha = 1.5f * g4 / g3;
    for (int e = tid; e < MS; e += NT) {
        int kk = e >> 7;
        L1[e] = (L0[e] + alpha * sx2t[e]) * sqrtf(eqv[kk]);
    }
    // qm = G D G^T
    mm_<128,128,128,0,false>(L1, L1, sq, nullptr, nullptr);
    // Q = h*( g1 D + W1 D + D W1^T + 2 g3 * qm ),  W1 = g2 X + g3 X2 + g4 X3
    const float c10 = g2, c20 = g3, c30 = g4, c11 = 2.f*g3;
    for (int e = tid; e < MS; e += NT) {
        int j = e >> 7, i = e & 127;
        float w1  = c10*sx[e]  + c20*sx2[e]  + c30*sx3[e];
        float w1t = c10*L0[e]  + c20*sx2t[e] + c30*sx3t[e];
        float vq = w1*eqv[i] + eqv[j]*w1t + c11*sq[e];
        if (i == j) vq += g1*eqv[j];
        sq[e] = h * vq;
    }
    __syncthreads();
    // L1 := A0^T, L0 := A1^T  (A0 = I+g1X+g2X2+g3X3, A1 = g4X+g5X2+g6X3)
    for (int e = tid; e < MS; e += NT) {
        int j = e >> 7, i = e & 127;
        float xt = L0[e], x2t_ = sx2t[e], x3t_ = sx3t[e];
        L1[e] = ((i==j)?1.f:0.f) + g1*xt + g2*x2t_ + g3*x3t_;
        L0[e] = g4*xt + g5*x2t_ + g6*x3t_;
    }
    // Ft = A0t + (A1*X3)^T
    mm_<128,128,128,1,false>(sx3, L0, L1, nullptr, nullptr);
}

#define SHARED_DECLS \
    __shared__ __align__(16) float L0[MS]; \
    __shared__ __align__(16) float L1[MS]; \
    __shared__ __align__(16) float SL[DX*DX]; \
    __shared__ float V0[DZ],V1[DZ],V2[DZ],V3[DZ],V4[DZ],V5[DZ]; \
    __shared__ float r64s[DX], u64s[DX]; \
    __shared__ float W16[KMIX], ebv[DZ], eqv[DZ], vvv[DZ], cvec[DZ]; \
    __shared__ float GJc[DZ], GJr[DZ]; \
    __shared__ int REC[DZ]; __shared__ int IPV1[1];

// =====================================================================
// prep: Ct, Rj, Rji, initial updated state (mu0u, p0u)
// =====================================================================
__global__ __launch_bounds__(NT) void kf_prep(
    const float* __restrict__ Cm, const float* __restrict__ Rm,
    const float* __restrict__ mu0, const float* __restrict__ P0,
    const float* __restrict__ xs,
    float* Ct, float* Rj, float* Rji, float* mu0u, float* p0u, float* scr)
{
    SHARED_DECLS
    const int tid = threadIdx.x;
    for (int i = tid; i < DZ*DX; i += NT) { int z = i>>6, m = i&63; Ct[i] = Cm[m*DZ + z]; }
    for (int i = tid; i < DX*DX; i += NT) {
        int a = i>>6, b = i&63;
        float v = Rm[i] + ((a==b) ? JITTER_C : 0.f);
        Rj[i] = v; SL[i] = v;
    }
    gj64_spd(SL, GJc, GJr);
    for (int i = tid; i < DX*DX; i += NT) Rji[i] = SL[i];
    float* z  = scr + SX;
    float* cp = scr + SX + DZ*DX;
    float* kt = scr + SX2;
    mm_<128,64,128,0,true>(P0, Ct, z, nullptr, cp);     // z = P0 C^T, cp = C P0
    mm_<64,64,128,3,false>(Ct, z, SL, Rj, nullptr);     // S0
    gj64_spd(SL, GJc, GJr);
    mm_<64,128,64,0,false>(SL, cp, kt, nullptr, nullptr); // K0^T
    mv_<64,128,2>(Ct, mu0, r64s, xs);                   // r = x0 - C mu0
    mv_<128,64,1>(kt, r64s, mu0u, mu0);                 // mu0u = mu0 + K0 r
    mm_<128,128,64,2,false>(kt, cp, p0u, P0, nullptr);  // P0u = P0 - K0 C P0
    __syncthreads();
    for (int e = tid; e < MS; e += NT) L0[e] = p0u[e];
    __syncthreads();
    for (int e = tid; e < MS; e += NT) {
        int i = e>>7, j = e&127;
        p0u[e] = 0.5f * (L0[e] + L0[j*DZ + i]);
    }
}

// =====================================================================
// pass A: per chunk, direct element recursion (predict + Woodbury update)
// =====================================================================
__global__ __launch_bounds__(NT) void kf_passA(
    const float* __restrict__ A_s, const float* __restrict__ b_s,
    const float* __restrict__ Qch, const float* __restrict__ es,
    const float* __restrict__ ts, const float* __restrict__ xs,
    const float* __restrict__ Ct, const float* __restrict__ Rj,
    const float* __restrict__ Rji,
    const float* __restrict__ mu0u, const float* __restrict__ p0u,
    float* elems, float* scr, int T, int LCH,
    float g1, float g2, float g3, float g4, float g5, float g6)
{
    SHARED_DECLS
    const int c = blockIdx.x, tid = threadIdx.x;
    float* sc = scr + (size_t)c * SCN;
    float* R = elems + (size_t)c * ESZ;
    float* RAs = R; float* RAts = R+MS; float* RCs = R+2*MS; float* RJs = R+3*MS;
    float* Rbs = R+4*MS; float* Rhs = R+4*MS+DZ;
    int eBeg = c*LCH, eEnd = (c*LCH + LCH < T) ? (c*LCH + LCH) : T;
    if (eBeg >= eEnd && c != 0) {
        for (int e = tid; e < MS; e += NT) {
            int i = e>>7, j = e&127; float id = (i==j)?1.f:0.f;
            RAs[e]=id; RAts[e]=id; RCs[e]=0.f; RJs[e]=0.f;
        }
        if (tid < DZ) { Rbs[tid]=0.f; Rhs[tid]=0.f; }
        return;
    }
    if (c == 0) {
        for (int e = tid; e < MS; e += NT) { RAs[e]=0.f; RCs[e]=p0u[e]; RJs[e]=0.f; }
        if (tid < DZ) { V0[tid]=mu0u[tid]; V5[tid]=0.f; }
        eBeg = 1;
    } else {
        for (int e = tid; e < MS; e += NT) {
            int i = e>>7, j = e&127;
            RAs[e] = (i==j)?1.f:0.f; RCs[e]=0.f; RJs[e]=0.f;
        }
        if (tid < DZ) { V0[tid]=0.f; V5[tid]=0.f; }
    }
    __syncthreads();
    float* tA = sc+SX;  float* tU = sc+SX2;
    float* z  = sc+SX3; float* zt = sc+SX3+DZ*DX;
    float* y  = sc+SX2T; float* hh = sc+SX2T+DZ*DX;
    float* h2 = sc+SX3T;
    for (int e = eBeg; e < eEnd; ++e) {
        phase1_dev(e, A_s,b_s,Qch,es,ts, sc+SX,sc+SX2,sc+SX2T,sc+SX3,sc+SX3T,sc+SQ,
                   L0,L1, W16,ebv,eqv,vvv,cvec, g1,g2,g3,g4,g5,g6);
        // ---- predict-compose (EJ=0) ----
        mm_<128,128,128,0,false>(L1, RAs, tA, nullptr, nullptr);   // RA' = F RA
        mm_<128,128,128,0,false>(RCs, L1, tU, nullptr, nullptr);   // U = RC F^T
        mm_<128,128,128,3,false>(L1, tU, L0, sc+SQ, nullptr);      // L0 = RC' = F U + Q
        mv_<128,128,1>(L1, V0, V1, cvec);                          // V1 = Rb' = F Rb + c
        // ---- update-compose (Woodbury on rank-64 J_u) ----
        mm_<128,64,128,0,true>(L0, Ct, z, nullptr, zt);            // Z = RC' C^T (dual)
        mm_<64,64,128,3,false>(Ct, z, SL, Rj, nullptr);            // S~ = R~ + C Z
        gj64_spd(SL, GJc, GJr);                                    // SL = S~^-1
        mm_<64,128,128,0,false>(Ct, tA, y, nullptr, nullptr);      // Y = C RA'
        mm_<64,128,64,0,false>(SL, y, hh, nullptr, nullptr);       // H = Si Y
        mm_<128,128,64,2,false>(zt, hh, RAs, tA, nullptr);         // RA'' = RA' - Z H
        mm_<128,128,64,1,false>(y, hh, RJs, nullptr, nullptr);     // RJ += Y^T H
        mm_<64,128,64,0,false>(SL, zt, h2, nullptr, nullptr);      // h2 = Si Z^T
        mm_<128,128,64,2,false>(zt, h2, RCs, L0, nullptr);         // RC'' = RC' - Z h2
        // vectors
        mv_<64,128,2>(Ct, V1, r64s, xs + (size_t)e*DX);            // r = x - C Rb'
        mv_<64,64,0>(Rji, xs + (size_t)e*DX, u64s, nullptr);       // u = R~i x
        mv_<128,64,1>(zt, u64s, V2, V1);                           // v1 = Rb' + Z u
        mv_<64,128,0>(Ct, V2, GJc, nullptr);                       // w = C v1
        mv_<64,64,0>(SL, GJc, GJr, nullptr);                       // w2 = Si w
        mv_<128,64,2>(zt, GJr, V0, V2);                            // Rb'' = v1 - Z w2
        mv_<64,64,0>(SL, r64s, u64s, nullptr);                     // s = Si r
        mv_<128,64,1>(y, u64s, V5, V5);                            // Reta += Y^T s
    }
    __syncthreads();
    if (tid < DZ) { Rbs[tid] = V0[tid]; Rhs[tid] = V5[tid]; }
    trans_g(RAs, RAts, L0);
}

// =====================================================================
// combine (generic, validated in R4/R5): Rd <- Rd (earlier) (x) E (later)
// =====================================================================
__device__ void combine(float* Rd,
    const float* EA, const float* EAt, const float* EC, const float* EJ,
    const float* Ebg, const float* Ehg,
    float* t1, float* t2, float* t3,
    float* L0, float* L1,
    float* V0, float* V1, float* V2, float* V3, float* V4, float* V5,
    float* GJc, float* GJr, int* REC, int* IPV1)
{
    float* RA = Rd; float* RAt = Rd+MS; float* RC = Rd+2*MS; float* RJ = Rd+3*MS;
    float* Rb = Rd+4*MS; float* Rh = Rd+4*MS+DZ;
    const int tid = threadIdx.x;
    __syncthreads();
    if (tid < DZ) { V0[tid]=Ebg[tid]; V1[tid]=Ehg[tid]; V2[tid]=Rb[tid]; }
    mm_<128,128,128,0,false>(EJ, RC, L0, nullptr, nullptr);    // L0 = EJ RC
    if (tid < DZ) L0[tid*DZ + tid] += 1.f;                     // M^T
    gj128_piv(L0, GJc, GJr, REC, IPV1);                        // L0 = M^-T
    mm_<128,128,128,0,false>(L0, RA, t1, nullptr, nullptr);    // t1 = Minv RA
    mm_<128,128,128,0,false>(EJ, RA, t2, nullptr, nullptr);    // t2 = EJ RA
    mm_<128,128,128,1,false>(t1, t2, RJ, nullptr, nullptr);    // RJ += t1^T t2
    mv_<128,128,1>(RC, V1, V3, V2);                            // v1 = Rb + RC Eh
    mv_<128,128,2>(EJ, V2, V4, V1);                            // w1 = Eh - EJ Rb
    mv_<128,128,1>(t1, V4, Rh, Rh);                            // Rh += t1^T w1
    mv_<128,128,0>(L0, V3, V5, nullptr);                       // z1 = Minv v1
    mv_<128,128,1>(EAt, V5, Rb, V0);                           // Rb = Eb + EA z1
    mm_<128,128,128,0,false>(L0, RC, t3, nullptr, nullptr);    // t3 = Minv RC
    mm_<128,128,128,0,false>(t3, EAt, t2, nullptr, nullptr);   // t2 = Minv RC EA^T
    mm_<128,128,128,3,false>(EAt, t2, RC, EC, nullptr);        // RC = EA t2 + EC
    mm_<128,128,128,0,false>(EAt, t1, RA, nullptr, nullptr);   // RA = EA t1
    trans_g(RA, RAt, L1);
}

// =====================================================================
// Kogge-Stone scan round
// =====================================================================
__global__ __launch_bounds__(NT) void kf_scan(
    const float* __restrict__ in, float* __restrict__ out, float* scr, int r)
{
    SHARED_DECLS
    const int c = blockIdx.x;
    float* sc = scr + (size_t)c * SCN;
    float* dst = out + (size_t)c * ESZ;
    const float* src = in + (size_t)((c >= r) ? (c - r) : c) * ESZ;
    for (int e = threadIdx.x; e < ESZ; e += NT) dst[e] = src[e];
    if (c >= r) {
        const float* E = in + (size_t)c * ESZ;
        combine(dst, E, E+MS, E+2*MS, E+3*MS, E+4*MS, E+4*MS+DZ,
                sc+SX, sc+SX2, sc+SX3, L0, L1,
                V0,V1,V2,V3,V4,V5, GJc, GJr, REC, IPV1);
    }
}

// =====================================================================
// pass C: per chunk, plain filter from exact boundary state; writes outputs
// =====================================================================
__global__ __launch_bounds__(NT) void kf_passC(
    const float* __restrict__ A_s, const float* __restrict__ b_s,
    const float* __restrict__ Qch, const float* __restrict__ es,
    const float* __restrict__ ts, const float* __restrict__ xs,
    const float* __restrict__ Ct, const float* __restrict__ Rj,
    const float* __restrict__ mu0u, const float* __restrict__ p0u,
    const float* __restrict__ pfx,
    float* mu_out, float* P_out, float* scr, int T, int LCH,
    float g1, float g2, float g3, float g4, float g5, float g6)
{
    SHARED_DECLS
    const int c = blockIdx.x, tid = threadIdx.x;
    float* sc = scr + (size_t)c * SCN;
    float* P = sc + SP;
    int eBeg = c*LCH, eEnd = (c*LCH + LCH < T) ? (c*LCH + LCH) : T;
    if (eBeg >= eEnd && c != 0) return;
    if (c == 0) {
        for (int e = tid; e < MS; e += NT) { float v = p0u[e]; P[e] = v; P_out[e] = v; }
        if (tid < DZ) { V0[tid] = mu0u[tid]; mu_out[tid] = mu0u[tid]; }
        eBeg = 1;
    } else {
        const float* X = pfx + (size_t)(c-1) * ESZ;
        for (int e = tid; e < MS; e += NT) P[e] = X[2*MS + e];
        if (tid < DZ) V0[tid] = X[4*MS + tid];
    }
    __syncthreads();
    float* U   = sc+SX;  float* Ppr = sc+SX2;
    float* z   = sc+SX3; float* zt  = sc+SX3+DZ*DX;
    float* kt  = sc+SX2T;
    for (int e = eBeg; e < eEnd; ++e) {
        phase1_dev(e, A_s,b_s,Qch,es,ts, sc+SX,sc+SX2,sc+SX2T,sc+SX3,sc+SX3T,sc+SQ,
                   L0,L1, W16,ebv,eqv,vvv,cvec, g1,g2,g3,g4,g5,g6);
        mm_<128,128,128,0,false>(P, L1, U, nullptr, nullptr);      // U = P F^T
        mm_<128,128,128,3,false>(L1, U, Ppr, sc+SQ, nullptr);      // Ppr = F U + Q
        mv_<128,128,1>(L1, V0, V1, cvec);                          // mupr = F mu + c
        mm_<128,64,128,0,true>(Ppr, Ct, z, nullptr, zt);           // Z = Ppr C^T (dual)
        mm_<64,64,128,3,false>(Ct, z, SL, Rj, nullptr);            // S
        gj64_spd(SL, GJc, GJr);
        mm_<64,128,64,0,false>(SL, zt, kt, nullptr, nullptr);      // K^T = Si Z^T
        mv_<64,128,2>(Ct, V1, r64s, xs + (size_t)e*DX);            // y = x - C mupr
        mv_<128,64,1>(kt, r64s, V0, V1);                           // mu = mupr + K y
        if (tid < DZ) mu_out[(size_t)e*DZ + tid] = V0[tid];
        mm_<128,128,64,2,false>(zt, kt, L1, Ppr, nullptr);         // L1 = Ppr - Z K^T
        float* po = P_out + (size_t)e * MS;
        for (int ee = tid; ee < MS; ee += NT) {
            int i = ee>>7, j = ee&127;
            float v = 0.5f * (L1[ee] + L1[j*DZ + i]);
            P[ee] = v; po[ee] = v;
        }
        __syncthreads();
    }
}

// =====================================================================
// host: RK stability polynomial coefficients
// =====================================================================
static void compute_gamma(double g[7])
{
    const double A[6][5] = {
        {0, 0, 0, 0, 0},
        {0.161, 0, 0, 0, 0},
        {-0.008480655492356989, 0.335480655492357, 0, 0, 0},
        {2.8971530571054935, -6.359448489975075, 4.3622954328695815, 0, 0},
        {5.325864828439257, -11.748883564062828, 7.4955393428898365, -0.09249506636175525, 0},
        {5.86145544294642, -12.92096931784711, 8.159367898576159, -0.071584973281401, -0.028269050394068383}};
    const double B[6] = {0.09646076681806523, 0.01, 0.4798896504144996,
                         1.379008574103742, -3.290069515436081, 2.324710524099774};
    double e[6][6];
    for (int i = 0; i < 6; ++i)
        for (int d = 0; d < 6; ++d) e[i][d] = 0.0;
    for (int i = 0; i < 6; ++i) {
        e[i][0] = 1.0;
        for (int j = 0; j < i; ++j)
            for (int d = 0; d < 5; ++d)
                e[i][d + 1] += A[i][j] * e[j][d];
    }
    g[0] = 1.0;
    for (int m = 1; m <= 6; ++m) {
        double s = 0.0;
        for (int i = 0; i < 6; ++i) s += B[i] * e[i][m - 1];
        g[m] = s;
    }
}

extern "C" void kernel_launch(void* const* d_in, const int* in_sizes, int n_in,
                              void* d_out, int out_size, void* d_ws, size_t ws_size,
                              hipStream_t stream)
{
    const float* xs  = (const float*)d_in[0];
    const float* ts  = (const float*)d_in[1];
    const float* es  = (const float*)d_in[2];
    const float* mu0 = (const float*)d_in[3];
    const float* P0  = (const float*)d_in[4];
    const float* A_s = (const float*)d_in[5];
    const float* b_s = (const float*)d_in[6];
    const float* Qch = (const float*)d_in[7];
    const float* Cm  = (const float*)d_in[8];
    const float* Rm  = (const float*)d_in[9];
    const int T = in_sizes[1];

    float* mu_out = (float*)d_out;
    float* P_out  = mu_out + (size_t)T * DZ;

    float* ws = (float*)d_ws;
    float* Ct    = ws;                        // 8192
    float* Rj    = ws + 8192;                 // 4096
    float* Rji   = ws + 12288;                // 4096
    float* mu0u  = ws + 16384;                // 128
    float* p0u   = ws + 16512;                // 16384
    float* elemsA = ws + 32896;
    float* elemsB = elemsA + (size_t)NCH * ESZ;
    float* scr    = elemsB + (size_t)NCH * ESZ;

    const int LCH = (T + NCH - 1) / NCH;

    double g[7];
    compute_gamma(g);
    const float g1 = (float)g[1], g2 = (float)g[2], g3 = (float)g[3];
    const float g4 = (float)g[4], g5 = (float)g[5], g6 = (float)g[6];

    hipLaunchKernelGGL(kf_prep, dim3(1), dim3(NT), 0, stream,
                       Cm, Rm, mu0, P0, xs, Ct, Rj, Rji, mu0u, p0u, scr);
    hipLaunchKernelGGL(kf_passA, dim3(NCH), dim3(NT), 0, stream,
                       A_s, b_s, Qch, es, ts, xs, Ct, Rj, Rji, mu0u, p0u,
                       elemsA, scr, T, LCH, g1, g2, g3, g4, g5, g6);
    float* bufs[2] = {elemsA, elemsB};
    int cur = 0;
    for (int r = 1; r < NCH; r <<= 1) {
        hipLaunchKernelGGL(kf_scan, dim3(NCH), dim3(NT), 0, stream,
                           bufs[cur], bufs[cur ^ 1], scr, r);
        cur ^= 1;
    }
    hipLaunchKernelGGL(kf_passC, dim3(NCH), dim3(NT), 0, stream,
                       A_s, b_s, Qch, es, ts, xs, Ct, Rj, mu0u, p0u,
                       bufs[cur], mu_out, P_out, scr, T, LCH, g1, g2, g3, g4, g5, g6);
}

// Round 7
// 13165.858 us; speedup vs baseline: 21.6599x; 1.1165x over previous
//
#include <hip/hip_runtime.h>
#include <math.h>

#define DZ 128
#define DX 64
#define KMIX 16
#define JITTER_C 1e-4f
#define MS (DZ*DZ)            // 16384
#define ESZ (4*MS + 2*DZ)     // element: A, At, C, J, b, eta
#define NCH 256               // chunks
#define NT 1024               // threads per block (16 waves, 4/SIMD)
#define SCN (5*MS + 256)      // per-chunk scratch floats

// scr slot offsets (per chunk)
#define SP   0
#define SX   (1*MS)
#define SX2  (2*MS)
#define SX2T (3*MS)
#define SQ   (4*MS)

// =====================================================================
// mm_: out[MxN] = op( sum_k At[k*M+i] * B[k*N+j] )  i.e. out = (At)^T*B
// MODE 0: store; 1: out += acc; 2: out = aux - acc; 3: out = aux + acc
// MODE 4: out = acc + e1*aux + I   (aux may alias out; per-thread tiles)
// DUAL: additionally store transposed result to outT (N x M).
// NT=1024 threads, 32x32 grid, per-thread tile (M/32)x(N/32).
// =====================================================================
template<int M, int N, int K, int MODE, bool DUAL>
__device__ void mm_(const float* __restrict__ At, const float* __restrict__ B,
                    float* __restrict__ out, const float* __restrict__ aux,
                    float* __restrict__ outT, float e1 = 0.f)
{
    __syncthreads();
    const int tid = threadIdx.x;
    constexpr int TM = M/32, TN = N/32;
    const int tx = tid & 31, ty = tid >> 5;
    const int i0 = ty*TM, j0 = tx*TN;
    float acc[TM*TN];
#pragma unroll
    for (int e = 0; e < TM*TN; ++e) acc[e] = 0.f;
#pragma unroll 4
    for (int k = 0; k < K; ++k) {
        const float* ar = At + k*M + i0;
        const float* br = B + k*N + j0;
        float av[TM], bv[TN];
        if constexpr (TM == 2) {
            float2 t = *reinterpret_cast<const float2*>(ar);
            av[0]=t.x; av[1]=t.y;
        } else {
#pragma unroll
            for (int a = 0; a < TM; a += 4) {
                float4 t = *reinterpret_cast<const float4*>(ar + a);
                av[a]=t.x; av[a+1]=t.y; av[a+2]=t.z; av[a+3]=t.w;
            }
        }
        if constexpr (TN == 2) {
            float2 t = *reinterpret_cast<const float2*>(br);
            bv[0]=t.x; bv[1]=t.y;
        } else {
#pragma unroll
            for (int b = 0; b < TN; b += 4) {
                float4 t = *reinterpret_cast<const float4*>(br + b);
                bv[b]=t.x; bv[b+1]=t.y; bv[b+2]=t.z; bv[b+3]=t.w;
            }
        }
#pragma unroll
        for (int a = 0; a < TM; ++a)
#pragma unroll
            for (int b = 0; b < TN; ++b)
                acc[a*TN+b] = fmaf(av[a], bv[b], acc[a*TN+b]);
    }
#pragma unroll
    for (int a = 0; a < TM; ++a) {
#pragma unroll
        for (int b = 0; b < TN; ++b) {
            const int row = i0+a, col = j0+b;
            const int idx = row*N + col;
            float v = acc[a*TN+b];
            if constexpr (MODE == 1) v += out[idx];
            else if constexpr (MODE == 2) v = aux[idx] - v;
            else if constexpr (MODE == 3) v += aux[idx];
            else if constexpr (MODE == 4) { v += e1*aux[idx]; if (row==col) v += 1.f; }
            out[idx] = v;
            acc[a*TN+b] = v;
        }
    }
    if constexpr (DUAL) {
#pragma unroll
        for (int b = 0; b < TN; ++b) {
#pragma unroll
            for (int a = 0; a < TM; a += 4) {
                float4 v = make_float4(acc[(a)*TN+b], acc[(a+1)*TN+b], acc[(a+2)*TN+b], acc[(a+3)*TN+b]);
                *reinterpret_cast<float4*>(outT + (j0+b)*M + i0 + a) = v;
            }
        }
    }
    __syncthreads();
}

// =====================================================================
// mv_: out[i] = op(aux[i], sum_k At[k*M+i]*v[k]) for i = tid < M
// MODE 0: sum; 1: aux + sum; 2: aux - sum
// =====================================================================
template<int M, int K, int MODE>
__device__ void mv_(const float* __restrict__ At, const float* __restrict__ v,
                    float* __restrict__ out, const float* __restrict__ aux)
{
    __syncthreads();
    const int tid = threadIdx.x;
    if (tid < M) {
        float s = 0.f;
        for (int k = 0; k < K; ++k)
            s = fmaf(At[k*M + tid], v[k], s);
        float r;
        if constexpr (MODE == 0) r = s;
        else if constexpr (MODE == 1) r = aux[tid] + s;
        else r = aux[tid] - s;
        out[tid] = r;
    }
    __syncthreads();
}

// dst[NxM] = src[MxN]^T via LDS bounce (128x128 only)
__device__ void trans_g(const float* __restrict__ src, float* __restrict__ dst,
                        float* __restrict__ Lb)
{
    __syncthreads();
    for (int e = threadIdx.x; e < MS; e += NT) Lb[e] = src[e];
    __syncthreads();
    for (int e = threadIdx.x; e < MS; e += NT) {
        int j = e >> 7, i = e & 127;
        dst[e] = Lb[i*DZ + j];
    }
    __syncthreads();
}

// =====================================================================
// gj64_spd: unpivoted in-place Gauss-Jordan of SPD 64x64 in LDS.
// =====================================================================
__device__ void gj64_spd(float* __restrict__ A, float* __restrict__ pc, float* __restrict__ pr)
{
    __syncthreads();
    const int tid = threadIdx.x;
    for (int p = 0; p < DX; ++p) {
        if (tid < DX) { pc[tid] = A[tid*DX + p]; pr[tid] = A[p*DX + tid]; }
        __syncthreads();
        const float rp = 1.f / pr[p];
        for (int e = tid; e < DX*DX; e += NT) {
            const int i = e >> 6, j = e & 63;
            const float pv = pr[j] * rp;
            float o;
            if (i == p) o = (j == p) ? rp : pv;
            else { const float fc = pc[i]; o = (j == p) ? (-fc*rp) : (A[e] - fc*pv); }
            A[e] = o;
        }
        __syncthreads();
    }
}

// =====================================================================
// gj128_piv: partial-pivoted GJ of 128x128 in LDS; wave-0 shfl argmax.
// =====================================================================
__device__ void gj128_piv(float* __restrict__ A, float* __restrict__ pc, float* __restrict__ pr,
                          int* __restrict__ rec, int* __restrict__ ipv1)
{
    __syncthreads();
    const int tid = threadIdx.x;
    for (int p = 0; p < DZ; ++p) {
        if (tid < 64) {
            float best = -1.f; int bi = p;
            for (int i = tid; i < DZ; i += 64) {
                float v = (i >= p) ? fabsf(A[i*DZ + p]) : -2.f;
                if (v > best) { best = v; bi = i; }
            }
            for (int off = 32; off > 0; off >>= 1) {
                float ob = __shfl_xor(best, off);
                int obi = __shfl_xor(bi, off);
                if (ob > best) { best = ob; bi = obi; }
            }
            if (tid == 0) { rec[p] = bi; ipv1[0] = bi; }
        }
        __syncthreads();
        const int r = ipv1[0];
        if (r != p) {
            for (int j = tid; j < DZ; j += NT) { float t = A[p*DZ+j]; A[p*DZ+j] = A[r*DZ+j]; A[r*DZ+j] = t; }
            __syncthreads();
        }
        if (tid < DZ) { pc[tid] = A[tid*DZ + p]; pr[tid] = A[p*DZ + tid]; }
        __syncthreads();
        const float rp = 1.f / pr[p];
        for (int e = tid; e < MS; e += NT) {
            const int i = e >> 7, j = e & 127;
            const float pv = pr[j] * rp;
            float o;
            if (i == p) o = (j == p) ? rp : pv;
            else { const float fc = pc[i]; o = (j == p) ? (-fc*rp) : (A[e] - fc*pv); }
            A[e] = o;
        }
        __syncthreads();
    }
    for (int p = DZ - 1; p >= 0; --p) {
        const int r = rec[p];
        if (r != p) {
            for (int i = tid; i < DZ; i += NT) { float t = A[i*DZ+p]; A[i*DZ+p] = A[i*DZ+r]; A[i*DZ+r] = t; }
            __syncthreads();
        }
    }
    __syncthreads();
}

// =====================================================================
// phase1_dev: step map, slim form (||X|| ~ 1e-2 so deg-3 F and Y<=2 Q
// are exact to ~1e-9 rel):
//   F = I + g1 X + (g2 I + g3 X) X^2      -> Ft in L0 (LDS)
//   Q = h (g1 D + W1 D + D W1^T),  W1 = g2 X + g3 X^2   -> sq
//   c = h (g1 + g2 X + g3 X^2 + g4 X^3) eb               -> cvec
// Uses: sx = X, sx2/sx2t = X^2/X^2T (scratch); L1 = temp (M matrix).
// =====================================================================
__device__ void phase1_dev(int k,
    const float* __restrict__ A_s, const float* __restrict__ b_s,
    const float* __restrict__ Qch, const float* __restrict__ es, const float* __restrict__ ts,
    float* sx, float* sx2, float* sx2t, float* sq,
    float* L0, float* L1,
    float* W16, float* ebv, float* eqv, float* vvv, float* cvec,
    float g1, float g2, float g3, float g4)
{
    const int tid = threadIdx.x;
    const float h = ts[k] - ts[k-1];
    if (h <= 0.f) {
        __syncthreads();
        for (int e = tid; e < MS; e += NT) {
            int i = e >> 7, j = e & 127;
            L0[e] = (i==j) ? 1.f : 0.f;
            sq[e] = 0.f;
        }
        if (tid < DZ) cvec[tid] = 0.f;
        __syncthreads();
        return;
    }
    __syncthreads();
    if (tid < KMIX) W16[tid] = es[(size_t)k*KMIX + tid];
    __syncthreads();
    if (tid == 0) {
        float s = 0.f;
        for (int m = 0; m < KMIX; ++m) s += W16[m];
        float inv = 1.f/s;
        for (int m = 0; m < KMIX; ++m) W16[m] *= inv;
    }
    __syncthreads();
    if (tid < DZ) {
        float eb = 0.f, eq = 0.f;
        for (int m = 0; m < KMIX; ++m) {
            float wm = W16[m];
            eb = fmaf(wm, b_s[m*DZ+tid], eb);
            float qc = Qch[m*DZ+tid];
            eq = fmaf(wm, qc*qc, eq);
        }
        ebv[tid] = eb; eqv[tid] = eq;
    }
    // X = h * sum_m w_m A_s[m] -> L1 (X), sx (X), L0 (Xt)
    const int tx = tid & 31, ty = tid >> 5;
    const int i0 = ty*4, j0 = tx*4;
    float t16[16];
#pragma unroll
    for (int e = 0; e < 16; ++e) t16[e] = 0.f;
    for (int m = 0; m < KMIX; ++m) {
        float wm = W16[m];
        const float* Am = A_s + (size_t)m * MS;
#pragma unroll
        for (int a = 0; a < 4; ++a) {
            float4 p0 = *reinterpret_cast<const float4*>(&Am[(i0+a)*DZ + j0]);
            t16[a*4+0]=fmaf(wm,p0.x,t16[a*4+0]); t16[a*4+1]=fmaf(wm,p0.y,t16[a*4+1]);
            t16[a*4+2]=fmaf(wm,p0.z,t16[a*4+2]); t16[a*4+3]=fmaf(wm,p0.w,t16[a*4+3]);
        }
    }
#pragma unroll
    for (int a = 0; a < 4; ++a)
#pragma unroll
        for (int b = 0; b < 4; ++b) {
            float v = h * t16[a*4+b];
            L1[(i0+a)*DZ + (j0+b)] = v;
            sx[(i0+a)*DZ + (j0+b)] = v;
            L0[(j0+b)*DZ + (i0+a)] = v;
        }
    __syncthreads();
    // cvec: 3 power iterations (terms through g4 X^3)
    {
        float gg[5]; gg[1]=g1; gg[2]=g2; gg[3]=g3; gg[4]=g4;
        if (tid < DZ) vvv[tid] = ebv[tid];
        float creg = (tid < DZ) ? g1 * ebv[tid] : 0.f;
        __syncthreads();
        for (int m = 1; m <= 3; ++m) {
            float vn = 0.f;
            if (tid < DZ)
                for (int kk = 0; kk < DZ; ++kk)
                    vn = fmaf(L0[kk*DZ + tid], vvv[kk], vn);
            __syncthreads();
            if (tid < DZ) vvv[tid] = vn;
            creg = fmaf(gg[m+1], vn, creg);
            __syncthreads();
        }
        if (tid < DZ) cvec[tid] = h * creg;
    }
    // X2 (dual)
    mm_<128,128,128,0,true>(L0, L1, sx2, nullptr, sx2t);
    // fused: Q elementwise -> sq ; M^T = g2 I + g3 Xt -> L1
    for (int e = tid; e < MS; e += NT) {
        int j = e >> 7, i = e & 127;   // j=row, i=col
        float xt = L0[e];
        float w1  = g2*sx[e] + g3*sx2[e];
        float w1t = g2*xt    + g3*sx2t[e];
        float vq = w1*eqv[i] + eqv[j]*w1t;
        if (i == j) vq += g1*eqv[j];
        sq[e] = h * vq;
        L1[e] = g3*xt + ((i==j) ? g2 : 0.f);
    }
    __syncthreads();
    // Ft = X2^T M^T + g1 Xt + I  -> L0 (MODE 4, aux aliases out, per-tile safe)
    mm_<128,128,128,4,false>(sx2, L1, L0, L0, nullptr, g1);
}

#define SHARED_DECLS \
    __shared__ __align__(16) float L0[MS]; \
    __shared__ __align__(16) float L1[MS]; \
    __shared__ __align__(16) float SL[DX*DX]; \
    __shared__ float V0[DZ],V1[DZ],V2[DZ],V3[DZ],V4[DZ],V5[DZ]; \
    __shared__ float r64s[DX], u64s[DX]; \
    __shared__ float W16[KMIX], ebv[DZ], eqv[DZ], vvv[DZ], cvec[DZ]; \
    __shared__ float GJc[DZ], GJr[DZ]; \
    __shared__ int REC[DZ]; __shared__ int IPV1[1];

// =====================================================================
// prep: Ct, Rj, Rji, initial updated state (mu0u, p0u)
// =====================================================================
__global__ __launch_bounds__(NT) void kf_prep(
    const float* __restrict__ Cm, const float* __restrict__ Rm,
    const float* __restrict__ mu0, const float* __restrict__ P0,
    const float* __restrict__ xs,
    float* Ct, float* Rj, float* Rji, float* mu0u, float* p0u, float* scr)
{
    SHARED_DECLS
    const int tid = threadIdx.x;
    for (int i = tid; i < DZ*DX; i += NT) { int z = i>>6, m = i&63; Ct[i] = Cm[m*DZ + z]; }
    for (int i = tid; i < DX*DX; i += NT) {
        int a = i>>6, b = i&63;
        float v = Rm[i] + ((a==b) ? JITTER_C : 0.f);
        Rj[i] = v; SL[i] = v;
    }
    gj64_spd(SL, GJc, GJr);
    for (int i = tid; i < DX*DX; i += NT) Rji[i] = SL[i];
    float* z  = scr + SX;
    float* cp = scr + SX + DZ*DX;
    float* kt = scr + SX2;
    mm_<128,64,128,0,true>(P0, Ct, z, nullptr, cp);     // z = P0 C^T, cp = C P0
    mm_<64,64,128,3,false>(Ct, z, SL, Rj, nullptr);     // S0
    gj64_spd(SL, GJc, GJr);
    mm_<64,128,64,0,false>(SL, cp, kt, nullptr, nullptr); // K0^T
    mv_<64,128,2>(Ct, mu0, r64s, xs);                   // r = x0 - C mu0
    mv_<128,64,1>(kt, r64s, mu0u, mu0);                 // mu0u = mu0 + K0 r
    mm_<128,128,64,2,false>(kt, cp, p0u, P0, nullptr);  // P0u = P0 - K0 C P0
    __syncthreads();
    for (int e = tid; e < MS; e += NT) L0[e] = p0u[e];
    __syncthreads();
    for (int e = tid; e < MS; e += NT) {
        int i = e>>7, j = e&127;
        p0u[e] = 0.5f * (L0[e] + L0[j*DZ + i]);
    }
}

// =====================================================================
// pass A: per chunk, direct element recursion (predict + Woodbury update)
// =====================================================================
__global__ __launch_bounds__(NT) void kf_passA(
    const float* __restrict__ A_s, const float* __restrict__ b_s,
    const float* __restrict__ Qch, const float* __restrict__ es,
    const float* __restrict__ ts, const float* __restrict__ xs,
    const float* __restrict__ Ct, const float* __restrict__ Rj,
    const float* __restrict__ Rji,
    const float* __restrict__ mu0u, const float* __restrict__ p0u,
    float* elems, float* scr, int T, int LCH,
    float g1, float g2, float g3, float g4)
{
    SHARED_DECLS
    const int c = blockIdx.x, tid = threadIdx.x;
    float* sc = scr + (size_t)c * SCN;
    float* R = elems + (size_t)c * ESZ;
    float* RAs = R; float* RAts = R+MS; float* RCs = R+2*MS; float* RJs = R+3*MS;
    float* Rbs = R+4*MS; float* Rhs = R+4*MS+DZ;
    int eBeg = c*LCH, eEnd = (c*LCH + LCH < T) ? (c*LCH + LCH) : T;
    if (eBeg >= eEnd && c != 0) {
        for (int e = tid; e < MS; e += NT) {
            int i = e>>7, j = e&127; float id = (i==j)?1.f:0.f;
            RAs[e]=id; RAts[e]=id; RCs[e]=0.f; RJs[e]=0.f;
        }
        if (tid < DZ) { Rbs[tid]=0.f; Rhs[tid]=0.f; }
        return;
    }
    if (c == 0) {
        for (int e = tid; e < MS; e += NT) { RAs[e]=0.f; RCs[e]=p0u[e]; RJs[e]=0.f; }
        if (tid < DZ) { V0[tid]=mu0u[tid]; V5[tid]=0.f; }
        eBeg = 1;
    } else {
        for (int e = tid; e < MS; e += NT) {
            int i = e>>7, j = e&127;
            RAs[e] = (i==j)?1.f:0.f; RCs[e]=0.f; RJs[e]=0.f;
        }
        if (tid < DZ) { V0[tid]=0.f; V5[tid]=0.f; }
    }
    __syncthreads();
    float* sx = sc+SX; float* sx2 = sc+SX2; float* sx2t = sc+SX2T; float* sq = sc+SQ;
    float* z  = sx2t;  float* zt = sx2t + 8192;   // after X2T dead
    float* y  = sq;    float* hh = sq + 8192;     // after Q consumed
    float* h2 = sx;                                // after tA dead
    for (int e = eBeg; e < eEnd; ++e) {
        phase1_dev(e, A_s,b_s,Qch,es,ts, sx,sx2,sx2t,sq, L0,L1,
                   W16,ebv,eqv,vvv,cvec, g1,g2,g3,g4);
        // ---- predict-compose (EJ=0); Ft in L0 ----
        mm_<128,128,128,0,false>(L0, RAs, sx, nullptr, nullptr);   // tA = F RA  (X dead)
        mv_<128,128,1>(L0, V0, V1, cvec);                          // Rb' = F Rb + c
        mm_<128,128,128,0,false>(RCs, L0, sx2, nullptr, nullptr);  // tU = RC F^T (X2 dead)
        mm_<128,128,128,3,false>(L0, sx2, L1, sq, nullptr);        // L1 = RC' = F tU + Q
        // ---- update-compose (Woodbury on rank-64 J_u) ----
        mm_<128,64,128,0,true>(L1, Ct, z, nullptr, zt);            // Z = RC' C^T (dual)
        mm_<64,64,128,3,false>(Ct, z, SL, Rj, nullptr);            // S~ = R~ + C Z
        gj64_spd(SL, GJc, GJr);                                    // SL = S~^-1
        mm_<64,128,128,0,false>(Ct, sx, y, nullptr, nullptr);      // Y = C tA (Q dead)
        mm_<64,128,64,0,false>(SL, y, hh, nullptr, nullptr);       // H = Si Y
        mm_<128,128,64,2,false>(zt, hh, RAs, sx, nullptr);         // RA'' = tA - Z H
        mm_<128,128,64,1,false>(y, hh, RJs, nullptr, nullptr);     // RJ += Y^T H
        mm_<64,128,64,0,false>(SL, zt, h2, nullptr, nullptr);      // h2 = Si Z^T (tA dead)
        mm_<128,128,64,2,false>(zt, h2, RCs, L1, nullptr);         // RC'' = RC' - Z h2
        // vectors
        mv_<64,128,2>(Ct, V1, r64s, xs + (size_t)e*DX);            // r = x - C Rb'
        mv_<64,64,0>(Rji, xs + (size_t)e*DX, u64s, nullptr);       // u = R~i x
        mv_<128,64,1>(zt, u64s, V2, V1);                           // v1 = Rb' + Z u
        mv_<64,128,0>(Ct, V2, GJc, nullptr);                       // w = C v1
        mv_<64,64,0>(SL, GJc, GJr, nullptr);                       // w2 = Si w
        mv_<128,64,2>(zt, GJr, V0, V2);                            // Rb'' = v1 - Z w2
        mv_<64,64,0>(SL, r64s, u64s, nullptr);                     // s = Si r
        mv_<128,64,1>(y, u64s, V5, V5);                            // Reta += Y^T s
    }
    __syncthreads();
    if (tid < DZ) { Rbs[tid] = V0[tid]; Rhs[tid] = V5[tid]; }
    trans_g(RAs, RAts, L0);
}

// =====================================================================
// combine: Rd <- Rd (earlier) (x) E (later).  lastj: only RC/Rb needed.
// =====================================================================
__device__ void combine(float* Rd,
    const float* EA, const float* EAt, const float* EC, const float* EJ,
    const float* Ebg, const float* Ehg,
    float* t1, float* t2, float* t3,
    float* L0, float* L1,
    float* V0, float* V1, float* V2, float* V3, float* V4, float* V5,
    float* GJc, float* GJr, int* REC, int* IPV1, int lastj)
{
    float* RA = Rd; float* RAt = Rd+MS; float* RC = Rd+2*MS; float* RJ = Rd+3*MS;
    float* Rb = Rd+4*MS; float* Rh = Rd+4*MS+DZ;
    const int tid = threadIdx.x;
    __syncthreads();
    if (tid < DZ) { V0[tid]=Ebg[tid]; V1[tid]=Ehg[tid]; V2[tid]=Rb[tid]; }
    mm_<128,128,128,0,false>(EJ, RC, L0, nullptr, nullptr);    // L0 = EJ RC
    if (tid < DZ) L0[tid*DZ + tid] += 1.f;                     // M^T
    gj128_piv(L0, GJc, GJr, REC, IPV1);                        // L0 = M^-T
    if (!lastj) {
        mm_<128,128,128,0,false>(L0, RA, t1, nullptr, nullptr);    // t1 = Minv RA
        mm_<128,128,128,0,false>(EJ, RA, t2, nullptr, nullptr);    // t2 = EJ RA
        mm_<128,128,128,1,false>(t1, t2, RJ, nullptr, nullptr);    // RJ += t1^T t2
        mv_<128,128,2>(EJ, V2, V4, V1);                            // w1 = Eh - EJ Rb
        mv_<128,128,1>(t1, V4, Rh, Rh);                            // Rh += t1^T w1
    }
    mv_<128,128,1>(RC, V1, V3, V2);                            // v1 = Rb + RC Eh
    mv_<128,128,0>(L0, V3, V5, nullptr);                       // z1 = Minv v1
    mv_<128,128,1>(EAt, V5, Rb, V0);                           // Rb = Eb + EA z1
    mm_<128,128,128,0,false>(L0, RC, t3, nullptr, nullptr);    // t3 = Minv RC
    mm_<128,128,128,0,false>(t3, EAt, t2, nullptr, nullptr);   // t2 = (Minv RC)^T EA^T
    mm_<128,128,128,3,false>(EAt, t2, RC, EC, nullptr);        // RC = EA t2 + EC
    if (!lastj) {
        mm_<128,128,128,0,false>(EAt, t1, RA, nullptr, nullptr);   // RA = EA t1
        trans_g(RA, RAt, L1);
    }
}

// =====================================================================
// Kogge-Stone scan round
// =====================================================================
__global__ __launch_bounds__(NT) void kf_scan(
    const float* __restrict__ in, float* __restrict__ out, float* scr, int r, int lastj)
{
    SHARED_DECLS
    const int c = blockIdx.x;
    float* sc = scr + (size_t)c * SCN;
    float* dst = out + (size_t)c * ESZ;
    const float* src = in + (size_t)((c >= r) ? (c - r) : c) * ESZ;
    if (lastj) {
        for (int e = threadIdx.x; e < MS; e += NT) dst[2*MS + e] = src[2*MS + e];
        for (int e = threadIdx.x; e < DZ; e += NT) dst[4*MS + e] = src[4*MS + e];
    } else {
        for (int e = threadIdx.x; e < ESZ; e += NT) dst[e] = src[e];
    }
    if (c >= r) {
        const float* E = in + (size_t)c * ESZ;
        combine(dst, E, E+MS, E+2*MS, E+3*MS, E+4*MS, E+4*MS+DZ,
                sc+SP, sc+SX, sc+SX2, L0, L1,
                V0,V1,V2,V3,V4,V5, GJc, GJr, REC, IPV1, lastj);
    }
}

// =====================================================================
// pass C: per chunk, plain filter from exact boundary state; writes outputs
// =====================================================================
__global__ __launch_bounds__(NT) void kf_passC(
    const float* __restrict__ A_s, const float* __restrict__ b_s,
    const float* __restrict__ Qch, const float* __restrict__ es,
    const float* __restrict__ ts, const float* __restrict__ xs,
    const float* __restrict__ Ct, const float* __restrict__ Rj,
    const float* __restrict__ mu0u, const float* __restrict__ p0u,
    const float* __restrict__ pfx,
    float* mu_out, float* P_out, float* scr, int T, int LCH,
    float g1, float g2, float g3, float g4)
{
    SHARED_DECLS
    const int c = blockIdx.x, tid = threadIdx.x;
    float* sc = scr + (size_t)c * SCN;
    float* P = sc + SP;
    int eBeg = c*LCH, eEnd = (c*LCH + LCH < T) ? (c*LCH + LCH) : T;
    if (eBeg >= eEnd && c != 0) return;
    if (c == 0) {
        for (int e = tid; e < MS; e += NT) { float v = p0u[e]; P[e] = v; P_out[e] = v; }
        if (tid < DZ) { V0[tid] = mu0u[tid]; mu_out[tid] = mu0u[tid]; }
        eBeg = 1;
    } else {
        const float* X = pfx + (size_t)(c-1) * ESZ;
        for (int e = tid; e < MS; e += NT) P[e] = X[2*MS + e];
        if (tid < DZ) V0[tid] = X[4*MS + tid];
    }
    __syncthreads();
    float* sx = sc+SX; float* sx2 = sc+SX2; float* sx2t = sc+SX2T; float* sq = sc+SQ;
    float* z  = sx2t;  float* zt = sx2t + 8192;
    for (int e = eBeg; e < eEnd; ++e) {
        phase1_dev(e, A_s,b_s,Qch,es,ts, sx,sx2,sx2t,sq, L0,L1,
                   W16,ebv,eqv,vvv,cvec, g1,g2,g3,g4);
        mm_<128,128,128,0,false>(P, L0, sx, nullptr, nullptr);     // U = P F^T (X dead)
        mm_<128,128,128,3,false>(L0, sx, sx2, sq, nullptr);        // Ppr = F U + Q (X2 dead)
        mv_<128,128,1>(L0, V0, V1, cvec);                          // mupr = F mu + c
        mm_<128,64,128,0,true>(sx2, Ct, z, nullptr, zt);           // Z = Ppr C^T (dual)
        mm_<64,64,128,3,false>(Ct, z, SL, Rj, nullptr);            // S
        gj64_spd(SL, GJc, GJr);
        mm_<64,128,64,0,false>(SL, zt, sq, nullptr, nullptr);      // kt = Si Z^T (Q dead)
        mv_<64,128,2>(Ct, V1, r64s, xs + (size_t)e*DX);            // y = x - C mupr
        mv_<128,64,1>(sq, r64s, V0, V1);                           // mu = mupr + K y
        if (tid < DZ) mu_out[(size_t)e*DZ + tid] = V0[tid];
        mm_<128,128,64,2,false>(zt, sq, L1, sx2, nullptr);         // P_u = Ppr - Z kt
        float* po = P_out + (size_t)e * MS;
        for (int ee = tid; ee < MS; ee += NT) {
            int i = ee>>7, j = ee&127;
            float v = 0.5f * (L1[ee] + L1[j*DZ + i]);
            P[ee] = v; po[ee] = v;
        }
        __syncthreads();
    }
}

// =====================================================================
// host: RK stability polynomial coefficients
// =====================================================================
static void compute_gamma(double g[7])
{
    const double A[6][5] = {
        {0, 0, 0, 0, 0},
        {0.161, 0, 0, 0, 0},
        {-0.008480655492356989, 0.335480655492357, 0, 0, 0},
        {2.8971530571054935, -6.359448489975075, 4.3622954328695815, 0, 0},
        {5.325864828439257, -11.748883564062828, 7.4955393428898365, -0.09249506636175525, 0},
        {5.86145544294642, -12.92096931784711, 8.159367898576159, -0.071584973281401, -0.028269050394068383}};
    const double B[6] = {0.09646076681806523, 0.01, 0.4798896504144996,
                         1.379008574103742, -3.290069515436081, 2.324710524099774};
    double e[6][6];
    for (int i = 0; i < 6; ++i)
        for (int d = 0; d < 6; ++d) e[i][d] = 0.0;
    for (int i = 0; i < 6; ++i) {
        e[i][0] = 1.0;
        for (int j = 0; j < i; ++j)
            for (int d = 0; d < 5; ++d)
                e[i][d + 1] += A[i][j] * e[j][d];
    }
    g[0] = 1.0;
    for (int m = 1; m <= 6; ++m) {
        double s = 0.0;
        for (int i = 0; i < 6; ++i) s += B[i] * e[i][m - 1];
        g[m] = s;
    }
}

extern "C" void kernel_launch(void* const* d_in, const int* in_sizes, int n_in,
                              void* d_out, int out_size, void* d_ws, size_t ws_size,
                              hipStream_t stream)
{
    const float* xs  = (const float*)d_in[0];
    const float* ts  = (const float*)d_in[1];
    const float* es  = (const float*)d_in[2];
    const float* mu0 = (const float*)d_in[3];
    const float* P0  = (const float*)d_in[4];
    const float* A_s = (const float*)d_in[5];
    const float* b_s = (const float*)d_in[6];
    const float* Qch = (const float*)d_in[7];
    const float* Cm  = (const float*)d_in[8];
    const float* Rm  = (const float*)d_in[9];
    const int T = in_sizes[1];

    float* mu_out = (float*)d_out;
    float* P_out  = mu_out + (size_t)T * DZ;

    float* ws = (float*)d_ws;
    float* Ct    = ws;                        // 8192
    float* Rj    = ws + 8192;                 // 4096
    float* Rji   = ws + 12288;                // 4096
    float* mu0u  = ws + 16384;                // 128
    float* p0u   = ws + 16512;                // 16384
    float* elemsA = ws + 32896;
    float* elemsB = elemsA + (size_t)NCH * ESZ;
    float* scr    = elemsB + (size_t)NCH * ESZ;

    const int LCH = (T + NCH - 1) / NCH;

    double g[7];
    compute_gamma(g);
    const float g1 = (float)g[1], g2 = (float)g[2], g3 = (float)g[3], g4 = (float)g[4];

    hipLaunchKernelGGL(kf_prep, dim3(1), dim3(NT), 0, stream,
                       Cm, Rm, mu0, P0, xs, Ct, Rj, Rji, mu0u, p0u, scr);
    hipLaunchKernelGGL(kf_passA, dim3(NCH), dim3(NT), 0, stream,
                       A_s, b_s, Qch, es, ts, xs, Ct, Rj, Rji, mu0u, p0u,
                       elemsA, scr, T, LCH, g1, g2, g3, g4);
    float* bufs[2] = {elemsA, elemsB};
    int cur = 0;
    for (int r = 1; r < NCH; r <<= 1) {
        const int lastj = ((r << 1) >= NCH) ? 1 : 0;
        hipLaunchKernelGGL(kf_scan, dim3(NCH), dim3(NT), 0, stream,
                           bufs[cur], bufs[cur ^ 1], scr, r, lastj);
        cur ^= 1;
    }
    hipLaunchKernelGGL(kf_passC, dim3(NCH), dim3(NT), 0, stream,
                       A_s, b_s, Qch, es, ts, xs, Ct, Rj, mu0u, p0u,
                       bufs[cur], mu_out, P_out, scr, T, LCH, g1, g2, g3, g4);
}

// Round 8
// 11930.506 us; speedup vs baseline: 23.9027x; 1.1035x over previous
//
#include <hip/hip_runtime.h>
#include <math.h>

#define DZ 128
#define DX 64
#define KMIX 16
#define JITTER_C 1e-4f
#define MS (DZ*DZ)            // 16384
#define ESZ (4*MS + 2*DZ)     // element: A, At, C, J, b, eta
#define NCH 256               // chunks
#define NT 1024               // threads per block (16 waves, 4/SIMD)
#define SCN (5*MS + 256)      // per-chunk scratch floats

// scr slot offsets (per chunk)
#define SP   0
#define SX   (1*MS)
#define SX2  (2*MS)
#define SX2T (3*MS)
#define SQ   (4*MS)

// =====================================================================
// mm_: out[MxN] = op( sum_k At[k*M+i] * B[k*N+j] )  i.e. out = (At)^T*B
// MODE 0: store; 1: out += acc; 2: out = aux - acc; 3: out = aux + acc
// MODE 4: out = acc + e1*aux + I   (aux may alias out; per-thread tiles)
// DUAL: additionally store transposed result to outT (N x M).
// NT=1024 threads, 32x32 grid, per-thread tile (M/32)x(N/32).
// =====================================================================
template<int M, int N, int K, int MODE, bool DUAL>
__device__ void mm_(const float* __restrict__ At, const float* __restrict__ B,
                    float* __restrict__ out, const float* __restrict__ aux,
                    float* __restrict__ outT, float e1 = 0.f)
{
    __syncthreads();
    const int tid = threadIdx.x;
    constexpr int TM = M/32, TN = N/32;
    const int tx = tid & 31, ty = tid >> 5;
    const int i0 = ty*TM, j0 = tx*TN;
    float acc[TM*TN];
#pragma unroll
    for (int e = 0; e < TM*TN; ++e) acc[e] = 0.f;
#pragma unroll 8
    for (int k = 0; k < K; ++k) {
        const float* ar = At + k*M + i0;
        const float* br = B + k*N + j0;
        float av[TM], bv[TN];
        if constexpr (TM == 2) {
            float2 t = *reinterpret_cast<const float2*>(ar);
            av[0]=t.x; av[1]=t.y;
        } else {
#pragma unroll
            for (int a = 0; a < TM; a += 4) {
                float4 t = *reinterpret_cast<const float4*>(ar + a);
                av[a]=t.x; av[a+1]=t.y; av[a+2]=t.z; av[a+3]=t.w;
            }
        }
        if constexpr (TN == 2) {
            float2 t = *reinterpret_cast<const float2*>(br);
            bv[0]=t.x; bv[1]=t.y;
        } else {
#pragma unroll
            for (int b = 0; b < TN; b += 4) {
                float4 t = *reinterpret_cast<const float4*>(br + b);
                bv[b]=t.x; bv[b+1]=t.y; bv[b+2]=t.z; bv[b+3]=t.w;
            }
        }
#pragma unroll
        for (int a = 0; a < TM; ++a)
#pragma unroll
            for (int b = 0; b < TN; ++b)
                acc[a*TN+b] = fmaf(av[a], bv[b], acc[a*TN+b]);
    }
#pragma unroll
    for (int a = 0; a < TM; ++a) {
#pragma unroll
        for (int b = 0; b < TN; ++b) {
            const int row = i0+a, col = j0+b;
            const int idx = row*N + col;
            float v = acc[a*TN+b];
            if constexpr (MODE == 1) v += out[idx];
            else if constexpr (MODE == 2) v = aux[idx] - v;
            else if constexpr (MODE == 3) v += aux[idx];
            else if constexpr (MODE == 4) { v += e1*aux[idx]; if (row==col) v += 1.f; }
            out[idx] = v;
            acc[a*TN+b] = v;
        }
    }
    if constexpr (DUAL) {
#pragma unroll
        for (int b = 0; b < TN; ++b) {
#pragma unroll
            for (int a = 0; a < TM; a += 4) {
                float4 v = make_float4(acc[(a)*TN+b], acc[(a+1)*TN+b], acc[(a+2)*TN+b], acc[(a+3)*TN+b]);
                *reinterpret_cast<float4*>(outT + (j0+b)*M + i0 + a) = v;
            }
        }
    }
    __syncthreads();
}

// =====================================================================
// mv_: out[i] = op(aux[i], sum_k At[k*M+i]*v[k]) for i = tid < M
// MODE 0: sum; 1: aux + sum; 2: aux - sum
// =====================================================================
template<int M, int K, int MODE>
__device__ void mv_(const float* __restrict__ At, const float* __restrict__ v,
                    float* __restrict__ out, const float* __restrict__ aux)
{
    __syncthreads();
    const int tid = threadIdx.x;
    if (tid < M) {
        float s = 0.f;
        for (int k = 0; k < K; ++k)
            s = fmaf(At[k*M + tid], v[k], s);
        float r;
        if constexpr (MODE == 0) r = s;
        else if constexpr (MODE == 1) r = aux[tid] + s;
        else r = aux[tid] - s;
        out[tid] = r;
    }
    __syncthreads();
}

// dst[NxM] = src[MxN]^T via LDS bounce (128x128 only)
__device__ void trans_g(const float* __restrict__ src, float* __restrict__ dst,
                        float* __restrict__ Lb)
{
    __syncthreads();
    for (int e = threadIdx.x; e < MS; e += NT) Lb[e] = src[e];
    __syncthreads();
    for (int e = threadIdx.x; e < MS; e += NT) {
        int j = e >> 7, i = e & 127;
        dst[e] = Lb[i*DZ + j];
    }
    __syncthreads();
}

// =====================================================================
// gj64_spd: rank-4 block Gauss-Jordan inverse of SPD 64x64 in LDS.
// Unpivoted (leading blocks of SPD Schur complements are PD).
// st: LDS scratch >= 512 floats. 16 iters x 2 barriers (vs 128).
// =====================================================================
__device__ void gj64_spd(float* __restrict__ A, float* __restrict__ st)
{
    const int tid = threadIdx.x;
    for (int p = 0; p < DX; p += 4) {
        __syncthreads();
        // stage Pc = A[:, p:p+4] (row-major st[i*4+b]) and Pr = A[p:p+4, :] (st[256+b*64+j])
        if (tid < 64) {
#pragma unroll
            for (int b = 0; b < 4; ++b) st[tid*4+b] = A[tid*DX + p + b];
        } else if (tid < 128) {
            int j = tid - 64;
#pragma unroll
            for (int b = 0; b < 4; ++b) st[256 + b*64 + j] = A[(p+b)*DX + j];
        }
        __syncthreads();
        // every thread redundantly inverts the 4x4 pivot block D
        float Dm[16], Di[16];
#pragma unroll
        for (int a = 0; a < 4; ++a)
#pragma unroll
            for (int b = 0; b < 4; ++b) {
                Dm[a*4+b] = st[(p+a)*4 + b];
                Di[a*4+b] = (a==b) ? 1.f : 0.f;
            }
#pragma unroll
        for (int q = 0; q < 4; ++q) {
            float rp = 1.f / Dm[q*4+q];
#pragma unroll
            for (int j = 0; j < 4; ++j) { Dm[q*4+j] *= rp; Di[q*4+j] *= rp; }
#pragma unroll
            for (int i = 0; i < 4; ++i) {
                if (i == q) continue;
                float f = Dm[i*4+q];
#pragma unroll
                for (int j = 0; j < 4; ++j) { Dm[i*4+j] = fmaf(-f, Dm[q*4+j], Dm[i*4+j]); Di[i*4+j] = fmaf(-f, Di[q*4+j], Di[i*4+j]); }
            }
        }
        // block-GJ update
        for (int e = tid; e < DX*DX; e += NT) {
            const int i = e >> 6, j = e & 63;
            const bool iP = (i >= p) && (i < p+4);
            const bool jP = (j >= p) && (j < p+4);
            float o;
            if (iP && jP) {
                o = Di[(i-p)*4 + (j-p)];
            } else if (iP) {
                const int a = i - p;
                o = Di[a*4+0]*st[256+0*64+j] + Di[a*4+1]*st[256+1*64+j]
                  + Di[a*4+2]*st[256+2*64+j] + Di[a*4+3]*st[256+3*64+j];
            } else {
                float Ei[4];
#pragma unroll
                for (int b = 0; b < 4; ++b)
                    Ei[b] = st[i*4+0]*Di[0*4+b] + st[i*4+1]*Di[1*4+b]
                          + st[i*4+2]*Di[2*4+b] + st[i*4+3]*Di[3*4+b];
                if (jP) o = -Ei[j-p];
                else    o = A[e] - (Ei[0]*st[256+0*64+j] + Ei[1]*st[256+1*64+j]
                                  + Ei[2]*st[256+2*64+j] + Ei[3]*st[256+3*64+j]);
            }
            A[e] = o;
        }
    }
    __syncthreads();
}

// =====================================================================
// gj128_piv: partial-pivoted GJ of 128x128 in LDS; wave-0 shfl argmax.
// =====================================================================
__device__ void gj128_piv(float* __restrict__ A, float* __restrict__ pc, float* __restrict__ pr,
                          int* __restrict__ rec, int* __restrict__ ipv1)
{
    __syncthreads();
    const int tid = threadIdx.x;
    for (int p = 0; p < DZ; ++p) {
        if (tid < 64) {
            float best = -1.f; int bi = p;
            for (int i = tid; i < DZ; i += 64) {
                float v = (i >= p) ? fabsf(A[i*DZ + p]) : -2.f;
                if (v > best) { best = v; bi = i; }
            }
            for (int off = 32; off > 0; off >>= 1) {
                float ob = __shfl_xor(best, off);
                int obi = __shfl_xor(bi, off);
                if (ob > best) { best = ob; bi = obi; }
            }
            if (tid == 0) { rec[p] = bi; ipv1[0] = bi; }
        }
        __syncthreads();
        const int r = ipv1[0];
        if (r != p) {
            for (int j = tid; j < DZ; j += NT) { float t = A[p*DZ+j]; A[p*DZ+j] = A[r*DZ+j]; A[r*DZ+j] = t; }
            __syncthreads();
        }
        if (tid < DZ) { pc[tid] = A[tid*DZ + p]; pr[tid] = A[p*DZ + tid]; }
        __syncthreads();
        const float rp = 1.f / pr[p];
        for (int e = tid; e < MS; e += NT) {
            const int i = e >> 7, j = e & 127;
            const float pv = pr[j] * rp;
            float o;
            if (i == p) o = (j == p) ? rp : pv;
            else { const float fc = pc[i]; o = (j == p) ? (-fc*rp) : (A[e] - fc*pv); }
            A[e] = o;
        }
        __syncthreads();
    }
    for (int p = DZ - 1; p >= 0; --p) {
        const int r = rec[p];
        if (r != p) {
            for (int i = tid; i < DZ; i += NT) { float t = A[i*DZ+p]; A[i*DZ+p] = A[i*DZ+r]; A[i*DZ+r] = t; }
            __syncthreads();
        }
    }
    __syncthreads();
}

// =====================================================================
// phase1_dev: slim step map (||X|| ~ 1e-2):
//   F = I + g1 X + (g2 I + g3 X) X^2      -> Ft in L0 (LDS)
//   Q = h (g1 D + W1 D + D W1^T),  W1 = g2 X + g3 X^2   -> sq
//   c = h (g1 + g2 X + g3 X^2 + g4 X^3) eb               -> cvec
// =====================================================================
__device__ void phase1_dev(int k,
    const float* __restrict__ A_s, const float* __restrict__ b_s,
    const float* __restrict__ Qch, const float* __restrict__ es, const float* __restrict__ ts,
    float* sx, float* sx2, float* sx2t, float* sq,
    float* L0, float* L1,
    float* W16, float* ebv, float* eqv, float* vvv, float* cvec,
    float g1, float g2, float g3, float g4)
{
    const int tid = threadIdx.x;
    const float h = ts[k] - ts[k-1];
    if (h <= 0.f) {
        __syncthreads();
        for (int e = tid; e < MS; e += NT) {
            int i = e >> 7, j = e & 127;
            L0[e] = (i==j) ? 1.f : 0.f;
            sq[e] = 0.f;
        }
        if (tid < DZ) cvec[tid] = 0.f;
        __syncthreads();
        return;
    }
    __syncthreads();
    if (tid < KMIX) W16[tid] = es[(size_t)k*KMIX + tid];
    __syncthreads();
    if (tid == 0) {
        float s = 0.f;
        for (int m = 0; m < KMIX; ++m) s += W16[m];
        float inv = 1.f/s;
        for (int m = 0; m < KMIX; ++m) W16[m] *= inv;
    }
    __syncthreads();
    if (tid < DZ) {
        float eb = 0.f, eq = 0.f;
        for (int m = 0; m < KMIX; ++m) {
            float wm = W16[m];
            eb = fmaf(wm, b_s[m*DZ+tid], eb);
            float qc = Qch[m*DZ+tid];
            eq = fmaf(wm, qc*qc, eq);
        }
        ebv[tid] = eb; eqv[tid] = eq;
    }
    // X = h * sum_m w_m A_s[m] -> L1 (X), sx (X), L0 (Xt)
    const int tx = tid & 31, ty = tid >> 5;
    const int i0 = ty*4, j0 = tx*4;
    float t16[16];
#pragma unroll
    for (int e = 0; e < 16; ++e) t16[e] = 0.f;
    for (int m = 0; m < KMIX; ++m) {
        float wm = W16[m];
        const float* Am = A_s + (size_t)m * MS;
#pragma unroll
        for (int a = 0; a < 4; ++a) {
            float4 p0 = *reinterpret_cast<const float4*>(&Am[(i0+a)*DZ + j0]);
            t16[a*4+0]=fmaf(wm,p0.x,t16[a*4+0]); t16[a*4+1]=fmaf(wm,p0.y,t16[a*4+1]);
            t16[a*4+2]=fmaf(wm,p0.z,t16[a*4+2]); t16[a*4+3]=fmaf(wm,p0.w,t16[a*4+3]);
        }
    }
#pragma unroll
    for (int a = 0; a < 4; ++a)
#pragma unroll
        for (int b = 0; b < 4; ++b) {
            float v = h * t16[a*4+b];
            L1[(i0+a)*DZ + (j0+b)] = v;
            sx[(i0+a)*DZ + (j0+b)] = v;
            L0[(j0+b)*DZ + (i0+a)] = v;
        }
    __syncthreads();
    // cvec: 3 power iterations (terms through g4 X^3)
    {
        float gg[5]; gg[1]=g1; gg[2]=g2; gg[3]=g3; gg[4]=g4;
        if (tid < DZ) vvv[tid] = ebv[tid];
        float creg = (tid < DZ) ? g1 * ebv[tid] : 0.f;
        __syncthreads();
        for (int m = 1; m <= 3; ++m) {
            float vn = 0.f;
            if (tid < DZ)
                for (int kk = 0; kk < DZ; ++kk)
                    vn = fmaf(L0[kk*DZ + tid], vvv[kk], vn);
            __syncthreads();
            if (tid < DZ) vvv[tid] = vn;
            creg = fmaf(gg[m+1], vn, creg);
            __syncthreads();
        }
        if (tid < DZ) cvec[tid] = h * creg;
    }
    // X2 (dual)
    mm_<128,128,128,0,true>(L0, L1, sx2, nullptr, sx2t);
    // fused: Q elementwise -> sq ; M^T = g2 I + g3 Xt -> L1
    for (int e = tid; e < MS; e += NT) {
        int j = e >> 7, i = e & 127;   // j=row, i=col
        float xt = L0[e];
        float w1  = g2*sx[e] + g3*sx2[e];
        float w1t = g2*xt    + g3*sx2t[e];
        float vq = w1*eqv[i] + eqv[j]*w1t;
        if (i == j) vq += g1*eqv[j];
        sq[e] = h * vq;
        L1[e] = g3*xt + ((i==j) ? g2 : 0.f);
    }
    __syncthreads();
    // Ft = X2^T M^T + g1 Xt + I  -> L0 (MODE 4, aux aliases out, per-tile safe)
    mm_<128,128,128,4,false>(sx2, L1, L0, L0, nullptr, g1);
}

#define SHARED_DECLS \
    __shared__ __align__(16) float L0[MS]; \
    __shared__ __align__(16) float L1[MS]; \
    __shared__ __align__(16) float SL[DX*DX]; \
    __shared__ __align__(16) float GJB[520]; \
    __shared__ float V0[DZ],V1[DZ],V2[DZ],V3[DZ],V4[DZ],V5[DZ]; \
    __shared__ float r64s[DX], u64s[DX]; \
    __shared__ float W16[KMIX], ebv[DZ], eqv[DZ], vvv[DZ], cvec[DZ]; \
    __shared__ float GJc[DZ], GJr[DZ]; \
    __shared__ int REC[DZ]; __shared__ int IPV1[1];

// =====================================================================
// prep: Ct, Rj, Rji, initial updated state (mu0u, p0u)
// =====================================================================
__global__ __launch_bounds__(NT) void kf_prep(
    const float* __restrict__ Cm, const float* __restrict__ Rm,
    const float* __restrict__ mu0, const float* __restrict__ P0,
    const float* __restrict__ xs,
    float* Ct, float* Rj, float* Rji, float* mu0u, float* p0u, float* scr)
{
    SHARED_DECLS
    const int tid = threadIdx.x;
    for (int i = tid; i < DZ*DX; i += NT) { int z = i>>6, m = i&63; Ct[i] = Cm[m*DZ + z]; }
    for (int i = tid; i < DX*DX; i += NT) {
        int a = i>>6, b = i&63;
        float v = Rm[i] + ((a==b) ? JITTER_C : 0.f);
        Rj[i] = v; SL[i] = v;
    }
    gj64_spd(SL, GJB);
    for (int i = tid; i < DX*DX; i += NT) Rji[i] = SL[i];
    float* z  = scr + SX;
    float* cp = scr + SX + DZ*DX;
    float* kt = scr + SX2;
    mm_<128,64,128,0,true>(P0, Ct, z, nullptr, cp);     // z = P0 C^T, cp = C P0
    mm_<64,64,128,3,false>(Ct, z, SL, Rj, nullptr);     // S0
    gj64_spd(SL, GJB);
    mm_<64,128,64,0,false>(SL, cp, kt, nullptr, nullptr); // K0^T
    mv_<64,128,2>(Ct, mu0, r64s, xs);                   // r = x0 - C mu0
    mv_<128,64,1>(kt, r64s, mu0u, mu0);                 // mu0u = mu0 + K0 r
    mm_<128,128,64,2,false>(kt, cp, p0u, P0, nullptr);  // P0u = P0 - K0 C P0
    __syncthreads();
    for (int e = tid; e < MS; e += NT) L0[e] = p0u[e];
    __syncthreads();
    for (int e = tid; e < MS; e += NT) {
        int i = e>>7, j = e&127;
        p0u[e] = 0.5f * (L0[e] + L0[j*DZ + i]);
    }
}

// =====================================================================
// pass A: per chunk, direct element recursion (predict + Woodbury update)
// Z/Zt live in L0 (Ft dead after predict) — 5 consumers read LDS.
// =====================================================================
__global__ __launch_bounds__(NT) void kf_passA(
    const float* __restrict__ A_s, const float* __restrict__ b_s,
    const float* __restrict__ Qch, const float* __restrict__ es,
    const float* __restrict__ ts, const float* __restrict__ xs,
    const float* __restrict__ Ct, const float* __restrict__ Rj,
    const float* __restrict__ Rji,
    const float* __restrict__ mu0u, const float* __restrict__ p0u,
    float* elems, float* scr, int T, int LCH,
    float g1, float g2, float g3, float g4)
{
    SHARED_DECLS
    const int c = blockIdx.x, tid = threadIdx.x;
    float* sc = scr + (size_t)c * SCN;
    float* R = elems + (size_t)c * ESZ;
    float* RAs = R; float* RAts = R+MS; float* RCs = R+2*MS; float* RJs = R+3*MS;
    float* Rbs = R+4*MS; float* Rhs = R+4*MS+DZ;
    int eBeg = c*LCH, eEnd = (c*LCH + LCH < T) ? (c*LCH + LCH) : T;
    if (eBeg >= eEnd && c != 0) {
        for (int e = tid; e < MS; e += NT) {
            int i = e>>7, j = e&127; float id = (i==j)?1.f:0.f;
            RAs[e]=id; RAts[e]=id; RCs[e]=0.f; RJs[e]=0.f;
        }
        if (tid < DZ) { Rbs[tid]=0.f; Rhs[tid]=0.f; }
        return;
    }
    if (c == 0) {
        for (int e = tid; e < MS; e += NT) { RAs[e]=0.f; RCs[e]=p0u[e]; RJs[e]=0.f; }
        if (tid < DZ) { V0[tid]=mu0u[tid]; V5[tid]=0.f; }
        eBeg = 1;
    } else {
        for (int e = tid; e < MS; e += NT) {
            int i = e>>7, j = e&127;
            RAs[e] = (i==j)?1.f:0.f; RCs[e]=0.f; RJs[e]=0.f;
        }
        if (tid < DZ) { V0[tid]=0.f; V5[tid]=0.f; }
    }
    __syncthreads();
    float* sx = sc+SX; float* sx2 = sc+SX2; float* sx2t = sc+SX2T; float* sq = sc+SQ;
    float* z  = L0;    float* zt = L0 + 8192;     // LDS-resident after Ft dead
    float* y  = sq;    float* hh = sq + 8192;     // after Q consumed
    float* h2 = sx;                                // after tA dead
    for (int e = eBeg; e < eEnd; ++e) {
        phase1_dev(e, A_s,b_s,Qch,es,ts, sx,sx2,sx2t,sq, L0,L1,
                   W16,ebv,eqv,vvv,cvec, g1,g2,g3,g4);
        // ---- predict-compose (EJ=0); Ft in L0 ----
        mm_<128,128,128,0,false>(L0, RAs, sx, nullptr, nullptr);   // tA = F RA  (X dead)
        mv_<128,128,1>(L0, V0, V1, cvec);                          // Rb' = F Rb + c
        mm_<128,128,128,0,false>(RCs, L0, sx2, nullptr, nullptr);  // tU = RC F^T (X2 dead)
        mm_<128,128,128,3,false>(L0, sx2, L1, sq, nullptr);        // L1 = RC' = F tU + Q
        // ---- update-compose (Woodbury on rank-64 J_u); Z/Zt -> L0 ----
        mm_<128,64,128,0,true>(L1, Ct, z, nullptr, zt);            // Z = RC' C^T (dual, LDS)
        mm_<64,64,128,3,false>(Ct, z, SL, Rj, nullptr);            // S~ = R~ + C Z
        gj64_spd(SL, GJB);                                         // SL = S~^-1
        mm_<64,128,128,0,false>(Ct, sx, y, nullptr, nullptr);      // Y = C tA (Q dead)
        mm_<64,128,64,0,false>(SL, y, hh, nullptr, nullptr);       // H = Si Y
        mm_<128,128,64,2,false>(zt, hh, RAs, sx, nullptr);         // RA'' = tA - Z H
        mm_<128,128,64,1,false>(y, hh, RJs, nullptr, nullptr);     // RJ += Y^T H
        mm_<64,128,64,0,false>(SL, zt, h2, nullptr, nullptr);      // h2 = Si Z^T (tA dead)
        mm_<128,128,64,2,false>(zt, h2, RCs, L1, nullptr);         // RC'' = RC' - Z h2
        // vectors
        mv_<64,128,2>(Ct, V1, r64s, xs + (size_t)e*DX);            // r = x - C Rb'
        mv_<64,64,0>(Rji, xs + (size_t)e*DX, u64s, nullptr);       // u = R~i x
        mv_<128,64,1>(zt, u64s, V2, V1);                           // v1 = Rb' + Z u
        mv_<64,128,0>(Ct, V2, GJc, nullptr);                       // w = C v1
        mv_<64,64,0>(SL, GJc, GJr, nullptr);                       // w2 = Si w
        mv_<128,64,2>(zt, GJr, V0, V2);                            // Rb'' = v1 - Z w2
        mv_<64,64,0>(SL, r64s, u64s, nullptr);                     // s = Si r
        mv_<128,64,1>(y, u64s, V5, V5);                            // Reta += Y^T s
    }
    __syncthreads();
    if (tid < DZ) { Rbs[tid] = V0[tid]; Rhs[tid] = V5[tid]; }
    trans_g(RAs, RAts, L0);
}

// =====================================================================
// combine: Rd <- Rd (earlier) (x) E (later).  t1 lives in L1 (LDS).
// lastj: only RC/Rb needed.
// =====================================================================
__device__ void combine(float* Rd,
    const float* EA, const float* EAt, const float* EC, const float* EJ,
    const float* Ebg, const float* Ehg,
    float* t2, float* t3,
    float* L0, float* L1,
    float* V0, float* V1, float* V2, float* V3, float* V4, float* V5,
    float* GJc, float* GJr, int* REC, int* IPV1, int lastj)
{
    float* RA = Rd; float* RAt = Rd+MS; float* RC = Rd+2*MS; float* RJ = Rd+3*MS;
    float* Rb = Rd+4*MS; float* Rh = Rd+4*MS+DZ;
    const int tid = threadIdx.x;
    __syncthreads();
    if (tid < DZ) { V0[tid]=Ebg[tid]; V1[tid]=Ehg[tid]; V2[tid]=Rb[tid]; }
    mm_<128,128,128,0,false>(EJ, RC, L0, nullptr, nullptr);    // L0 = EJ RC
    if (tid < DZ) L0[tid*DZ + tid] += 1.f;                     // M^T
    gj128_piv(L0, GJc, GJr, REC, IPV1);                        // L0 = M^-T
    if (!lastj) {
        mm_<128,128,128,0,false>(L0, RA, L1, nullptr, nullptr);    // t1 = Minv RA (LDS)
        mm_<128,128,128,0,false>(EJ, RA, t2, nullptr, nullptr);    // t2 = EJ RA
        mm_<128,128,128,1,false>(L1, t2, RJ, nullptr, nullptr);    // RJ += t1^T t2
        mv_<128,128,2>(EJ, V2, V4, V1);                            // w1 = Eh - EJ Rb
        mv_<128,128,1>(L1, V4, Rh, Rh);                            // Rh += t1^T w1
    }
    mv_<128,128,1>(RC, V1, V3, V2);                            // v1 = Rb + RC Eh
    mv_<128,128,0>(L0, V3, V5, nullptr);                       // z1 = Minv v1
    mv_<128,128,1>(EAt, V5, Rb, V0);                           // Rb = Eb + EA z1
    mm_<128,128,128,0,false>(L0, RC, t3, nullptr, nullptr);    // t3 = Minv RC
    mm_<128,128,128,0,false>(t3, EAt, t2, nullptr, nullptr);   // t2 = (Minv RC)^T EA^T
    mm_<128,128,128,3,false>(EAt, t2, RC, EC, nullptr);        // RC = EA t2 + EC
    if (!lastj) {
        mm_<128,128,128,0,false>(EAt, L1, RA, nullptr, nullptr);   // RA = EA t1
        trans_g(RA, RAt, L1);
    }
}

// =====================================================================
// Kogge-Stone scan round
// =====================================================================
__global__ __launch_bounds__(NT) void kf_scan(
    const float* __restrict__ in, float* __restrict__ out, float* scr, int r, int lastj)
{
    SHARED_DECLS
    const int c = blockIdx.x;
    float* sc = scr + (size_t)c * SCN;
    float* dst = out + (size_t)c * ESZ;
    const float* src = in + (size_t)((c >= r) ? (c - r) : c) * ESZ;
    if (lastj) {
        for (int e = threadIdx.x; e < MS; e += NT) dst[2*MS + e] = src[2*MS + e];
        for (int e = threadIdx.x; e < DZ; e += NT) dst[4*MS + e] = src[4*MS + e];
    } else {
        for (int e = threadIdx.x; e < ESZ; e += NT) dst[e] = src[e];
    }
    if (c >= r) {
        const float* E = in + (size_t)c * ESZ;
        combine(dst, E, E+MS, E+2*MS, E+3*MS, E+4*MS, E+4*MS+DZ,
                sc+SP, sc+SX, L0, L1,
                V0,V1,V2,V3,V4,V5, GJc, GJr, REC, IPV1, lastj);
    }
}

// =====================================================================
// pass C: per chunk, plain filter from exact boundary state; writes outputs.
// Ppr lives in L1; Z/Zt in L0 (after mupr).
// =====================================================================
__global__ __launch_bounds__(NT) void kf_passC(
    const float* __restrict__ A_s, const float* __restrict__ b_s,
    const float* __restrict__ Qch, const float* __restrict__ es,
    const float* __restrict__ ts, const float* __restrict__ xs,
    const float* __restrict__ Ct, const float* __restrict__ Rj,
    const float* __restrict__ mu0u, const float* __restrict__ p0u,
    const float* __restrict__ pfx,
    float* mu_out, float* P_out, float* scr, int T, int LCH,
    float g1, float g2, float g3, float g4)
{
    SHARED_DECLS
    const int c = blockIdx.x, tid = threadIdx.x;
    float* sc = scr + (size_t)c * SCN;
    float* P = sc + SP;
    int eBeg = c*LCH, eEnd = (c*LCH + LCH < T) ? (c*LCH + LCH) : T;
    if (eBeg >= eEnd && c != 0) return;
    if (c == 0) {
        for (int e = tid; e < MS; e += NT) { float v = p0u[e]; P[e] = v; P_out[e] = v; }
        if (tid < DZ) { V0[tid] = mu0u[tid]; mu_out[tid] = mu0u[tid]; }
        eBeg = 1;
    } else {
        const float* X = pfx + (size_t)(c-1) * ESZ;
        for (int e = tid; e < MS; e += NT) P[e] = X[2*MS + e];
        if (tid < DZ) V0[tid] = X[4*MS + tid];
    }
    __syncthreads();
    float* sx = sc+SX; float* sx2 = sc+SX2; float* sx2t = sc+SX2T; float* sq = sc+SQ;
    float* z  = L0;    float* zt = L0 + 8192;
    for (int e = eBeg; e < eEnd; ++e) {
        phase1_dev(e, A_s,b_s,Qch,es,ts, sx,sx2,sx2t,sq, L0,L1,
                   W16,ebv,eqv,vvv,cvec, g1,g2,g3,g4);
        mm_<128,128,128,0,false>(P, L0, sx, nullptr, nullptr);     // U = P F^T (X dead)
        mm_<128,128,128,3,false>(L0, sx, L1, sq, nullptr);         // Ppr = F U + Q -> L1
        mv_<128,128,1>(L0, V0, V1, cvec);                          // mupr = F mu + c (Ft last use)
        mm_<128,64,128,0,true>(L1, Ct, z, nullptr, zt);            // Z = Ppr C^T (dual, LDS)
        mm_<64,64,128,3,false>(Ct, z, SL, Rj, nullptr);            // S
        gj64_spd(SL, GJB);
        mm_<64,128,64,0,false>(SL, zt, sx2, nullptr, nullptr);     // kt = Si Z^T
        mv_<64,128,2>(Ct, V1, r64s, xs + (size_t)e*DX);            // y = x - C mupr
        mv_<128,64,1>(sx2, r64s, V0, V1);                          // mu = mupr + K y
        if (tid < DZ) mu_out[(size_t)e*DZ + tid] = V0[tid];
        mm_<128,128,64,2,false>(zt, sx2, L1, L1, nullptr);         // P_u = Ppr - Z kt (in-place)
        float* po = P_out + (size_t)e * MS;
        for (int ee = tid; ee < MS; ee += NT) {
            int i = ee>>7, j = ee&127;
            float v = 0.5f * (L1[ee] + L1[j*DZ + i]);
            P[ee] = v;
            __builtin_nontemporal_store(v, &po[ee]);
        }
        __syncthreads();
    }
}

// =====================================================================
// host: RK stability polynomial coefficients
// =====================================================================
static void compute_gamma(double g[7])
{
    const double A[6][5] = {
        {0, 0, 0, 0, 0},
        {0.161, 0, 0, 0, 0},
        {-0.008480655492356989, 0.335480655492357, 0, 0, 0},
        {2.8971530571054935, -6.359448489975075, 4.3622954328695815, 0, 0},
        {5.325864828439257, -11.748883564062828, 7.4955393428898365, -0.09249506636175525, 0},
        {5.86145544294642, -12.92096931784711, 8.159367898576159, -0.071584973281401, -0.028269050394068383}};
    const double B[6] = {0.09646076681806523, 0.01, 0.4798896504144996,
                         1.379008574103742, -3.290069515436081, 2.324710524099774};
    double e[6][6];
    for (int i = 0; i < 6; ++i)
        for (int d = 0; d < 6; ++d) e[i][d] = 0.0;
    for (int i = 0; i < 6; ++i) {
        e[i][0] = 1.0;
        for (int j = 0; j < i; ++j)
            for (int d = 0; d < 5; ++d)
                e[i][d + 1] += A[i][j] * e[j][d];
    }
    g[0] = 1.0;
    for (int m = 1; m <= 6; ++m) {
        double s = 0.0;
        for (int i = 0; i < 6; ++i) s += B[i] * e[i][m - 1];
        g[m] = s;
    }
}

extern "C" void kernel_launch(void* const* d_in, const int* in_sizes, int n_in,
                              void* d_out, int out_size, void* d_ws, size_t ws_size,
                              hipStream_t stream)
{
    const float* xs  = (const float*)d_in[0];
    const float* ts  = (const float*)d_in[1];
    const float* es  = (const float*)d_in[2];
    const float* mu0 = (const float*)d_in[3];
    const float* P0  = (const float*)d_in[4];
    const float* A_s = (const float*)d_in[5];
    const float* b_s = (const float*)d_in[6];
    const float* Qch = (const float*)d_in[7];
    const float* Cm  = (const float*)d_in[8];
    const float* Rm  = (const float*)d_in[9];
    const int T = in_sizes[1];

    float* mu_out = (float*)d_out;
    float* P_out  = mu_out + (size_t)T * DZ;

    float* ws = (float*)d_ws;
    float* Ct    = ws;                        // 8192
    float* Rj    = ws + 8192;                 // 4096
    float* Rji   = ws + 12288;                // 4096
    float* mu0u  = ws + 16384;                // 128
    float* p0u   = ws + 16512;                // 16384
    float* elemsA = ws + 32896;
    float* elemsB = elemsA + (size_t)NCH * ESZ;
    float* scr    = elemsB + (size_t)NCH * ESZ;

    const int LCH = (T + NCH - 1) / NCH;

    double g[7];
    compute_gamma(g);
    const float g1 = (float)g[1], g2 = (float)g[2], g3 = (float)g[3], g4 = (float)g[4];

    hipLaunchKernelGGL(kf_prep, dim3(1), dim3(NT), 0, stream,
                       Cm, Rm, mu0, P0, xs, Ct, Rj, Rji, mu0u, p0u, scr);
    hipLaunchKernelGGL(kf_passA, dim3(NCH), dim3(NT), 0, stream,
                       A_s, b_s, Qch, es, ts, xs, Ct, Rj, Rji, mu0u, p0u,
                       elemsA, scr, T, LCH, g1, g2, g3, g4);
    float* bufs[2] = {elemsA, elemsB};
    int cur = 0;
    for (int r = 1; r < NCH; r <<= 1) {
        const int lastj = ((r << 1) >= NCH) ? 1 : 0;
        hipLaunchKernelGGL(kf_scan, dim3(NCH), dim3(NT), 0, stream,
                           bufs[cur], bufs[cur ^ 1], scr, r, lastj);
        cur ^= 1;
    }
    hipLaunchKernelGGL(kf_passC, dim3(NCH), dim3(NT), 0, stream,
                       A_s, b_s, Qch, es, ts, xs, Ct, Rj, mu0u, p0u,
                       bufs[cur], mu_out, P_out, scr, T, LCH, g1, g2, g3, g4);
}

// Round 9
// 11663.721 us; speedup vs baseline: 24.4494x; 1.0229x over previous
//
#include <hip/hip_runtime.h>
#include <math.h>

#define DZ 128
#define DX 64
#define KMIX 16
#define JITTER_C 1e-4f
#define MS (DZ*DZ)            // 16384
#define ESZ (4*MS + 2*DZ)     // element: A, At, C, J, b, eta
#define NCH 256               // chunks
#define NT 1024               // threads per block (16 waves, 4/SIMD)
#define SCN (5*MS + 256)      // per-chunk scratch floats

// scr slot offsets (per chunk)
#define SP   0
#define SX   (1*MS)
#define SX2  (2*MS)
#define SX2T (3*MS)
#define SQ   (4*MS)

// =====================================================================
// mm_: out[MxN] = op( sum_k At[k*M+i] * B[k*N+j] )  i.e. out = (At)^T*B
// MODE 0: store; 1: out += acc; 2: out = aux - acc; 3: out = aux + acc
// MODE 4: out = acc + e1*aux + I   (aux may alias out; per-thread tiles)
// DUAL: additionally store transposed result to outT (N x M).
// NT=1024 threads, 32x32 grid, per-thread tile (M/32)x(N/32).
// K-loop is WAVE-SKEWED: wave w starts at w*K/16 (two linear sub-loops)
// so waves issue loads at staggered phases instead of barrier-lockstep.
// =====================================================================
template<int M, int N, int K, int MODE, bool DUAL>
__device__ void mm_(const float* __restrict__ At, const float* __restrict__ B,
                    float* __restrict__ out, const float* __restrict__ aux,
                    float* __restrict__ outT, float e1 = 0.f)
{
    __syncthreads();
    const int tid = threadIdx.x;
    constexpr int TM = M/32, TN = N/32;
    const int tx = tid & 31, ty = tid >> 5;
    const int i0 = ty*TM, j0 = tx*TN;
    float acc[TM*TN];
#pragma unroll
    for (int e = 0; e < TM*TN; ++e) acc[e] = 0.f;
    auto body = [&](int k) {
        const float* ar = At + k*M + i0;
        const float* br = B + k*N + j0;
        float av[TM], bv[TN];
        if constexpr (TM == 2) {
            float2 t = *reinterpret_cast<const float2*>(ar);
            av[0]=t.x; av[1]=t.y;
        } else {
#pragma unroll
            for (int a = 0; a < TM; a += 4) {
                float4 t = *reinterpret_cast<const float4*>(ar + a);
                av[a]=t.x; av[a+1]=t.y; av[a+2]=t.z; av[a+3]=t.w;
            }
        }
        if constexpr (TN == 2) {
            float2 t = *reinterpret_cast<const float2*>(br);
            bv[0]=t.x; bv[1]=t.y;
        } else {
#pragma unroll
            for (int b = 0; b < TN; b += 4) {
                float4 t = *reinterpret_cast<const float4*>(br + b);
                bv[b]=t.x; bv[b+1]=t.y; bv[b+2]=t.z; bv[b+3]=t.w;
            }
        }
#pragma unroll
        for (int a = 0; a < TM; ++a)
#pragma unroll
            for (int b = 0; b < TN; ++b)
                acc[a*TN+b] = fmaf(av[a], bv[b], acc[a*TN+b]);
    };
    const int off = (tid >> 6) * (K >> 4);   // wave-skewed start
#pragma unroll 8
    for (int k = off; k < K; ++k) body(k);
#pragma unroll 8
    for (int k = 0; k < off; ++k) body(k);
#pragma unroll
    for (int a = 0; a < TM; ++a) {
#pragma unroll
        for (int b = 0; b < TN; ++b) {
            const int row = i0+a, col = j0+b;
            const int idx = row*N + col;
            float v = acc[a*TN+b];
            if constexpr (MODE == 1) v += out[idx];
            else if constexpr (MODE == 2) v = aux[idx] - v;
            else if constexpr (MODE == 3) v += aux[idx];
            else if constexpr (MODE == 4) { v += e1*aux[idx]; if (row==col) v += 1.f; }
            out[idx] = v;
            acc[a*TN+b] = v;
        }
    }
    if constexpr (DUAL) {
#pragma unroll
        for (int b = 0; b < TN; ++b) {
#pragma unroll
            for (int a = 0; a < TM; a += 4) {
                float4 v = make_float4(acc[(a)*TN+b], acc[(a+1)*TN+b], acc[(a+2)*TN+b], acc[(a+3)*TN+b]);
                *reinterpret_cast<float4*>(outT + (j0+b)*M + i0 + a) = v;
            }
        }
    }
    __syncthreads();
}

// =====================================================================
// mv_: out[i] = op(aux[i], sum_k At[k*M+i]*v[k]) — PARALLEL over K:
// NT/M threads per row, shfl_xor reduce, lane 0 writes.
// MODE 0: sum; 1: aux + sum; 2: aux - sum
// =====================================================================
template<int M, int K, int MODE>
__device__ void mv_(const float* __restrict__ At, const float* __restrict__ v,
                    float* __restrict__ out, const float* __restrict__ aux)
{
    __syncthreads();
    const int tid = threadIdx.x;
    constexpr int TPR = NT / M;       // 8 (M=128) or 16 (M=64); divides 64
    constexpr int CH  = K / TPR;
    const int r  = tid / TPR;
    const int sg = tid % TPR;
    const int k0 = sg * CH;
    float s = 0.f;
#pragma unroll
    for (int k = 0; k < CH; ++k)
        s = fmaf(At[(k0 + k)*M + r], v[k0 + k], s);
#pragma unroll
    for (int o = 1; o < TPR; o <<= 1) s += __shfl_xor(s, o);
    if (sg == 0) {
        float rr;
        if constexpr (MODE == 0) rr = s;
        else if constexpr (MODE == 1) rr = aux[r] + s;
        else rr = aux[r] - s;
        out[r] = rr;
    }
    __syncthreads();
}

// dst[NxM] = src[MxN]^T via XOR-swizzled LDS bounce (128x128 only).
// Swizzle col ^ (row&31) makes BOTH phases bank-conflict-free.
__device__ void trans_g(const float* __restrict__ src, float* __restrict__ dst,
                        float* __restrict__ Lb)
{
    __syncthreads();
    for (int e = threadIdx.x; e < MS; e += NT) {
        int i = e >> 7, j = e & 127;
        Lb[(i << 7) + (j ^ (i & 31))] = src[e];
    }
    __syncthreads();
    for (int e = threadIdx.x; e < MS; e += NT) {
        int a = e >> 7, b = e & 127;
        dst[e] = Lb[(b << 7) + (a ^ (b & 31))];
    }
    __syncthreads();
}

// =====================================================================
// gj64_spd: rank-4 block Gauss-Jordan inverse of SPD 64x64 in LDS.
// =====================================================================
__device__ void gj64_spd(float* __restrict__ A, float* __restrict__ st)
{
    const int tid = threadIdx.x;
    for (int p = 0; p < DX; p += 4) {
        __syncthreads();
        if (tid < 64) {
#pragma unroll
            for (int b = 0; b < 4; ++b) st[tid*4+b] = A[tid*DX + p + b];
        } else if (tid < 128) {
            int j = tid - 64;
#pragma unroll
            for (int b = 0; b < 4; ++b) st[256 + b*64 + j] = A[(p+b)*DX + j];
        }
        __syncthreads();
        float Dm[16], Di[16];
#pragma unroll
        for (int a = 0; a < 4; ++a)
#pragma unroll
            for (int b = 0; b < 4; ++b) {
                Dm[a*4+b] = st[(p+a)*4 + b];
                Di[a*4+b] = (a==b) ? 1.f : 0.f;
            }
#pragma unroll
        for (int q = 0; q < 4; ++q) {
            float rp = 1.f / Dm[q*4+q];
#pragma unroll
            for (int j = 0; j < 4; ++j) { Dm[q*4+j] *= rp; Di[q*4+j] *= rp; }
#pragma unroll
            for (int i = 0; i < 4; ++i) {
                if (i == q) continue;
                float f = Dm[i*4+q];
#pragma unroll
                for (int j = 0; j < 4; ++j) { Dm[i*4+j] = fmaf(-f, Dm[q*4+j], Dm[i*4+j]); Di[i*4+j] = fmaf(-f, Di[q*4+j], Di[i*4+j]); }
            }
        }
        for (int e = tid; e < DX*DX; e += NT) {
            const int i = e >> 6, j = e & 63;
            const bool iP = (i >= p) && (i < p+4);
            const bool jP = (j >= p) && (j < p+4);
            float o;
            if (iP && jP) {
                o = Di[(i-p)*4 + (j-p)];
            } else if (iP) {
                const int a = i - p;
                o = Di[a*4+0]*st[256+0*64+j] + Di[a*4+1]*st[256+1*64+j]
                  + Di[a*4+2]*st[256+2*64+j] + Di[a*4+3]*st[256+3*64+j];
            } else {
                float Ei[4];
#pragma unroll
                for (int b = 0; b < 4; ++b)
                    Ei[b] = st[i*4+0]*Di[0*4+b] + st[i*4+1]*Di[1*4+b]
                          + st[i*4+2]*Di[2*4+b] + st[i*4+3]*Di[3*4+b];
                if (jP) o = -Ei[j-p];
                else    o = A[e] - (Ei[0]*st[256+0*64+j] + Ei[1]*st[256+1*64+j]
                                  + Ei[2]*st[256+2*64+j] + Ei[3]*st[256+3*64+j]);
            }
            A[e] = o;
        }
    }
    __syncthreads();
}

// =====================================================================
// gj128_piv: partial-pivoted GJ of 128x128 in LDS; wave-0 shfl argmax.
// =====================================================================
__device__ void gj128_piv(float* __restrict__ A, float* __restrict__ pc, float* __restrict__ pr,
                          int* __restrict__ rec, int* __restrict__ ipv1)
{
    __syncthreads();
    const int tid = threadIdx.x;
    for (int p = 0; p < DZ; ++p) {
        if (tid < 64) {
            float best = -1.f; int bi = p;
            for (int i = tid; i < DZ; i += 64) {
                float v = (i >= p) ? fabsf(A[i*DZ + p]) : -2.f;
                if (v > best) { best = v; bi = i; }
            }
            for (int off = 32; off > 0; off >>= 1) {
                float ob = __shfl_xor(best, off);
                int obi = __shfl_xor(bi, off);
                if (ob > best) { best = ob; bi = obi; }
            }
            if (tid == 0) { rec[p] = bi; ipv1[0] = bi; }
        }
        __syncthreads();
        const int r = ipv1[0];
        if (r != p) {
            for (int j = tid; j < DZ; j += NT) { float t = A[p*DZ+j]; A[p*DZ+j] = A[r*DZ+j]; A[r*DZ+j] = t; }
            __syncthreads();
        }
        if (tid < DZ) { pc[tid] = A[tid*DZ + p]; pr[tid] = A[p*DZ + tid]; }
        __syncthreads();
        const float rp = 1.f / pr[p];
        for (int e = tid; e < MS; e += NT) {
            const int i = e >> 7, j = e & 127;
            const float pv = pr[j] * rp;
            float o;
            if (i == p) o = (j == p) ? rp : pv;
            else { const float fc = pc[i]; o = (j == p) ? (-fc*rp) : (A[e] - fc*pv); }
            A[e] = o;
        }
        __syncthreads();
    }
    for (int p = DZ - 1; p >= 0; --p) {
        const int r = rec[p];
        if (r != p) {
            for (int i = tid; i < DZ; i += NT) { float t = A[i*DZ+p]; A[i*DZ+p] = A[i*DZ+r]; A[i*DZ+r] = t; }
            __syncthreads();
        }
    }
    __syncthreads();
}

// =====================================================================
// phase1_dev: slim step map (||X|| ~ 1e-2):
//   F = I + g1 X + (g2 I + g3 X) X^2      -> Ft in L0 (LDS)
//   Q = h (g1 D + W1 D + D W1^T),  W1 = g2 X + g3 X^2   -> sq
//   c = h (g1 + g2 X + g3 X^2 + g4 X^3) eb               -> cvec
// =====================================================================
__device__ void phase1_dev(int k,
    const float* __restrict__ A_s, const float* __restrict__ b_s,
    const float* __restrict__ Qch, const float* __restrict__ es, const float* __restrict__ ts,
    float* sx, float* sx2, float* sx2t, float* sq,
    float* L0, float* L1,
    float* W16, float* ebv, float* eqv, float* vvv, float* cvec,
    float g1, float g2, float g3, float g4)
{
    const int tid = threadIdx.x;
    const float h = ts[k] - ts[k-1];
    if (h <= 0.f) {
        __syncthreads();
        for (int e = tid; e < MS; e += NT) {
            int i = e >> 7, j = e & 127;
            L0[e] = (i==j) ? 1.f : 0.f;
            sq[e] = 0.f;
        }
        if (tid < DZ) cvec[tid] = 0.f;
        __syncthreads();
        return;
    }
    __syncthreads();
    if (tid < KMIX) W16[tid] = es[(size_t)k*KMIX + tid];
    __syncthreads();
    if (tid == 0) {
        float s = 0.f;
        for (int m = 0; m < KMIX; ++m) s += W16[m];
        float inv = 1.f/s;
        for (int m = 0; m < KMIX; ++m) W16[m] *= inv;
    }
    __syncthreads();
    if (tid < DZ) {
        float eb = 0.f, eq = 0.f;
        for (int m = 0; m < KMIX; ++m) {
            float wm = W16[m];
            eb = fmaf(wm, b_s[m*DZ+tid], eb);
            float qc = Qch[m*DZ+tid];
            eq = fmaf(wm, qc*qc, eq);
        }
        ebv[tid] = eb; eqv[tid] = eq;
    }
    // X = h * sum_m w_m A_s[m] -> L1 (X), sx (X), L0 (Xt); wave-skewed m-loop
    const int tx = tid & 31, ty = tid >> 5;
    const int i0 = ty*4, j0 = tx*4;
    float t16[16];
#pragma unroll
    for (int e = 0; e < 16; ++e) t16[e] = 0.f;
    {
        const int mq = (tid >> 6) & (KMIX - 1);
        for (int mi = 0; mi < KMIX; ++mi) {
            int m = mi + mq; if (m >= KMIX) m -= KMIX;
            float wm = W16[m];
            const float* Am = A_s + (size_t)m * MS;
#pragma unroll
            for (int a = 0; a < 4; ++a) {
                float4 p0 = *reinterpret_cast<const float4*>(&Am[(i0+a)*DZ + j0]);
                t16[a*4+0]=fmaf(wm,p0.x,t16[a*4+0]); t16[a*4+1]=fmaf(wm,p0.y,t16[a*4+1]);
                t16[a*4+2]=fmaf(wm,p0.z,t16[a*4+2]); t16[a*4+3]=fmaf(wm,p0.w,t16[a*4+3]);
            }
        }
    }
#pragma unroll
    for (int a = 0; a < 4; ++a)
#pragma unroll
        for (int b = 0; b < 4; ++b) {
            float v = h * t16[a*4+b];
            L1[(i0+a)*DZ + (j0+b)] = v;
            sx[(i0+a)*DZ + (j0+b)] = v;
            L0[(j0+b)*DZ + (i0+a)] = v;
        }
    __syncthreads();
    // cvec: 3 power iterations (terms through g4 X^3) — small, serial rows
    {
        float gg[5]; gg[1]=g1; gg[2]=g2; gg[3]=g3; gg[4]=g4;
        if (tid < DZ) vvv[tid] = ebv[tid];
        float creg = (tid < DZ) ? g1 * ebv[tid] : 0.f;
        __syncthreads();
        for (int m = 1; m <= 3; ++m) {
            float vn = 0.f;
            if (tid < DZ)
                for (int kk = 0; kk < DZ; ++kk)
                    vn = fmaf(L0[kk*DZ + tid], vvv[kk], vn);
            __syncthreads();
            if (tid < DZ) vvv[tid] = vn;
            creg = fmaf(gg[m+1], vn, creg);
            __syncthreads();
        }
        if (tid < DZ) cvec[tid] = h * creg;
    }
    // X2 (dual)
    mm_<128,128,128,0,true>(L0, L1, sx2, nullptr, sx2t);
    // fused: Q elementwise -> sq ; M^T = g2 I + g3 Xt -> L1
    for (int e = tid; e < MS; e += NT) {
        int j = e >> 7, i = e & 127;   // j=row, i=col
        float xt = L0[e];
        float w1  = g2*sx[e] + g3*sx2[e];
        float w1t = g2*xt    + g3*sx2t[e];
        float vq = w1*eqv[i] + eqv[j]*w1t;
        if (i == j) vq += g1*eqv[j];
        sq[e] = h * vq;
        L1[e] = g3*xt + ((i==j) ? g2 : 0.f);
    }
    __syncthreads();
    // Ft = X2^T M^T + g1 Xt + I  -> L0 (MODE 4, aux aliases out, per-tile safe)
    mm_<128,128,128,4,false>(sx2, L1, L0, L0, nullptr, g1);
}

#define SHARED_DECLS \
    __shared__ __align__(16) float L0[MS]; \
    __shared__ __align__(16) float L1[MS]; \
    __shared__ __align__(16) float SL[DX*DX]; \
    __shared__ __align__(16) float GJB[520]; \
    __shared__ float V0[DZ],V1[DZ],V2[DZ],V3[DZ],V4[DZ],V5[DZ]; \
    __shared__ float r64s[DX], u64s[DX]; \
    __shared__ float W16[KMIX], ebv[DZ], eqv[DZ], vvv[DZ], cvec[DZ]; \
    __shared__ float GJc[DZ], GJr[DZ]; \
    __shared__ int REC[DZ]; __shared__ int IPV1[1];

// =====================================================================
// prep: Ct, Rj, Rji, initial updated state (mu0u, p0u)
// =====================================================================
__global__ __launch_bounds__(NT) void kf_prep(
    const float* __restrict__ Cm, const float* __restrict__ Rm,
    const float* __restrict__ mu0, const float* __restrict__ P0,
    const float* __restrict__ xs,
    float* Ct, float* Rj, float* Rji, float* mu0u, float* p0u, float* scr)
{
    SHARED_DECLS
    const int tid = threadIdx.x;
    for (int i = tid; i < DZ*DX; i += NT) { int z = i>>6, m = i&63; Ct[i] = Cm[m*DZ + z]; }
    for (int i = tid; i < DX*DX; i += NT) {
        int a = i>>6, b = i&63;
        float v = Rm[i] + ((a==b) ? JITTER_C : 0.f);
        Rj[i] = v; SL[i] = v;
    }
    gj64_spd(SL, GJB);
    for (int i = tid; i < DX*DX; i += NT) Rji[i] = SL[i];
    float* z  = scr + SX;
    float* cp = scr + SX + DZ*DX;
    float* kt = scr + SX2;
    mm_<128,64,128,0,true>(P0, Ct, z, nullptr, cp);     // z = P0 C^T, cp = C P0
    mm_<64,64,128,3,false>(Ct, z, SL, Rj, nullptr);     // S0
    gj64_spd(SL, GJB);
    mm_<64,128,64,0,false>(SL, cp, kt, nullptr, nullptr); // K0^T
    mv_<64,128,2>(Ct, mu0, r64s, xs);                   // r = x0 - C mu0
    mv_<128,64,1>(kt, r64s, mu0u, mu0);                 // mu0u = mu0 + K0 r
    mm_<128,128,64,2,false>(kt, cp, p0u, P0, nullptr);  // P0u = P0 - K0 C P0
    __syncthreads();
    for (int e = tid; e < MS; e += NT) L0[e] = p0u[e];
    __syncthreads();
    for (int e = tid; e < MS; e += NT) {
        int i = e>>7, j = e&127;
        p0u[e] = 0.5f * (L0[e] + L0[j*DZ + i]);
    }
}

// =====================================================================
// pass A: per chunk, direct element recursion (predict + Woodbury update)
// =====================================================================
__global__ __launch_bounds__(NT) void kf_passA(
    const float* __restrict__ A_s, const float* __restrict__ b_s,
    const float* __restrict__ Qch, const float* __restrict__ es,
    const float* __restrict__ ts, const float* __restrict__ xs,
    const float* __restrict__ Ct, const float* __restrict__ Rj,
    const float* __restrict__ Rji,
    const float* __restrict__ mu0u, const float* __restrict__ p0u,
    float* elems, float* scr, int T, int LCH,
    float g1, float g2, float g3, float g4)
{
    SHARED_DECLS
    const int c = blockIdx.x, tid = threadIdx.x;
    float* sc = scr + (size_t)c * SCN;
    float* R = elems + (size_t)c * ESZ;
    float* RAs = R; float* RAts = R+MS; float* RCs = R+2*MS; float* RJs = R+3*MS;
    float* Rbs = R+4*MS; float* Rhs = R+4*MS+DZ;
    int eBeg = c*LCH, eEnd = (c*LCH + LCH < T) ? (c*LCH + LCH) : T;
    if (eBeg >= eEnd && c != 0) {
        for (int e = tid; e < MS; e += NT) {
            int i = e>>7, j = e&127; float id = (i==j)?1.f:0.f;
            RAs[e]=id; RAts[e]=id; RCs[e]=0.f; RJs[e]=0.f;
        }
        if (tid < DZ) { Rbs[tid]=0.f; Rhs[tid]=0.f; }
        return;
    }
    if (c == 0) {
        for (int e = tid; e < MS; e += NT) { RAs[e]=0.f; RCs[e]=p0u[e]; RJs[e]=0.f; }
        if (tid < DZ) { V0[tid]=mu0u[tid]; V5[tid]=0.f; }
        eBeg = 1;
    } else {
        for (int e = tid; e < MS; e += NT) {
            int i = e>>7, j = e&127;
            RAs[e] = (i==j)?1.f:0.f; RCs[e]=0.f; RJs[e]=0.f;
        }
        if (tid < DZ) { V0[tid]=0.f; V5[tid]=0.f; }
    }
    __syncthreads();
    float* sx = sc+SX; float* sx2 = sc+SX2; float* sx2t = sc+SX2T; float* sq = sc+SQ;
    float* z  = L0;    float* zt = L0 + 8192;     // LDS-resident after Ft dead
    float* y  = sq;    float* hh = sq + 8192;     // after Q consumed
    float* h2 = sx;                                // after tA dead
    for (int e = eBeg; e < eEnd; ++e) {
        phase1_dev(e, A_s,b_s,Qch,es,ts, sx,sx2,sx2t,sq, L0,L1,
                   W16,ebv,eqv,vvv,cvec, g1,g2,g3,g4);
        // ---- predict-compose (EJ=0); Ft in L0 ----
        mm_<128,128,128,0,false>(L0, RAs, sx, nullptr, nullptr);   // tA = F RA  (X dead)
        mv_<128,128,1>(L0, V0, V1, cvec);                          // Rb' = F Rb + c
        mm_<128,128,128,0,false>(RCs, L0, sx2, nullptr, nullptr);  // tU = RC F^T (X2 dead)
        mm_<128,128,128,3,false>(L0, sx2, L1, sq, nullptr);        // L1 = RC' = F tU + Q
        // ---- update-compose (Woodbury on rank-64 J_u); Z/Zt -> L0 ----
        mm_<128,64,128,0,true>(L1, Ct, z, nullptr, zt);            // Z = RC' C^T (dual, LDS)
        mm_<64,64,128,3,false>(Ct, z, SL, Rj, nullptr);            // S~ = R~ + C Z
        gj64_spd(SL, GJB);                                         // SL = S~^-1
        mm_<64,128,128,0,false>(Ct, sx, y, nullptr, nullptr);      // Y = C tA (Q dead)
        mm_<64,128,64,0,false>(SL, y, hh, nullptr, nullptr);       // H = Si Y
        mm_<128,128,64,2,false>(zt, hh, RAs, sx, nullptr);         // RA'' = tA - Z H
        mm_<128,128,64,1,false>(y, hh, RJs, nullptr, nullptr);     // RJ += Y^T H
        mm_<64,128,64,0,false>(SL, zt, h2, nullptr, nullptr);      // h2 = Si Z^T (tA dead)
        mm_<128,128,64,2,false>(zt, h2, RCs, L1, nullptr);         // RC'' = RC' - Z h2
        // vectors
        mv_<64,128,2>(Ct, V1, r64s, xs + (size_t)e*DX);            // r = x - C Rb'
        mv_<64,64,0>(Rji, xs + (size_t)e*DX, u64s, nullptr);       // u = R~i x
        mv_<128,64,1>(zt, u64s, V2, V1);                           // v1 = Rb' + Z u
        mv_<64,128,0>(Ct, V2, GJc, nullptr);                       // w = C v1
        mv_<64,64,0>(SL, GJc, GJr, nullptr);                       // w2 = Si w
        mv_<128,64,2>(zt, GJr, V0, V2);                            // Rb'' = v1 - Z w2
        mv_<64,64,0>(SL, r64s, u64s, nullptr);                     // s = Si r
        mv_<128,64,1>(y, u64s, V5, V5);                            // Reta += Y^T s
    }
    __syncthreads();
    if (tid < DZ) { Rbs[tid] = V0[tid]; Rhs[tid] = V5[tid]; }
    trans_g(RAs, RAts, L0);
}

// =====================================================================
// combine: Rd <- Rd (earlier) (x) E (later).  t1 lives in L1 (LDS).
// lastj: only RC/Rb needed.
// =====================================================================
__device__ void combine(float* Rd,
    const float* EA, const float* EAt, const float* EC, const float* EJ,
    const float* Ebg, const float* Ehg,
    float* t2, float* t3,
    float* L0, float* L1,
    float* V0, float* V1, float* V2, float* V3, float* V4, float* V5,
    float* GJc, float* GJr, int* REC, int* IPV1, int lastj)
{
    float* RA = Rd; float* RAt = Rd+MS; float* RC = Rd+2*MS; float* RJ = Rd+3*MS;
    float* Rb = Rd+4*MS; float* Rh = Rd+4*MS+DZ;
    const int tid = threadIdx.x;
    __syncthreads();
    if (tid < DZ) { V0[tid]=Ebg[tid]; V1[tid]=Ehg[tid]; V2[tid]=Rb[tid]; }
    mm_<128,128,128,0,false>(EJ, RC, L0, nullptr, nullptr);    // L0 = EJ RC
    if (tid < DZ) L0[tid*DZ + tid] += 1.f;                     // M^T
    gj128_piv(L0, GJc, GJr, REC, IPV1);                        // L0 = M^-T
    if (!lastj) {
        mm_<128,128,128,0,false>(L0, RA, L1, nullptr, nullptr);    // t1 = Minv RA (LDS)
        mm_<128,128,128,0,false>(EJ, RA, t2, nullptr, nullptr);    // t2 = EJ RA
        mm_<128,128,128,1,false>(L1, t2, RJ, nullptr, nullptr);    // RJ += t1^T t2
        mv_<128,128,2>(EJ, V2, V4, V1);                            // w1 = Eh - EJ Rb
        mv_<128,128,1>(L1, V4, Rh, Rh);                            // Rh += t1^T w1
    }
    mv_<128,128,1>(RC, V1, V3, V2);                            // v1 = Rb + RC Eh
    mv_<128,128,0>(L0, V3, V5, nullptr);                       // z1 = Minv v1
    mv_<128,128,1>(EAt, V5, Rb, V0);                           // Rb = Eb + EA z1
    mm_<128,128,128,0,false>(L0, RC, t3, nullptr, nullptr);    // t3 = Minv RC
    mm_<128,128,128,0,false>(t3, EAt, t2, nullptr, nullptr);   // t2 = (Minv RC)^T EA^T
    mm_<128,128,128,3,false>(EAt, t2, RC, EC, nullptr);        // RC = EA t2 + EC
    if (!lastj) {
        mm_<128,128,128,0,false>(EAt, L1, RA, nullptr, nullptr);   // RA = EA t1
        trans_g(RA, RAt, L1);
    }
}

// =====================================================================
// Kogge-Stone scan round
// =====================================================================
__global__ __launch_bounds__(NT) void kf_scan(
    const float* __restrict__ in, float* __restrict__ out, float* scr, int r, int lastj)
{
    SHARED_DECLS
    const int c = blockIdx.x;
    float* sc = scr + (size_t)c * SCN;
    float* dst = out + (size_t)c * ESZ;
    const float* src = in + (size_t)((c >= r) ? (c - r) : c) * ESZ;
    if (lastj) {
        for (int e = threadIdx.x; e < MS; e += NT) dst[2*MS + e] = src[2*MS + e];
        for (int e = threadIdx.x; e < DZ; e += NT) dst[4*MS + e] = src[4*MS + e];
    } else {
        for (int e = threadIdx.x; e < ESZ; e += NT) dst[e] = src[e];
    }
    if (c >= r) {
        const float* E = in + (size_t)c * ESZ;
        combine(dst, E, E+MS, E+2*MS, E+3*MS, E+4*MS, E+4*MS+DZ,
                sc+SP, sc+SX, L0, L1,
                V0,V1,V2,V3,V4,V5, GJc, GJr, REC, IPV1, lastj);
    }
}

// =====================================================================
// pass C: per chunk, plain filter from exact boundary state; writes outputs.
// Ppr lives in L1; Z/Zt in L0; symmetrize via swizzled L0 bounce.
// =====================================================================
__global__ __launch_bounds__(NT) void kf_passC(
    const float* __restrict__ A_s, const float* __restrict__ b_s,
    const float* __restrict__ Qch, const float* __restrict__ es,
    const float* __restrict__ ts, const float* __restrict__ xs,
    const float* __restrict__ Ct, const float* __restrict__ Rj,
    const float* __restrict__ mu0u, const float* __restrict__ p0u,
    const float* __restrict__ pfx,
    float* mu_out, float* P_out, float* scr, int T, int LCH,
    float g1, float g2, float g3, float g4)
{
    SHARED_DECLS
    const int c = blockIdx.x, tid = threadIdx.x;
    float* sc = scr + (size_t)c * SCN;
    float* P = sc + SP;
    int eBeg = c*LCH, eEnd = (c*LCH + LCH < T) ? (c*LCH + LCH) : T;
    if (eBeg >= eEnd && c != 0) return;
    if (c == 0) {
        for (int e = tid; e < MS; e += NT) { float v = p0u[e]; P[e] = v; P_out[e] = v; }
        if (tid < DZ) { V0[tid] = mu0u[tid]; mu_out[tid] = mu0u[tid]; }
        eBeg = 1;
    } else {
        const float* X = pfx + (size_t)(c-1) * ESZ;
        for (int e = tid; e < MS; e += NT) P[e] = X[2*MS + e];
        if (tid < DZ) V0[tid] = X[4*MS + tid];
    }
    __syncthreads();
    float* sx = sc+SX; float* sx2 = sc+SX2; float* sx2t = sc+SX2T; float* sq = sc+SQ;
    float* z  = L0;    float* zt = L0 + 8192;
    for (int e = eBeg; e < eEnd; ++e) {
        phase1_dev(e, A_s,b_s,Qch,es,ts, sx,sx2,sx2t,sq, L0,L1,
                   W16,ebv,eqv,vvv,cvec, g1,g2,g3,g4);
        mm_<128,128,128,0,false>(P, L0, sx, nullptr, nullptr);     // U = P F^T (X dead)
        mm_<128,128,128,3,false>(L0, sx, L1, sq, nullptr);         // Ppr = F U + Q -> L1
        mv_<128,128,1>(L0, V0, V1, cvec);                          // mupr = F mu + c (Ft last use)
        mm_<128,64,128,0,true>(L1, Ct, z, nullptr, zt);            // Z = Ppr C^T (dual, LDS)
        mm_<64,64,128,3,false>(Ct, z, SL, Rj, nullptr);            // S
        gj64_spd(SL, GJB);
        mm_<64,128,64,0,false>(SL, zt, sx2, nullptr, nullptr);     // kt = Si Z^T
        mv_<64,128,2>(Ct, V1, r64s, xs + (size_t)e*DX);            // y = x - C mupr
        mv_<128,64,1>(sx2, r64s, V0, V1);                          // mu = mupr + K y
        if (tid < DZ) mu_out[(size_t)e*DZ + tid] = V0[tid];
        mm_<128,128,64,2,false>(zt, sx2, L1, L1, nullptr);         // P_u = Ppr - Z kt (in-place)
        // symmetrize: swizzled bounce of P_u into L0 (conflict-free reads)
        for (int ee = tid; ee < MS; ee += NT) {
            int i = ee >> 7, j = ee & 127;
            L0[(i << 7) + (j ^ (i & 31))] = L1[ee];
        }
        __syncthreads();
        float* po = P_out + (size_t)e * MS;
        for (int ee = tid; ee < MS; ee += NT) {
            int i = ee >> 7, j = ee & 127;
            float v = 0.5f * (L1[ee] + L0[(j << 7) + (i ^ (j & 31))]);
            P[ee] = v;
            __builtin_nontemporal_store(v, &po[ee]);
        }
        __syncthreads();
    }
}

// =====================================================================
// host: RK stability polynomial coefficients
// =====================================================================
static void compute_gamma(double g[7])
{
    const double A[6][5] = {
        {0, 0, 0, 0, 0},
        {0.161, 0, 0, 0, 0},
        {-0.008480655492356989, 0.335480655492357, 0, 0, 0},
        {2.8971530571054935, -6.359448489975075, 4.3622954328695815, 0, 0},
        {5.325864828439257, -11.748883564062828, 7.4955393428898365, -0.09249506636175525, 0},
        {5.86145544294642, -12.92096931784711, 8.159367898576159, -0.071584973281401, -0.028269050394068383}};
    const double B[6] = {0.09646076681806523, 0.01, 0.4798896504144996,
                         1.379008574103742, -3.290069515436081, 2.324710524099774};
    double e[6][6];
    for (int i = 0; i < 6; ++i)
        for (int d = 0; d < 6; ++d) e[i][d] = 0.0;
    for (int i = 0; i < 6; ++i) {
        e[i][0] = 1.0;
        for (int j = 0; j < i; ++j)
            for (int d = 0; d < 5; ++d)
                e[i][d + 1] += A[i][j] * e[j][d];
    }
    g[0] = 1.0;
    for (int m = 1; m <= 6; ++m) {
        double s = 0.0;
        for (int i = 0; i < 6; ++i) s += B[i] * e[i][m - 1];
        g[m] = s;
    }
}

extern "C" void kernel_launch(void* const* d_in, const int* in_sizes, int n_in,
                              void* d_out, int out_size, void* d_ws, size_t ws_size,
                              hipStream_t stream)
{
    const float* xs  = (const float*)d_in[0];
    const float* ts  = (const float*)d_in[1];
    const float* es  = (const float*)d_in[2];
    const float* mu0 = (const float*)d_in[3];
    const float* P0  = (const float*)d_in[4];
    const float* A_s = (const float*)d_in[5];
    const float* b_s = (const float*)d_in[6];
    const float* Qch = (const float*)d_in[7];
    const float* Cm  = (const float*)d_in[8];
    const float* Rm  = (const float*)d_in[9];
    const int T = in_sizes[1];

    float* mu_out = (float*)d_out;
    float* P_out  = mu_out + (size_t)T * DZ;

    float* ws = (float*)d_ws;
    float* Ct    = ws;                        // 8192
    float* Rj    = ws + 8192;                 // 4096
    float* Rji   = ws + 12288;                // 4096
    float* mu0u  = ws + 16384;                // 128
    float* p0u   = ws + 16512;                // 16384
    float* elemsA = ws + 32896;
    float* elemsB = elemsA + (size_t)NCH * ESZ;
    float* scr    = elemsB + (size_t)NCH * ESZ;

    const int LCH = (T + NCH - 1) / NCH;

    double g[7];
    compute_gamma(g);
    const float g1 = (float)g[1], g2 = (float)g[2], g3 = (float)g[3], g4 = (float)g[4];

    hipLaunchKernelGGL(kf_prep, dim3(1), dim3(NT), 0, stream,
                       Cm, Rm, mu0, P0, xs, Ct, Rj, Rji, mu0u, p0u, scr);
    hipLaunchKernelGGL(kf_passA, dim3(NCH), dim3(NT), 0, stream,
                       A_s, b_s, Qch, es, ts, xs, Ct, Rj, Rji, mu0u, p0u,
                       elemsA, scr, T, LCH, g1, g2, g3, g4);
    float* bufs[2] = {elemsA, elemsB};
    int cur = 0;
    for (int r = 1; r < NCH; r <<= 1) {
        const int lastj = ((r << 1) >= NCH) ? 1 : 0;
        hipLaunchKernelGGL(kf_scan, dim3(NCH), dim3(NT), 0, stream,
                           bufs[cur], bufs[cur ^ 1], scr, r, lastj);
        cur ^= 1;
    }
    hipLaunchKernelGGL(kf_passC, dim3(NCH), dim3(NT), 0, stream,
                       A_s, b_s, Qch, es, ts, xs, Ct, Rj, mu0u, p0u,
                       bufs[cur], mu_out, P_out, scr, T, LCH, g1, g2, g3, g4);
}